// Round 1
// baseline (1434.809 us; speedup 1.0000x reference)
//
#include <hip/hip_runtime.h>

// GCN forward: 4x [GEMM -> symmetric-normalized aggregation -> lrelu -> BN(folded)]
// then mean-pool per graph @ Wout. All fp32.
//
// Key structure:
//  - CSR built per launch (counting sort): scatter->gather, no big float atomics.
//  - dinv folded: linS = (h@W)*dinv[row]; agg[v] = dinv[v]*(linS[v] + sum_in linS[row]).
//  - BN folded into next GEMM: Wf = s[:,None]*W, plus row-constant term t@W entering
//    aggregation as q[v]*(t@W), q[v] = dinv[v]*(dinv[v]+sum_in dinv[row]).
//  - Final layer fuses pool: per-node dot(a4,Wout) -> atomicAdd into per-graph acc.

__global__ __launch_bounds__(256) void k_count(const int* __restrict__ ei,
                                               int* __restrict__ cnt, int E) {
  int i = blockIdx.x * 256 + threadIdx.x;
  if (i < E) atomicAdd(&cnt[ei[E + i]], 1);
}

__global__ __launch_bounds__(256) void k_dinv(const int* __restrict__ cnt,
                                              float* __restrict__ dinv, int N) {
  int i = blockIdx.x * 256 + threadIdx.x;
  if (i < N) dinv[i] = rsqrtf((float)(cnt[i] + 1));
}

__global__ __launch_bounds__(256) void k_sd(const int* __restrict__ ei,
                                            const float* __restrict__ dinv,
                                            float* __restrict__ sd, int E) {
  int i = blockIdx.x * 256 + threadIdx.x;
  if (i < E) atomicAdd(&sd[ei[E + i]], dinv[ei[i]]);
}

__global__ __launch_bounds__(256) void k_q(const float* __restrict__ dinv,
                                           const float* __restrict__ sd,
                                           float* __restrict__ q, int N) {
  int i = blockIdx.x * 256 + threadIdx.x;
  if (i < N) q[i] = dinv[i] * (dinv[i] + sd[i]);
}

__global__ __launch_bounds__(256) void k_scan1(const int* __restrict__ cnt,
                                               int* __restrict__ incl,
                                               int* __restrict__ bsums, int N) {
  __shared__ int s[256];
  int tid = threadIdx.x;
  int idx = blockIdx.x * 256 + tid;
  int v = (idx < N) ? cnt[idx] : 0;
  s[tid] = v;
  __syncthreads();
  for (int off = 1; off < 256; off <<= 1) {
    int t = (tid >= off) ? s[tid - off] : 0;
    __syncthreads();
    s[tid] += t;
    __syncthreads();
  }
  if (idx < N) incl[idx] = s[tid];
  if (tid == 255) bsums[blockIdx.x] = s[255];
}

// nb must be <= 512 (N <= 131072 here: nb = 391)
__global__ __launch_bounds__(512) void k_scan2(const int* __restrict__ bsums,
                                               int* __restrict__ bpref, int nb) {
  __shared__ int s[512];
  int tid = threadIdx.x;
  int v = (tid < nb) ? bsums[tid] : 0;
  s[tid] = v;
  __syncthreads();
  for (int off = 1; off < 512; off <<= 1) {
    int t = (tid >= off) ? s[tid - off] : 0;
    __syncthreads();
    s[tid] += t;
    __syncthreads();
  }
  bpref[tid] = s[tid] - v;  // exclusive prefix of block sums
}

__global__ __launch_bounds__(256) void k_scan3(const int* __restrict__ incl,
                                               const int* __restrict__ cnt,
                                               const int* __restrict__ bpref,
                                               int* __restrict__ offs, int N) {
  int idx = blockIdx.x * 256 + threadIdx.x;
  if (idx < N) offs[idx] = incl[idx] - cnt[idx] + bpref[blockIdx.x];
}

__global__ __launch_bounds__(256) void k_csr(const int* __restrict__ ei,
                                             const int* __restrict__ offs,
                                             int* __restrict__ cursor,
                                             int* __restrict__ rows, int E) {
  int i = blockIdx.x * 256 + threadIdx.x;
  if (i < E) {
    int c = ei[E + i];
    int p = offs[c] + atomicAdd(&cursor[c], 1);
    rows[p] = ei[i];
  }
}

__global__ __launch_bounds__(256) void k_cntg(const int* __restrict__ batch,
                                              float* __restrict__ cntG, int N) {
  int i = blockIdx.x * 256 + threadIdx.x;
  if (i < N) atomicAdd(&cntG[batch[i]], 1.0f);
}

// L[v][:] = (x[v][0:9] @ W0) * dinv[v]
__global__ __launch_bounds__(256) void k_gemm_in(const float* __restrict__ x,
                                                 const float* __restrict__ W0,
                                                 const float* __restrict__ dinv,
                                                 float* __restrict__ L, int N) {
  __shared__ float Wl[9 * 128];
  const int t = threadIdx.x;
  for (int i = t; i < 9 * 128; i += 256) Wl[i] = W0[i];
  __syncthreads();
  const int col = t & 127;
  const int rsub = t >> 7;  // 0..1
  const int base = blockIdx.x * 16;
  for (int it = 0; it < 8; it++) {
    int row = base + it * 2 + rsub;
    if (row < N) {
      float xr[9];
#pragma unroll
      for (int k = 0; k < 9; k++) xr[k] = x[row * 9 + k];
      float a = 0.f;
#pragma unroll
      for (int k = 0; k < 9; k++) a += xr[k] * Wl[k * 128 + col];
      L[row * 128 + col] = a * dinv[row];
    }
  }
}

// L[v][:] = (A[v][:] @ Wf) * dinv[v].  Tile: 32 rows x 128 cols per block.
__global__ __launch_bounds__(256) void k_gemm128(const float* __restrict__ A,
                                                 const float* __restrict__ Wf,
                                                 const float* __restrict__ dinv,
                                                 float* __restrict__ L, int N) {
  __shared__ float Wl[64 * 128];  // 32 KB (K-tile of 64)
  __shared__ float Al[32 * 128];  // 16 KB
  float4* Wl4 = (float4*)Wl;
  float4* Al4 = (float4*)Al;
  const int t = threadIdx.x;
  const int row0 = blockIdx.x * 32;
  const int rows = min(32, N - row0);
  const float4* A4 = (const float4*)(A + row0 * 128);
#pragma unroll
  for (int i = 0; i < 4; i++) {
    int idx = t + i * 256;  // 0..1023 covers 32x32 float4
    float4 z = {0.f, 0.f, 0.f, 0.f};
    Al4[idx] = (idx < rows * 32) ? A4[idx] : z;
  }
  const int colq = t & 31;   // 4 cols: 4*colq..+3
  const int rowg = t >> 5;   // 8 groups x 4 rows
  float4 acc[4];
#pragma unroll
  for (int r = 0; r < 4; r++) acc[r] = {0.f, 0.f, 0.f, 0.f};
  const float4* W4 = (const float4*)Wf;
  for (int kt = 0; kt < 128; kt += 64) {
    __syncthreads();
#pragma unroll
    for (int i = 0; i < 8; i++) {
      int idx = t + i * 256;  // 0..2047
      Wl4[idx] = W4[kt * 32 + idx];
    }
    __syncthreads();
#pragma unroll 4
    for (int k = 0; k < 64; k += 4) {
      float4 w0 = Wl4[(k + 0) * 32 + colq];
      float4 w1 = Wl4[(k + 1) * 32 + colq];
      float4 w2 = Wl4[(k + 2) * 32 + colq];
      float4 w3 = Wl4[(k + 3) * 32 + colq];
#pragma unroll
      for (int r = 0; r < 4; r++) {
        float4 av = Al4[(rowg * 4 + r) * 32 + ((kt + k) >> 2)];
        acc[r].x += av.x * w0.x + av.y * w1.x + av.z * w2.x + av.w * w3.x;
        acc[r].y += av.x * w0.y + av.y * w1.y + av.z * w2.y + av.w * w3.y;
        acc[r].z += av.x * w0.z + av.y * w1.z + av.z * w2.z + av.w * w3.z;
        acc[r].w += av.x * w0.w + av.y * w1.w + av.z * w2.w + av.w * w3.w;
      }
    }
  }
#pragma unroll
  for (int r = 0; r < 4; r++) {
    int row = row0 + rowg * 4 + r;
    if (row < N) {
      float dv = dinv[row];
      float4 o = acc[r];
      o.x *= dv; o.y *= dv; o.z *= dv; o.w *= dv;
      ((float4*)L)[row * 32 + colq] = o;
    }
  }
}

// MODE 0: a = lrelu(dinv[v]*(self+gather) + q[v]*tw + b); write Aout; accumulate BN stats.
// MODE 1: same a, then dot with Wout, atomicAdd into per-graph pool accumulator.
template <int MODE>
__global__ __launch_bounds__(128) void k_spmm(
    const float* __restrict__ L, const int* __restrict__ offs,
    const int* __restrict__ cnt, const int* __restrict__ rows,
    const float* __restrict__ dinv, const float* __restrict__ q,
    const float* __restrict__ tw, const float* __restrict__ bias,
    float* __restrict__ Aout, float* __restrict__ stats,
    const float* __restrict__ wout, const int* __restrict__ batch,
    float* __restrict__ pacc, int N) {
  const int f = threadIdx.x;
  const float twf = tw[f];
  const float bf = bias[f];
  float wo = 0.f;
  if (MODE == 1) wo = wout[f];
  float ls = 0.f, lq = 0.f;
  __shared__ float red[2];
  const int vbase = blockIdx.x * 16;
  for (int nn = 0; nn < 16; nn++) {
    const int v = vbase + nn;
    const bool valid = v < N;
    float a = 0.f;
    if (valid) {
      const int st = offs[v];
      const int dg = cnt[v];
      float a0 = L[v * 128 + f], a1 = 0.f, a2 = 0.f, a3 = 0.f;
      int e = 0;
      for (; e + 4 <= dg; e += 4) {
        int r0 = rows[st + e], r1 = rows[st + e + 1];
        int r2 = rows[st + e + 2], r3 = rows[st + e + 3];
        a0 += L[r0 * 128 + f];
        a1 += L[r1 * 128 + f];
        a2 += L[r2 * 128 + f];
        a3 += L[r3 * 128 + f];
      }
      for (; e < dg; e++) a0 += L[rows[st + e] * 128 + f];
      float z = dinv[v] * ((a0 + a1) + (a2 + a3)) + q[v] * twf + bf;
      a = (z > 0.f) ? z : 0.01f * z;
      if (MODE == 0) {
        Aout[v * 128 + f] = a;
        ls += a;
        lq += a * a;
      }
    }
    if (MODE == 1) {
      float val = valid ? a * wo : 0.f;
#pragma unroll
      for (int o = 32; o > 0; o >>= 1) val += __shfl_down(val, o, 64);
      if ((f & 63) == 0) red[f >> 6] = val;
      __syncthreads();
      if (f == 0 && valid) atomicAdd(&pacc[batch[v]], red[0] + red[1]);
      __syncthreads();
    }
  }
  if (MODE == 0) {
    atomicAdd(&stats[f], ls);
    atomicAdd(&stats[128 + f], lq);
  }
}

// Fold BN affine (from batch stats of previous activation) into next layer's weights.
__global__ __launch_bounds__(128) void k_fold(const float* __restrict__ stats,
                                              const float* __restrict__ g,
                                              const float* __restrict__ be,
                                              const float* __restrict__ W,
                                              float* __restrict__ Wf,
                                              float* __restrict__ tw, float invN) {
  __shared__ float ss[128], tt[128];
  const int j = threadIdx.x;
  float m = stats[j] * invN;
  float var = stats[128 + j] * invN - m * m;
  float sj = g[j] * rsqrtf(var + 1e-5f);
  ss[j] = sj;
  tt[j] = be[j] - m * sj;
  __syncthreads();
  float acc = 0.f;
  for (int i = 0; i < 128; i++) {
    float w = W[i * 128 + j];
    Wf[i * 128 + j] = ss[i] * w;
    acc += tt[i] * w;
  }
  tw[j] = acc;
}

__global__ __launch_bounds__(256) void k_out(const float* __restrict__ pacc,
                                             const float* __restrict__ cntG,
                                             const float* __restrict__ bout,
                                             float* __restrict__ out, int G) {
  int i = blockIdx.x * 256 + threadIdx.x;
  if (i < G) out[i] = pacc[i] / fmaxf(cntG[i], 1.0f) + bout[0];
}

extern "C" void kernel_launch(void* const* d_in, const int* in_sizes, int n_in,
                              void* d_out, int out_size, void* d_ws, size_t ws_size,
                              hipStream_t stream) {
  const float* x    = (const float*)d_in[0];
  const int*   ei   = (const int*)d_in[1];
  const int*   batch= (const int*)d_in[2];
  const float* W0   = (const float*)d_in[3];
  const float* b0   = (const float*)d_in[4];
  const float* W1   = (const float*)d_in[5];
  const float* b1   = (const float*)d_in[6];
  const float* W2   = (const float*)d_in[7];
  const float* b2   = (const float*)d_in[8];
  const float* W3   = (const float*)d_in[9];
  const float* b3   = (const float*)d_in[10];
  const float* g1   = (const float*)d_in[11];
  const float* be1  = (const float*)d_in[12];
  const float* g2   = (const float*)d_in[13];
  const float* be2  = (const float*)d_in[14];
  const float* g3   = (const float*)d_in[15];
  const float* be3  = (const float*)d_in[16];
  const float* Wout = (const float*)d_in[17];
  const float* bout = (const float*)d_in[18];
  float* out = (float*)d_out;

  const int N = in_sizes[0] / 9;
  const int E = in_sizes[1] / 2;
  const int G = out_size;

  char* w = (char*)d_ws;
  auto alloc = [&](size_t bytes) -> void* {
    void* p = (void*)w;
    w += (bytes + 255) & ~(size_t)255;
    return p;
  };
  int*   cnt    = (int*)alloc((size_t)N * 4);
  int*   cursor = (int*)alloc((size_t)N * 4);
  int*   offs   = (int*)alloc((size_t)N * 4);
  int*   incl   = (int*)alloc((size_t)N * 4);
  int*   bsums  = (int*)alloc(512 * 4);
  int*   bpref  = (int*)alloc(512 * 4);
  float* dinv   = (float*)alloc((size_t)N * 4);
  float* sd     = (float*)alloc((size_t)N * 4);
  float* q      = (float*)alloc((size_t)N * 4);
  int*   rows   = (int*)alloc((size_t)E * 4);
  float* cntG   = (float*)alloc((size_t)G * 4);
  float* pacc   = (float*)alloc((size_t)G * 4);
  float* stats  = (float*)alloc(3 * 256 * 4);
  float* tw0    = (float*)alloc(128 * 4);
  float* Wf     = (float*)alloc(128 * 128 * 4);
  float* tw     = (float*)alloc(128 * 4);
  float* L      = (float*)alloc((size_t)N * 128 * 4);
  float* Abuf   = (float*)alloc((size_t)N * 128 * 4);

  hipMemsetAsync(cnt,    0, (size_t)N * 4, stream);
  hipMemsetAsync(cursor, 0, (size_t)N * 4, stream);
  hipMemsetAsync(sd,     0, (size_t)N * 4, stream);
  hipMemsetAsync(cntG,   0, (size_t)G * 4, stream);
  hipMemsetAsync(pacc,   0, (size_t)G * 4, stream);
  hipMemsetAsync(stats,  0, 3 * 256 * 4, stream);
  hipMemsetAsync(tw0,    0, 128 * 4, stream);

  const int eb  = (E + 255) / 256;
  const int nbN = (N + 255) / 256;  // also the scan block count (must be <= 512)
  const int sb  = (N + 15) / 16;    // spmm / gemm_in blocks
  const int gb  = (N + 31) / 32;    // gemm128 blocks
  const float invN = 1.0f / (float)N;

  // --- graph preprocessing ---
  k_count<<<eb, 256, 0, stream>>>(ei, cnt, E);
  k_dinv<<<nbN, 256, 0, stream>>>(cnt, dinv, N);
  k_sd<<<eb, 256, 0, stream>>>(ei, dinv, sd, E);
  k_q<<<nbN, 256, 0, stream>>>(dinv, sd, q, N);
  k_scan1<<<nbN, 256, 0, stream>>>(cnt, incl, bsums, N);
  k_scan2<<<1, 512, 0, stream>>>(bsums, bpref, nbN);
  k_scan3<<<nbN, 256, 0, stream>>>(incl, cnt, bpref, offs, N);
  k_csr<<<eb, 256, 0, stream>>>(ei, offs, cursor, rows, E);
  k_cntg<<<nbN, 256, 0, stream>>>(batch, cntG, N);

  // --- layer 1 (x @ W0) ---
  k_gemm_in<<<sb, 256, 0, stream>>>(x, W0, dinv, L, N);
  k_spmm<0><<<sb, 128, 0, stream>>>(L, offs, cnt, rows, dinv, q, tw0, b0,
                                    Abuf, stats, nullptr, nullptr, nullptr, N);
  // --- layer 2 ---
  k_fold<<<1, 128, 0, stream>>>(stats, g1, be1, W1, Wf, tw, invN);
  k_gemm128<<<gb, 256, 0, stream>>>(Abuf, Wf, dinv, L, N);
  k_spmm<0><<<sb, 128, 0, stream>>>(L, offs, cnt, rows, dinv, q, tw, b1,
                                    Abuf, stats + 256, nullptr, nullptr, nullptr, N);
  // --- layer 3 ---
  k_fold<<<1, 128, 0, stream>>>(stats + 256, g2, be2, W2, Wf, tw, invN);
  k_gemm128<<<gb, 256, 0, stream>>>(Abuf, Wf, dinv, L, N);
  k_spmm<0><<<sb, 128, 0, stream>>>(L, offs, cnt, rows, dinv, q, tw, b2,
                                    Abuf, stats + 512, nullptr, nullptr, nullptr, N);
  // --- layer 4 (+ fused pool @ Wout) ---
  k_fold<<<1, 128, 0, stream>>>(stats + 512, g3, be3, W3, Wf, tw, invN);
  k_gemm128<<<gb, 256, 0, stream>>>(Abuf, Wf, dinv, L, N);
  k_spmm<1><<<sb, 128, 0, stream>>>(L, offs, cnt, rows, dinv, q, tw, b3,
                                    Abuf, nullptr, Wout, batch, pacc, N);
  k_out<<<(G + 255) / 256, 256, 0, stream>>>(pacc, cntG, bout, out, G);
}

// Round 2
// 1432.888 us; speedup vs baseline: 1.0013x; 1.0013x over previous
//
#include <hip/hip_runtime.h>

// GCN forward: 4x [GEMM -> symmetric-normalized aggregation -> lrelu -> BN(folded)]
// then mean-pool per graph @ Wout. All fp32.
//
// Key structure:
//  - CSR built per launch (counting sort): scatter->gather, no big float atomics.
//  - Layer 1 commuted: A(x@W0) = (Ax)@W0 -> gather 48B rows instead of 512B.
//  - dinv folded: linS = (h@W)*dinv[row]; agg[v] = dinv[v]*(linS[v] + sum_in linS[row]).
//  - BN folded into next GEMM: Wf = s[:,None]*W, plus row-constant term t@W entering
//    aggregation as q[v]*(t@W), q[v] = dinv[v]*(dinv[v]+sum_in dinv[row]).
//  - SpMM: 32-lane group per node, float4 gathers (4x bytes/outstanding-load vs scalar),
//    manual index prefetch to break index->gather dependency.
//  - Final layer fuses pool: per-node dot(a4,Wout) -> atomicAdd per-graph.

#define LRELU(z) ((z) > 0.f ? (z) : 0.01f * (z))
#define ADD4(d, s) \
  { d.x += s.x; d.y += s.y; d.z += s.z; d.w += s.w; }

__global__ __launch_bounds__(256) void k_count(const int* __restrict__ ei,
                                               int* __restrict__ cnt, int E) {
  int i = blockIdx.x * 256 + threadIdx.x;
  if (i < E) atomicAdd(&cnt[ei[E + i]], 1);
}

__global__ __launch_bounds__(256) void k_dinv(const int* __restrict__ cnt,
                                              float* __restrict__ dinv, int N) {
  int i = blockIdx.x * 256 + threadIdx.x;
  if (i < N) dinv[i] = rsqrtf((float)(cnt[i] + 1));
}

__global__ __launch_bounds__(256) void k_sd(const int* __restrict__ ei,
                                            const float* __restrict__ dinv,
                                            float* __restrict__ sd, int E) {
  int i = blockIdx.x * 256 + threadIdx.x;
  if (i < E) atomicAdd(&sd[ei[E + i]], dinv[ei[i]]);
}

__global__ __launch_bounds__(256) void k_q(const float* __restrict__ dinv,
                                           const float* __restrict__ sd,
                                           float* __restrict__ q, int N) {
  int i = blockIdx.x * 256 + threadIdx.x;
  if (i < N) q[i] = dinv[i] * (dinv[i] + sd[i]);
}

__global__ __launch_bounds__(256) void k_scan1(const int* __restrict__ cnt,
                                               int* __restrict__ incl,
                                               int* __restrict__ bsums, int N) {
  __shared__ int s[256];
  int tid = threadIdx.x;
  int idx = blockIdx.x * 256 + tid;
  int v = (idx < N) ? cnt[idx] : 0;
  s[tid] = v;
  __syncthreads();
  for (int off = 1; off < 256; off <<= 1) {
    int t = (tid >= off) ? s[tid - off] : 0;
    __syncthreads();
    s[tid] += t;
    __syncthreads();
  }
  if (idx < N) incl[idx] = s[tid];
  if (tid == 255) bsums[blockIdx.x] = s[255];
}

// nb must be <= 512 (N <= 131072 here: nb = 391)
__global__ __launch_bounds__(512) void k_scan2(const int* __restrict__ bsums,
                                               int* __restrict__ bpref, int nb) {
  __shared__ int s[512];
  int tid = threadIdx.x;
  int v = (tid < nb) ? bsums[tid] : 0;
  s[tid] = v;
  __syncthreads();
  for (int off = 1; off < 512; off <<= 1) {
    int t = (tid >= off) ? s[tid - off] : 0;
    __syncthreads();
    s[tid] += t;
    __syncthreads();
  }
  bpref[tid] = s[tid] - v;  // exclusive prefix of block sums
}

__global__ __launch_bounds__(256) void k_scan3(const int* __restrict__ incl,
                                               const int* __restrict__ cnt,
                                               const int* __restrict__ bpref,
                                               int* __restrict__ offs, int N) {
  int idx = blockIdx.x * 256 + threadIdx.x;
  if (idx < N) offs[idx] = incl[idx] - cnt[idx] + bpref[blockIdx.x];
}

__global__ __launch_bounds__(256) void k_csr(const int* __restrict__ ei,
                                             const int* __restrict__ offs,
                                             int* __restrict__ cursor,
                                             int* __restrict__ rows, int E) {
  int i = blockIdx.x * 256 + threadIdx.x;
  if (i < E) {
    int c = ei[E + i];
    int p = offs[c] + atomicAdd(&cursor[c], 1);
    rows[p] = ei[i];
  }
}

__global__ __launch_bounds__(256) void k_cntg(const int* __restrict__ batch,
                                              float* __restrict__ cntG, int N) {
  int i = blockIdx.x * 256 + threadIdx.x;
  if (i < N) atomicAdd(&cntG[batch[i]], 1.0f);
}

// u[v][0:9] = x[v][0:9] * dinv[v], padded to 12 floats
__global__ __launch_bounds__(256) void k_prep_x(const float* __restrict__ x,
                                                const float* __restrict__ dinv,
                                                float* __restrict__ u, int N) {
  int i = blockIdx.x * 256 + threadIdx.x;
  if (i >= N) return;
  float dv = dinv[i];
  const float* xr = x + (size_t)i * 9;
  float4 v0, v1, v2;
  v0.x = xr[0] * dv; v0.y = xr[1] * dv; v0.z = xr[2] * dv; v0.w = xr[3] * dv;
  v1.x = xr[4] * dv; v1.y = xr[5] * dv; v1.z = xr[6] * dv; v1.w = xr[7] * dv;
  v2 = make_float4(xr[8] * dv, 0.f, 0.f, 0.f);
  float4* u4 = (float4*)u;
  u4[(size_t)i * 3 + 0] = v0;
  u4[(size_t)i * 3 + 1] = v1;
  u4[(size_t)i * 3 + 2] = v2;
}

// ax[v] = dinv[v]*(u[v] + sum_in u[row]) over 12-float (padded 9) rows
__global__ __launch_bounds__(256) void k_spmm9(
    const float* __restrict__ u, const int* __restrict__ offs,
    const int* __restrict__ cnt, const int* __restrict__ rows,
    const float* __restrict__ dinv, float* __restrict__ ax, int N) {
  int i = blockIdx.x * 256 + threadIdx.x;
  if (i >= N) return;
  const float4* __restrict__ u4 = (const float4*)u;
  const int st = offs[i];
  const int dg = cnt[i];
  float4 a0 = u4[(size_t)i * 3 + 0];
  float4 a1 = u4[(size_t)i * 3 + 1];
  float4 a2 = u4[(size_t)i * 3 + 2];
  float4 c0 = make_float4(0, 0, 0, 0), c1 = c0, c2 = c0;
  int e = 0, r0 = 0, r1 = 0;
  if (dg >= 2) { r0 = rows[st]; r1 = rows[st + 1]; }
  for (; e + 4 <= dg; e += 2) {
    float4 x0 = u4[(size_t)r0 * 3 + 0];
    float4 x1 = u4[(size_t)r0 * 3 + 1];
    float4 x2 = u4[(size_t)r0 * 3 + 2];
    float4 y0 = u4[(size_t)r1 * 3 + 0];
    float4 y1 = u4[(size_t)r1 * 3 + 1];
    float4 y2 = u4[(size_t)r1 * 3 + 2];
    r0 = rows[st + e + 2];
    r1 = rows[st + e + 3];
    ADD4(a0, x0); ADD4(a1, x1); ADD4(a2, x2);
    ADD4(c0, y0); ADD4(c1, y1); ADD4(c2, y2);
  }
  if (e + 2 <= dg) {
    float4 x0 = u4[(size_t)r0 * 3 + 0];
    float4 x1 = u4[(size_t)r0 * 3 + 1];
    float4 x2 = u4[(size_t)r0 * 3 + 2];
    float4 y0 = u4[(size_t)r1 * 3 + 0];
    float4 y1 = u4[(size_t)r1 * 3 + 1];
    float4 y2 = u4[(size_t)r1 * 3 + 2];
    ADD4(a0, x0); ADD4(a1, x1); ADD4(a2, x2);
    ADD4(c0, y0); ADD4(c1, y1); ADD4(c2, y2);
    e += 2;
  }
  for (; e < dg; e++) {
    int r = rows[st + e];
    float4 x0 = u4[(size_t)r * 3 + 0];
    float4 x1 = u4[(size_t)r * 3 + 1];
    float4 x2 = u4[(size_t)r * 3 + 2];
    ADD4(a0, x0); ADD4(a1, x1); ADD4(a2, x2);
  }
  ADD4(a0, c0); ADD4(a1, c1); ADD4(a2, c2);
  float dv = dinv[i];
  a0.x *= dv; a0.y *= dv; a0.z *= dv; a0.w *= dv;
  a1.x *= dv; a1.y *= dv; a1.z *= dv; a1.w *= dv;
  a2.x *= dv;
  a2.y = 0.f; a2.z = 0.f; a2.w = 0.f;
  float4* ax4 = (float4*)ax;
  ax4[(size_t)i * 3 + 0] = a0;
  ax4[(size_t)i * 3 + 1] = a1;
  ax4[(size_t)i * 3 + 2] = a2;
}

// h1 = lrelu(ax[v][0:9] @ W0 + b0); writes Abuf; accumulates BN stats.
__global__ __launch_bounds__(256) void k_gemm_in(
    const float* __restrict__ ax, const float* __restrict__ W0,
    const float* __restrict__ b0, float* __restrict__ Abuf,
    float* __restrict__ stats, int N) {
  __shared__ float Wl[9 * 128];
  __shared__ float rs[128], rq[128];
  const int t = threadIdx.x;
  for (int i = t; i < 9 * 128; i += 256) Wl[i] = W0[i];
  if (t < 128) { rs[t] = 0.f; rq[t] = 0.f; }
  __syncthreads();
  const int col = t & 127;
  const int rsub = t >> 7;
  const int base = blockIdx.x * 16;
  const float bc = b0[col];
  float ls = 0.f, lq = 0.f;
  for (int it = 0; it < 8; it++) {
    int row = base + it * 2 + rsub;
    if (row < N) {
      const float* ar = ax + (size_t)row * 12;
      float acc = bc;
#pragma unroll
      for (int k = 0; k < 9; k++) acc += ar[k] * Wl[k * 128 + col];
      float a = LRELU(acc);
      Abuf[(size_t)row * 128 + col] = a;
      ls += a;
      lq += a * a;
    }
  }
  atomicAdd(&rs[col], ls);
  atomicAdd(&rq[col], lq);
  __syncthreads();
  if (t < 128) {
    atomicAdd(&stats[t], rs[t]);
    atomicAdd(&stats[128 + t], rq[t]);
  }
}

// L[v][:] = (A[v][:] @ Wf) * dinv[v].  Tile: 32 rows x 128 cols per block.
__global__ __launch_bounds__(256) void k_gemm128(const float* __restrict__ A,
                                                 const float* __restrict__ Wf,
                                                 const float* __restrict__ dinv,
                                                 float* __restrict__ L, int N) {
  __shared__ float Wl[64 * 128];  // 32 KB (K-tile of 64)
  __shared__ float Al[32 * 128];  // 16 KB
  float4* Wl4 = (float4*)Wl;
  float4* Al4 = (float4*)Al;
  const int t = threadIdx.x;
  const int row0 = blockIdx.x * 32;
  const int rows = min(32, N - row0);
  const float4* A4 = (const float4*)(A + (size_t)row0 * 128);
#pragma unroll
  for (int i = 0; i < 4; i++) {
    int idx = t + i * 256;  // 0..1023 covers 32x32 float4
    float4 z = {0.f, 0.f, 0.f, 0.f};
    Al4[idx] = (idx < rows * 32) ? A4[idx] : z;
  }
  const int colq = t & 31;   // 4 cols: 4*colq..+3
  const int rowg = t >> 5;   // 8 groups x 4 rows
  float4 acc[4];
#pragma unroll
  for (int r = 0; r < 4; r++) acc[r] = {0.f, 0.f, 0.f, 0.f};
  const float4* W4 = (const float4*)Wf;
  for (int kt = 0; kt < 128; kt += 64) {
    __syncthreads();
#pragma unroll
    for (int i = 0; i < 8; i++) {
      int idx = t + i * 256;  // 0..2047
      Wl4[idx] = W4[kt * 32 + idx];
    }
    __syncthreads();
#pragma unroll 4
    for (int k = 0; k < 64; k += 4) {
      float4 w0 = Wl4[(k + 0) * 32 + colq];
      float4 w1 = Wl4[(k + 1) * 32 + colq];
      float4 w2 = Wl4[(k + 2) * 32 + colq];
      float4 w3 = Wl4[(k + 3) * 32 + colq];
#pragma unroll
      for (int r = 0; r < 4; r++) {
        float4 av = Al4[(rowg * 4 + r) * 32 + ((kt + k) >> 2)];
        acc[r].x += av.x * w0.x + av.y * w1.x + av.z * w2.x + av.w * w3.x;
        acc[r].y += av.x * w0.y + av.y * w1.y + av.z * w2.y + av.w * w3.y;
        acc[r].z += av.x * w0.z + av.y * w1.z + av.z * w2.z + av.w * w3.z;
        acc[r].w += av.x * w0.w + av.y * w1.w + av.z * w2.w + av.w * w3.w;
      }
    }
  }
#pragma unroll
  for (int r = 0; r < 4; r++) {
    int row = row0 + rowg * 4 + r;
    if (row < N) {
      float dv = dinv[row];
      float4 o = acc[r];
      o.x *= dv; o.y *= dv; o.z *= dv; o.w *= dv;
      ((float4*)L)[(size_t)row * 32 + colq] = o;
    }
  }
}

// SpMM over 128-dim rows. 256 threads = 8 groups x 32 lanes; group owns a node,
// lane q32 owns float4 chunk q32 of the row. float4 gathers, index prefetch.
// MODE 0: a = lrelu(dinv*(self+gather) + q*tw + b); write Aout; BN stats.
// MODE 1: same a, then dot(a, Wout) group-reduced, atomicAdd per-graph pool.
template <int MODE>
__global__ __launch_bounds__(256) void k_spmm(
    const float* __restrict__ L, const int* __restrict__ offs,
    const int* __restrict__ cnt, const int* __restrict__ rows,
    const float* __restrict__ dinv, const float* __restrict__ qv,
    const float* __restrict__ tw, const float* __restrict__ bias,
    float* __restrict__ Aout, float* __restrict__ stats,
    const float* __restrict__ wout, const int* __restrict__ batch,
    float* __restrict__ pacc, int N) {
  const int t = threadIdx.x;
  const int g = t >> 5;
  const int q32 = t & 31;
  const float4* __restrict__ L4 = (const float4*)L;
  const float4 t4 = ((const float4*)tw)[q32];
  const float4 b4 = ((const float4*)bias)[q32];
  float4 wo4 = make_float4(0, 0, 0, 0);
  if (MODE == 1) wo4 = ((const float4*)wout)[q32];
  __shared__ float rs[128], rq[128];
  float4 ls = make_float4(0, 0, 0, 0), lq = make_float4(0, 0, 0, 0);
  if (MODE == 0) {
    if (t < 128) { rs[t] = 0.f; rq[t] = 0.f; }
    __syncthreads();
  }
  const int vbase = blockIdx.x * 16 + g * 2;
  for (int n = 0; n < 2; n++) {
    const int v = vbase + n;
    if (v >= N) break;
    const int st = offs[v];
    const int dg = cnt[v];
    float4 s0 = L4[(size_t)v * 32 + q32];
    float4 s1 = make_float4(0, 0, 0, 0), s2 = s1, s3 = s1;
    int e = 0, r0 = 0, r1 = 0, r2 = 0, r3 = 0;
    if (dg >= 4) {
      r0 = rows[st]; r1 = rows[st + 1]; r2 = rows[st + 2]; r3 = rows[st + 3];
    }
    for (; e + 8 <= dg; e += 4) {
      float4 g0 = L4[(size_t)r0 * 32 + q32];
      float4 g1 = L4[(size_t)r1 * 32 + q32];
      float4 g2 = L4[(size_t)r2 * 32 + q32];
      float4 g3 = L4[(size_t)r3 * 32 + q32];
      r0 = rows[st + e + 4]; r1 = rows[st + e + 5];
      r2 = rows[st + e + 6]; r3 = rows[st + e + 7];
      ADD4(s0, g0); ADD4(s1, g1); ADD4(s2, g2); ADD4(s3, g3);
    }
    if (e + 4 <= dg) {
      float4 g0 = L4[(size_t)r0 * 32 + q32];
      float4 g1 = L4[(size_t)r1 * 32 + q32];
      float4 g2 = L4[(size_t)r2 * 32 + q32];
      float4 g3 = L4[(size_t)r3 * 32 + q32];
      ADD4(s0, g0); ADD4(s1, g1); ADD4(s2, g2); ADD4(s3, g3);
      e += 4;
    }
    for (; e < dg; e++) {
      int r = rows[st + e];
      float4 g0 = L4[(size_t)r * 32 + q32];
      ADD4(s0, g0);
    }
    float4 acc;
    acc.x = (s0.x + s1.x) + (s2.x + s3.x);
    acc.y = (s0.y + s1.y) + (s2.y + s3.y);
    acc.z = (s0.z + s1.z) + (s2.z + s3.z);
    acc.w = (s0.w + s1.w) + (s2.w + s3.w);
    const float dv = dinv[v];
    const float qf = qv[v];
    float4 a;
    a.x = LRELU(dv * acc.x + qf * t4.x + b4.x);
    a.y = LRELU(dv * acc.y + qf * t4.y + b4.y);
    a.z = LRELU(dv * acc.z + qf * t4.z + b4.z);
    a.w = LRELU(dv * acc.w + qf * t4.w + b4.w);
    if (MODE == 0) {
      ((float4*)Aout)[(size_t)v * 32 + q32] = a;
      ls.x += a.x; ls.y += a.y; ls.z += a.z; ls.w += a.w;
      lq.x += a.x * a.x; lq.y += a.y * a.y;
      lq.z += a.z * a.z; lq.w += a.w * a.w;
    } else {
      float s = a.x * wo4.x + a.y * wo4.y + a.z * wo4.z + a.w * wo4.w;
      s += __shfl_down(s, 16, 32);
      s += __shfl_down(s, 8, 32);
      s += __shfl_down(s, 4, 32);
      s += __shfl_down(s, 2, 32);
      s += __shfl_down(s, 1, 32);
      if (q32 == 0) atomicAdd(&pacc[batch[v]], s);
    }
  }
  if (MODE == 0) {
    const int f0 = q32 * 4;
    atomicAdd(&rs[f0 + 0], ls.x); atomicAdd(&rs[f0 + 1], ls.y);
    atomicAdd(&rs[f0 + 2], ls.z); atomicAdd(&rs[f0 + 3], ls.w);
    atomicAdd(&rq[f0 + 0], lq.x); atomicAdd(&rq[f0 + 1], lq.y);
    atomicAdd(&rq[f0 + 2], lq.z); atomicAdd(&rq[f0 + 3], lq.w);
    __syncthreads();
    if (t < 128) {
      atomicAdd(&stats[t], rs[t]);
      atomicAdd(&stats[128 + t], rq[t]);
    }
  }
}

// Fold BN affine (from batch stats of previous activation) into next layer's weights.
__global__ __launch_bounds__(128) void k_fold(const float* __restrict__ stats,
                                              const float* __restrict__ g,
                                              const float* __restrict__ be,
                                              const float* __restrict__ W,
                                              float* __restrict__ Wf,
                                              float* __restrict__ tw, float invN) {
  __shared__ float ss[128], tt[128];
  const int j = threadIdx.x;
  float m = stats[j] * invN;
  float var = stats[128 + j] * invN - m * m;
  float sj = g[j] * rsqrtf(var + 1e-5f);
  ss[j] = sj;
  tt[j] = be[j] - m * sj;
  __syncthreads();
  float acc = 0.f;
  for (int i = 0; i < 128; i++) {
    float w = W[i * 128 + j];
    Wf[i * 128 + j] = ss[i] * w;
    acc += tt[i] * w;
  }
  tw[j] = acc;
}

__global__ __launch_bounds__(256) void k_out(const float* __restrict__ pacc,
                                             const float* __restrict__ cntG,
                                             const float* __restrict__ bout,
                                             float* __restrict__ out, int G) {
  int i = blockIdx.x * 256 + threadIdx.x;
  if (i < G) out[i] = pacc[i] / fmaxf(cntG[i], 1.0f) + bout[0];
}

extern "C" void kernel_launch(void* const* d_in, const int* in_sizes, int n_in,
                              void* d_out, int out_size, void* d_ws, size_t ws_size,
                              hipStream_t stream) {
  const float* x    = (const float*)d_in[0];
  const int*   ei   = (const int*)d_in[1];
  const int*   batch= (const int*)d_in[2];
  const float* W0   = (const float*)d_in[3];
  const float* b0   = (const float*)d_in[4];
  const float* W1   = (const float*)d_in[5];
  const float* b1   = (const float*)d_in[6];
  const float* W2   = (const float*)d_in[7];
  const float* b2   = (const float*)d_in[8];
  const float* W3   = (const float*)d_in[9];
  const float* b3   = (const float*)d_in[10];
  const float* g1   = (const float*)d_in[11];
  const float* be1  = (const float*)d_in[12];
  const float* g2   = (const float*)d_in[13];
  const float* be2  = (const float*)d_in[14];
  const float* g3   = (const float*)d_in[15];
  const float* be3  = (const float*)d_in[16];
  const float* Wout = (const float*)d_in[17];
  const float* bout = (const float*)d_in[18];
  float* out = (float*)d_out;

  const int N = in_sizes[0] / 9;
  const int E = in_sizes[1] / 2;
  const int G = out_size;

  char* w = (char*)d_ws;
  auto alloc = [&](size_t bytes) -> void* {
    void* p = (void*)w;
    w += (bytes + 255) & ~(size_t)255;
    return p;
  };
  int*   cnt    = (int*)alloc((size_t)N * 4);
  int*   cursor = (int*)alloc((size_t)N * 4);
  int*   offs   = (int*)alloc((size_t)N * 4);
  int*   incl   = (int*)alloc((size_t)N * 4);
  int*   bsums  = (int*)alloc(512 * 4);
  int*   bpref  = (int*)alloc(512 * 4);
  float* dinv   = (float*)alloc((size_t)N * 4);
  float* sd     = (float*)alloc((size_t)N * 4);
  float* q      = (float*)alloc((size_t)N * 4);
  int*   rows   = (int*)alloc((size_t)E * 4);
  float* cntG   = (float*)alloc((size_t)G * 4);
  float* pacc   = (float*)alloc((size_t)G * 4);
  float* stats  = (float*)alloc(3 * 256 * 4);
  float* Wf     = (float*)alloc(128 * 128 * 4);
  float* tw     = (float*)alloc(128 * 4);
  float* u      = (float*)alloc((size_t)N * 12 * 4);
  float* ax     = (float*)alloc((size_t)N * 12 * 4);
  float* L      = (float*)alloc((size_t)N * 128 * 4);
  float* Abuf   = (float*)alloc((size_t)N * 128 * 4);

  hipMemsetAsync(cnt,    0, (size_t)N * 4, stream);
  hipMemsetAsync(cursor, 0, (size_t)N * 4, stream);
  hipMemsetAsync(sd,     0, (size_t)N * 4, stream);
  hipMemsetAsync(cntG,   0, (size_t)G * 4, stream);
  hipMemsetAsync(pacc,   0, (size_t)G * 4, stream);
  hipMemsetAsync(stats,  0, 3 * 256 * 4, stream);

  const int eb  = (E + 255) / 256;
  const int nbN = (N + 255) / 256;  // also the scan block count (must be <= 512)
  const int sb  = (N + 15) / 16;    // spmm / gemm_in blocks
  const int gb  = (N + 31) / 32;    // gemm128 blocks
  const float invN = 1.0f / (float)N;

  // --- graph preprocessing ---
  k_count<<<eb, 256, 0, stream>>>(ei, cnt, E);
  k_dinv<<<nbN, 256, 0, stream>>>(cnt, dinv, N);
  k_sd<<<eb, 256, 0, stream>>>(ei, dinv, sd, E);
  k_q<<<nbN, 256, 0, stream>>>(dinv, sd, q, N);
  k_scan1<<<nbN, 256, 0, stream>>>(cnt, incl, bsums, N);
  k_scan2<<<1, 512, 0, stream>>>(bsums, bpref, nbN);
  k_scan3<<<nbN, 256, 0, stream>>>(incl, cnt, bpref, offs, N);
  k_csr<<<eb, 256, 0, stream>>>(ei, offs, cursor, rows, E);
  k_cntg<<<nbN, 256, 0, stream>>>(batch, cntG, N);

  // --- layer 1: aggregate 9-dim input first (A x) @ W0 ---
  k_prep_x<<<nbN, 256, 0, stream>>>(x, dinv, u, N);
  k_spmm9<<<nbN, 256, 0, stream>>>(u, offs, cnt, rows, dinv, ax, N);
  k_gemm_in<<<sb, 256, 0, stream>>>(ax, W0, b0, Abuf, stats, N);
  // --- layer 2 ---
  k_fold<<<1, 128, 0, stream>>>(stats, g1, be1, W1, Wf, tw, invN);
  k_gemm128<<<gb, 256, 0, stream>>>(Abuf, Wf, dinv, L, N);
  k_spmm<0><<<sb, 256, 0, stream>>>(L, offs, cnt, rows, dinv, q, tw, b1,
                                    Abuf, stats + 256, nullptr, nullptr, nullptr, N);
  // --- layer 3 ---
  k_fold<<<1, 128, 0, stream>>>(stats + 256, g2, be2, W2, Wf, tw, invN);
  k_gemm128<<<gb, 256, 0, stream>>>(Abuf, Wf, dinv, L, N);
  k_spmm<0><<<sb, 256, 0, stream>>>(L, offs, cnt, rows, dinv, q, tw, b2,
                                    Abuf, stats + 512, nullptr, nullptr, nullptr, N);
  // --- layer 4 (+ fused pool @ Wout) ---
  k_fold<<<1, 128, 0, stream>>>(stats + 512, g3, be3, W3, Wf, tw, invN);
  k_gemm128<<<gb, 256, 0, stream>>>(Abuf, Wf, dinv, L, N);
  k_spmm<1><<<sb, 256, 0, stream>>>(L, offs, cnt, rows, dinv, q, tw, b3,
                                    Abuf, nullptr, Wout, batch, pacc, N);
  k_out<<<(G + 255) / 256, 256, 0, stream>>>(pacc, cntG, bout, out, G);
}

// Round 3
// 1318.556 us; speedup vs baseline: 1.0882x; 1.0867x over previous
//
#include <hip/hip_runtime.h>

// GCN forward: 4x [GEMM -> symmetric-normalized aggregation -> lrelu -> BN(folded)]
// then mean-pool per graph @ Wout.
//
// Key structure:
//  - CSR built per launch (counting sort): scatter->gather, no big float atomics.
//  - Layer 1 commuted: A(x@W0) = (Ax)@W0 -> gather 48B rows instead of 512B.
//  - dinv folded: linS = (h@W)*dinv[row]; agg[v] = dinv[v]*(linS[v] + sum_in linS[row]).
//  - BN folded into next GEMM: Wf = s[:,None]*W, plus row-constant term t@W entering
//    aggregation as q[v]*(t@W), q[v] = dinv[v]*(dinv[v]+sum_in dinv[row]).
//  - L (gathered buffer) stored as bf16: halves the L2-miss traffic that bounds the
//    SpMM (random 256B-row gather, accumulate fp32). R2 evidence: FETCH 406MB/261us
//    = 1.55 TB/s L2-miss path is the binding constraint, latency structure is not.
//  - Final layer fuses pool: per-node dot(a4,Wout) -> atomicAdd per-graph.

#define LRELU(z) ((z) > 0.f ? (z) : 0.01f * (z))
#define ADD4(d, s) \
  { d.x += s.x; d.y += s.y; d.z += s.z; d.w += s.w; }

__device__ inline unsigned pack_bf16x2(float a, float b) {
  unsigned ua = __float_as_uint(a);
  unsigned ub = __float_as_uint(b);
  ua = (ua + 0x7FFFu + ((ua >> 16) & 1u)) >> 16;
  ub = (ub + 0x7FFFu + ((ub >> 16) & 1u)) >> 16;
  return ua | (ub << 16);
}

// unpack uint2 (4 bf16) -> float4
__device__ inline float4 unpack_bf16x4(uint2 u) {
  float4 r;
  r.x = __uint_as_float(u.x << 16);
  r.y = __uint_as_float(u.x & 0xffff0000u);
  r.z = __uint_as_float(u.y << 16);
  r.w = __uint_as_float(u.y & 0xffff0000u);
  return r;
}

__global__ __launch_bounds__(256) void k_count(const int* __restrict__ ei,
                                               int* __restrict__ cnt, int E) {
  int i = blockIdx.x * 256 + threadIdx.x;
  if (i < E) atomicAdd(&cnt[ei[E + i]], 1);
}

__global__ __launch_bounds__(256) void k_dinv(const int* __restrict__ cnt,
                                              float* __restrict__ dinv, int N) {
  int i = blockIdx.x * 256 + threadIdx.x;
  if (i < N) dinv[i] = rsqrtf((float)(cnt[i] + 1));
}

__global__ __launch_bounds__(256) void k_sd(const int* __restrict__ ei,
                                            const float* __restrict__ dinv,
                                            float* __restrict__ sd, int E) {
  int i = blockIdx.x * 256 + threadIdx.x;
  if (i < E) atomicAdd(&sd[ei[E + i]], dinv[ei[i]]);
}

__global__ __launch_bounds__(256) void k_q(const float* __restrict__ dinv,
                                           const float* __restrict__ sd,
                                           float* __restrict__ q, int N) {
  int i = blockIdx.x * 256 + threadIdx.x;
  if (i < N) q[i] = dinv[i] * (dinv[i] + sd[i]);
}

__global__ __launch_bounds__(256) void k_scan1(const int* __restrict__ cnt,
                                               int* __restrict__ incl,
                                               int* __restrict__ bsums, int N) {
  __shared__ int s[256];
  int tid = threadIdx.x;
  int idx = blockIdx.x * 256 + tid;
  int v = (idx < N) ? cnt[idx] : 0;
  s[tid] = v;
  __syncthreads();
  for (int off = 1; off < 256; off <<= 1) {
    int t = (tid >= off) ? s[tid - off] : 0;
    __syncthreads();
    s[tid] += t;
    __syncthreads();
  }
  if (idx < N) incl[idx] = s[tid];
  if (tid == 255) bsums[blockIdx.x] = s[255];
}

// nb must be <= 512 (N <= 131072 here: nb = 391)
__global__ __launch_bounds__(512) void k_scan2(const int* __restrict__ bsums,
                                               int* __restrict__ bpref, int nb) {
  __shared__ int s[512];
  int tid = threadIdx.x;
  int v = (tid < nb) ? bsums[tid] : 0;
  s[tid] = v;
  __syncthreads();
  for (int off = 1; off < 512; off <<= 1) {
    int t = (tid >= off) ? s[tid - off] : 0;
    __syncthreads();
    s[tid] += t;
    __syncthreads();
  }
  bpref[tid] = s[tid] - v;  // exclusive prefix of block sums
}

__global__ __launch_bounds__(256) void k_scan3(const int* __restrict__ incl,
                                               const int* __restrict__ cnt,
                                               const int* __restrict__ bpref,
                                               int* __restrict__ offs, int N) {
  int idx = blockIdx.x * 256 + threadIdx.x;
  if (idx < N) offs[idx] = incl[idx] - cnt[idx] + bpref[blockIdx.x];
}

__global__ __launch_bounds__(256) void k_csr(const int* __restrict__ ei,
                                             const int* __restrict__ offs,
                                             int* __restrict__ cursor,
                                             int* __restrict__ rows, int E) {
  int i = blockIdx.x * 256 + threadIdx.x;
  if (i < E) {
    int c = ei[E + i];
    int p = offs[c] + atomicAdd(&cursor[c], 1);
    rows[p] = ei[i];
  }
}

__global__ __launch_bounds__(256) void k_cntg(const int* __restrict__ batch,
                                              float* __restrict__ cntG, int N) {
  int i = blockIdx.x * 256 + threadIdx.x;
  if (i < N) atomicAdd(&cntG[batch[i]], 1.0f);
}

// u[v][0:9] = x[v][0:9] * dinv[v], padded to 12 floats
__global__ __launch_bounds__(256) void k_prep_x(const float* __restrict__ x,
                                                const float* __restrict__ dinv,
                                                float* __restrict__ u, int N) {
  int i = blockIdx.x * 256 + threadIdx.x;
  if (i >= N) return;
  float dv = dinv[i];
  const float* xr = x + (size_t)i * 9;
  float4 v0, v1, v2;
  v0.x = xr[0] * dv; v0.y = xr[1] * dv; v0.z = xr[2] * dv; v0.w = xr[3] * dv;
  v1.x = xr[4] * dv; v1.y = xr[5] * dv; v1.z = xr[6] * dv; v1.w = xr[7] * dv;
  v2 = make_float4(xr[8] * dv, 0.f, 0.f, 0.f);
  float4* u4 = (float4*)u;
  u4[(size_t)i * 3 + 0] = v0;
  u4[(size_t)i * 3 + 1] = v1;
  u4[(size_t)i * 3 + 2] = v2;
}

// ax[v] = dinv[v]*(u[v] + sum_in u[row]) over 12-float (padded 9) rows
__global__ __launch_bounds__(256) void k_spmm9(
    const float* __restrict__ u, const int* __restrict__ offs,
    const int* __restrict__ cnt, const int* __restrict__ rows,
    const float* __restrict__ dinv, float* __restrict__ ax, int N) {
  int i = blockIdx.x * 256 + threadIdx.x;
  if (i >= N) return;
  const float4* __restrict__ u4 = (const float4*)u;
  const int st = offs[i];
  const int dg = cnt[i];
  float4 a0 = u4[(size_t)i * 3 + 0];
  float4 a1 = u4[(size_t)i * 3 + 1];
  float4 a2 = u4[(size_t)i * 3 + 2];
  float4 c0 = make_float4(0, 0, 0, 0), c1 = c0, c2 = c0;
  int e = 0, r0 = 0, r1 = 0;
  if (dg >= 2) { r0 = rows[st]; r1 = rows[st + 1]; }
  for (; e + 4 <= dg; e += 2) {
    float4 x0 = u4[(size_t)r0 * 3 + 0];
    float4 x1 = u4[(size_t)r0 * 3 + 1];
    float4 x2 = u4[(size_t)r0 * 3 + 2];
    float4 y0 = u4[(size_t)r1 * 3 + 0];
    float4 y1 = u4[(size_t)r1 * 3 + 1];
    float4 y2 = u4[(size_t)r1 * 3 + 2];
    r0 = rows[st + e + 2];
    r1 = rows[st + e + 3];
    ADD4(a0, x0); ADD4(a1, x1); ADD4(a2, x2);
    ADD4(c0, y0); ADD4(c1, y1); ADD4(c2, y2);
  }
  if (e + 2 <= dg) {
    float4 x0 = u4[(size_t)r0 * 3 + 0];
    float4 x1 = u4[(size_t)r0 * 3 + 1];
    float4 x2 = u4[(size_t)r0 * 3 + 2];
    float4 y0 = u4[(size_t)r1 * 3 + 0];
    float4 y1 = u4[(size_t)r1 * 3 + 1];
    float4 y2 = u4[(size_t)r1 * 3 + 2];
    ADD4(a0, x0); ADD4(a1, x1); ADD4(a2, x2);
    ADD4(c0, y0); ADD4(c1, y1); ADD4(c2, y2);
    e += 2;
  }
  for (; e < dg; e++) {
    int r = rows[st + e];
    float4 x0 = u4[(size_t)r * 3 + 0];
    float4 x1 = u4[(size_t)r * 3 + 1];
    float4 x2 = u4[(size_t)r * 3 + 2];
    ADD4(a0, x0); ADD4(a1, x1); ADD4(a2, x2);
  }
  ADD4(a0, c0); ADD4(a1, c1); ADD4(a2, c2);
  float dv = dinv[i];
  a0.x *= dv; a0.y *= dv; a0.z *= dv; a0.w *= dv;
  a1.x *= dv; a1.y *= dv; a1.z *= dv; a1.w *= dv;
  a2.x *= dv;
  a2.y = 0.f; a2.z = 0.f; a2.w = 0.f;
  float4* ax4 = (float4*)ax;
  ax4[(size_t)i * 3 + 0] = a0;
  ax4[(size_t)i * 3 + 1] = a1;
  ax4[(size_t)i * 3 + 2] = a2;
}

// h1 = lrelu(ax[v][0:9] @ W0 + b0); writes Abuf; accumulates BN stats.
__global__ __launch_bounds__(256) void k_gemm_in(
    const float* __restrict__ ax, const float* __restrict__ W0,
    const float* __restrict__ b0, float* __restrict__ Abuf,
    float* __restrict__ stats, int N) {
  __shared__ float Wl[9 * 128];
  __shared__ float rs[128], rq[128];
  const int t = threadIdx.x;
  for (int i = t; i < 9 * 128; i += 256) Wl[i] = W0[i];
  if (t < 128) { rs[t] = 0.f; rq[t] = 0.f; }
  __syncthreads();
  const int col = t & 127;
  const int rsub = t >> 7;
  const int base = blockIdx.x * 16;
  const float bc = b0[col];
  float ls = 0.f, lq = 0.f;
  for (int it = 0; it < 8; it++) {
    int row = base + it * 2 + rsub;
    if (row < N) {
      const float* ar = ax + (size_t)row * 12;
      float acc = bc;
#pragma unroll
      for (int k = 0; k < 9; k++) acc += ar[k] * Wl[k * 128 + col];
      float a = LRELU(acc);
      Abuf[(size_t)row * 128 + col] = a;
      ls += a;
      lq += a * a;
    }
  }
  atomicAdd(&rs[col], ls);
  atomicAdd(&rq[col], lq);
  __syncthreads();
  if (t < 128) {
    atomicAdd(&stats[t], rs[t]);
    atomicAdd(&stats[128 + t], rq[t]);
  }
}

// L[v][:] = bf16((A[v][:] @ Wf) * dinv[v]).  Tile: 32 rows x 128 cols per block.
__global__ __launch_bounds__(256) void k_gemm128(const float* __restrict__ A,
                                                 const float* __restrict__ Wf,
                                                 const float* __restrict__ dinv,
                                                 unsigned* __restrict__ Lb, int N) {
  __shared__ float Wl[64 * 128];  // 32 KB (K-tile of 64)
  __shared__ float Al[32 * 128];  // 16 KB
  float4* Wl4 = (float4*)Wl;
  float4* Al4 = (float4*)Al;
  const int t = threadIdx.x;
  const int row0 = blockIdx.x * 32;
  const int rows = min(32, N - row0);
  const float4* A4 = (const float4*)(A + (size_t)row0 * 128);
#pragma unroll
  for (int i = 0; i < 4; i++) {
    int idx = t + i * 256;  // 0..1023 covers 32x32 float4
    float4 z = {0.f, 0.f, 0.f, 0.f};
    Al4[idx] = (idx < rows * 32) ? A4[idx] : z;
  }
  const int colq = t & 31;   // 4 cols: 4*colq..+3
  const int rowg = t >> 5;   // 8 groups x 4 rows
  float4 acc[4];
#pragma unroll
  for (int r = 0; r < 4; r++) acc[r] = {0.f, 0.f, 0.f, 0.f};
  const float4* W4 = (const float4*)Wf;
  for (int kt = 0; kt < 128; kt += 64) {
    __syncthreads();
#pragma unroll
    for (int i = 0; i < 8; i++) {
      int idx = t + i * 256;  // 0..2047
      Wl4[idx] = W4[kt * 32 + idx];
    }
    __syncthreads();
#pragma unroll 4
    for (int k = 0; k < 64; k += 4) {
      float4 w0 = Wl4[(k + 0) * 32 + colq];
      float4 w1 = Wl4[(k + 1) * 32 + colq];
      float4 w2 = Wl4[(k + 2) * 32 + colq];
      float4 w3 = Wl4[(k + 3) * 32 + colq];
#pragma unroll
      for (int r = 0; r < 4; r++) {
        float4 av = Al4[(rowg * 4 + r) * 32 + ((kt + k) >> 2)];
        acc[r].x += av.x * w0.x + av.y * w1.x + av.z * w2.x + av.w * w3.x;
        acc[r].y += av.x * w0.y + av.y * w1.y + av.z * w2.y + av.w * w3.y;
        acc[r].z += av.x * w0.z + av.y * w1.z + av.z * w2.z + av.w * w3.z;
        acc[r].w += av.x * w0.w + av.y * w1.w + av.z * w2.w + av.w * w3.w;
      }
    }
  }
#pragma unroll
  for (int r = 0; r < 4; r++) {
    int row = row0 + rowg * 4 + r;
    if (row < N) {
      float dv = dinv[row];
      float4 o = acc[r];
      uint2 p;
      p.x = pack_bf16x2(o.x * dv, o.y * dv);
      p.y = pack_bf16x2(o.z * dv, o.w * dv);
      ((uint2*)Lb)[(size_t)row * 32 + colq] = p;
    }
  }
}

// SpMM over 128-dim bf16 rows (256B). 256 threads = 8 groups x 32 lanes; group owns
// a node, lane q32 owns bf16x4 chunk q32 of the row. fp32 accumulate, index prefetch.
// MODE 0: a = lrelu(dinv*(self+gather) + q*tw + b); write Aout; BN stats.
// MODE 1: same a, then dot(a, Wout) group-reduced, atomicAdd per-graph pool.
template <int MODE>
__global__ __launch_bounds__(256) void k_spmm(
    const unsigned* __restrict__ Lb, const int* __restrict__ offs,
    const int* __restrict__ cnt, const int* __restrict__ rows,
    const float* __restrict__ dinv, const float* __restrict__ qv,
    const float* __restrict__ tw, const float* __restrict__ bias,
    float* __restrict__ Aout, float* __restrict__ stats,
    const float* __restrict__ wout, const int* __restrict__ batch,
    float* __restrict__ pacc, int N) {
  const int t = threadIdx.x;
  const int g = t >> 5;
  const int q32 = t & 31;
  const uint2* __restrict__ L2p = (const uint2*)Lb;
  const float4 t4 = ((const float4*)tw)[q32];
  const float4 b4 = ((const float4*)bias)[q32];
  float4 wo4 = make_float4(0, 0, 0, 0);
  if (MODE == 1) wo4 = ((const float4*)wout)[q32];
  __shared__ float rs[128], rq[128];
  float4 ls = make_float4(0, 0, 0, 0), lq = make_float4(0, 0, 0, 0);
  if (MODE == 0) {
    if (t < 128) { rs[t] = 0.f; rq[t] = 0.f; }
    __syncthreads();
  }
  const int vbase = blockIdx.x * 16 + g * 2;
  for (int n = 0; n < 2; n++) {
    const int v = vbase + n;
    if (v >= N) break;
    const int st = offs[v];
    const int dg = cnt[v];
    float4 s0 = unpack_bf16x4(L2p[(size_t)v * 32 + q32]);
    float4 s1 = make_float4(0, 0, 0, 0), s2 = s1, s3 = s1;
    int e = 0, r0 = 0, r1 = 0, r2 = 0, r3 = 0;
    if (dg >= 4) {
      r0 = rows[st]; r1 = rows[st + 1]; r2 = rows[st + 2]; r3 = rows[st + 3];
    }
    for (; e + 8 <= dg; e += 4) {
      uint2 u0 = L2p[(size_t)r0 * 32 + q32];
      uint2 u1 = L2p[(size_t)r1 * 32 + q32];
      uint2 u2 = L2p[(size_t)r2 * 32 + q32];
      uint2 u3 = L2p[(size_t)r3 * 32 + q32];
      r0 = rows[st + e + 4]; r1 = rows[st + e + 5];
      r2 = rows[st + e + 6]; r3 = rows[st + e + 7];
      float4 g0 = unpack_bf16x4(u0);
      float4 g1 = unpack_bf16x4(u1);
      float4 g2 = unpack_bf16x4(u2);
      float4 g3 = unpack_bf16x4(u3);
      ADD4(s0, g0); ADD4(s1, g1); ADD4(s2, g2); ADD4(s3, g3);
    }
    if (e + 4 <= dg) {
      float4 g0 = unpack_bf16x4(L2p[(size_t)r0 * 32 + q32]);
      float4 g1 = unpack_bf16x4(L2p[(size_t)r1 * 32 + q32]);
      float4 g2 = unpack_bf16x4(L2p[(size_t)r2 * 32 + q32]);
      float4 g3 = unpack_bf16x4(L2p[(size_t)r3 * 32 + q32]);
      ADD4(s0, g0); ADD4(s1, g1); ADD4(s2, g2); ADD4(s3, g3);
      e += 4;
    }
    for (; e < dg; e++) {
      int r = rows[st + e];
      float4 g0 = unpack_bf16x4(L2p[(size_t)r * 32 + q32]);
      ADD4(s0, g0);
    }
    float4 acc;
    acc.x = (s0.x + s1.x) + (s2.x + s3.x);
    acc.y = (s0.y + s1.y) + (s2.y + s3.y);
    acc.z = (s0.z + s1.z) + (s2.z + s3.z);
    acc.w = (s0.w + s1.w) + (s2.w + s3.w);
    const float dv = dinv[v];
    const float qf = qv[v];
    float4 a;
    a.x = LRELU(dv * acc.x + qf * t4.x + b4.x);
    a.y = LRELU(dv * acc.y + qf * t4.y + b4.y);
    a.z = LRELU(dv * acc.z + qf * t4.z + b4.z);
    a.w = LRELU(dv * acc.w + qf * t4.w + b4.w);
    if (MODE == 0) {
      ((float4*)Aout)[(size_t)v * 32 + q32] = a;
      ls.x += a.x; ls.y += a.y; ls.z += a.z; ls.w += a.w;
      lq.x += a.x * a.x; lq.y += a.y * a.y;
      lq.z += a.z * a.z; lq.w += a.w * a.w;
    } else {
      float s = a.x * wo4.x + a.y * wo4.y + a.z * wo4.z + a.w * wo4.w;
      s += __shfl_down(s, 16, 32);
      s += __shfl_down(s, 8, 32);
      s += __shfl_down(s, 4, 32);
      s += __shfl_down(s, 2, 32);
      s += __shfl_down(s, 1, 32);
      if (q32 == 0) atomicAdd(&pacc[batch[v]], s);
    }
  }
  if (MODE == 0) {
    const int f0 = q32 * 4;
    atomicAdd(&rs[f0 + 0], ls.x); atomicAdd(&rs[f0 + 1], ls.y);
    atomicAdd(&rs[f0 + 2], ls.z); atomicAdd(&rs[f0 + 3], ls.w);
    atomicAdd(&rq[f0 + 0], lq.x); atomicAdd(&rq[f0 + 1], lq.y);
    atomicAdd(&rq[f0 + 2], lq.z); atomicAdd(&rq[f0 + 3], lq.w);
    __syncthreads();
    if (t < 128) {
      atomicAdd(&stats[t], rs[t]);
      atomicAdd(&stats[128 + t], rq[t]);
    }
  }
}

// Fold BN affine (from batch stats of previous activation) into next layer's weights.
__global__ __launch_bounds__(128) void k_fold(const float* __restrict__ stats,
                                              const float* __restrict__ g,
                                              const float* __restrict__ be,
                                              const float* __restrict__ W,
                                              float* __restrict__ Wf,
                                              float* __restrict__ tw, float invN) {
  __shared__ float ss[128], tt[128];
  const int j = threadIdx.x;
  float m = stats[j] * invN;
  float var = stats[128 + j] * invN - m * m;
  float sj = g[j] * rsqrtf(var + 1e-5f);
  ss[j] = sj;
  tt[j] = be[j] - m * sj;
  __syncthreads();
  float acc = 0.f;
  for (int i = 0; i < 128; i++) {
    float w = W[i * 128 + j];
    Wf[i * 128 + j] = ss[i] * w;
    acc += tt[i] * w;
  }
  tw[j] = acc;
}

__global__ __launch_bounds__(256) void k_out(const float* __restrict__ pacc,
                                             const float* __restrict__ cntG,
                                             const float* __restrict__ bout,
                                             float* __restrict__ out, int G) {
  int i = blockIdx.x * 256 + threadIdx.x;
  if (i < G) out[i] = pacc[i] / fmaxf(cntG[i], 1.0f) + bout[0];
}

extern "C" void kernel_launch(void* const* d_in, const int* in_sizes, int n_in,
                              void* d_out, int out_size, void* d_ws, size_t ws_size,
                              hipStream_t stream) {
  const float* x    = (const float*)d_in[0];
  const int*   ei   = (const int*)d_in[1];
  const int*   batch= (const int*)d_in[2];
  const float* W0   = (const float*)d_in[3];
  const float* b0   = (const float*)d_in[4];
  const float* W1   = (const float*)d_in[5];
  const float* b1   = (const float*)d_in[6];
  const float* W2   = (const float*)d_in[7];
  const float* b2   = (const float*)d_in[8];
  const float* W3   = (const float*)d_in[9];
  const float* b3   = (const float*)d_in[10];
  const float* g1   = (const float*)d_in[11];
  const float* be1  = (const float*)d_in[12];
  const float* g2   = (const float*)d_in[13];
  const float* be2  = (const float*)d_in[14];
  const float* g3   = (const float*)d_in[15];
  const float* be3  = (const float*)d_in[16];
  const float* Wout = (const float*)d_in[17];
  const float* bout = (const float*)d_in[18];
  float* out = (float*)d_out;

  const int N = in_sizes[0] / 9;
  const int E = in_sizes[1] / 2;
  const int G = out_size;

  char* w = (char*)d_ws;
  auto alloc = [&](size_t bytes) -> void* {
    void* p = (void*)w;
    w += (bytes + 255) & ~(size_t)255;
    return p;
  };
  int*   cnt    = (int*)alloc((size_t)N * 4);
  int*   cursor = (int*)alloc((size_t)N * 4);
  int*   offs   = (int*)alloc((size_t)N * 4);
  int*   incl   = (int*)alloc((size_t)N * 4);
  int*   bsums  = (int*)alloc(512 * 4);
  int*   bpref  = (int*)alloc(512 * 4);
  float* dinv   = (float*)alloc((size_t)N * 4);
  float* sd     = (float*)alloc((size_t)N * 4);
  float* q      = (float*)alloc((size_t)N * 4);
  int*   rows   = (int*)alloc((size_t)E * 4);
  float* cntG   = (float*)alloc((size_t)G * 4);
  float* pacc   = (float*)alloc((size_t)G * 4);
  float* stats  = (float*)alloc(3 * 256 * 4);
  float* Wf     = (float*)alloc(128 * 128 * 4);
  float* tw     = (float*)alloc(128 * 4);
  float* u      = (float*)alloc((size_t)N * 12 * 4);
  float* ax     = (float*)alloc((size_t)N * 12 * 4);
  unsigned* Lb  = (unsigned*)alloc((size_t)N * 128 * 2);  // bf16 rows, 256B each
  float* Abuf   = (float*)alloc((size_t)N * 128 * 4);

  hipMemsetAsync(cnt,    0, (size_t)N * 4, stream);
  hipMemsetAsync(cursor, 0, (size_t)N * 4, stream);
  hipMemsetAsync(sd,     0, (size_t)N * 4, stream);
  hipMemsetAsync(cntG,   0, (size_t)G * 4, stream);
  hipMemsetAsync(pacc,   0, (size_t)G * 4, stream);
  hipMemsetAsync(stats,  0, 3 * 256 * 4, stream);

  const int eb  = (E + 255) / 256;
  const int nbN = (N + 255) / 256;  // also the scan block count (must be <= 512)
  const int sb  = (N + 15) / 16;    // spmm / gemm_in blocks
  const int gb  = (N + 31) / 32;    // gemm128 blocks
  const float invN = 1.0f / (float)N;

  // --- graph preprocessing ---
  k_count<<<eb, 256, 0, stream>>>(ei, cnt, E);
  k_dinv<<<nbN, 256, 0, stream>>>(cnt, dinv, N);
  k_sd<<<eb, 256, 0, stream>>>(ei, dinv, sd, E);
  k_q<<<nbN, 256, 0, stream>>>(dinv, sd, q, N);
  k_scan1<<<nbN, 256, 0, stream>>>(cnt, incl, bsums, N);
  k_scan2<<<1, 512, 0, stream>>>(bsums, bpref, nbN);
  k_scan3<<<nbN, 256, 0, stream>>>(incl, cnt, bpref, offs, N);
  k_csr<<<eb, 256, 0, stream>>>(ei, offs, cursor, rows, E);
  k_cntg<<<nbN, 256, 0, stream>>>(batch, cntG, N);

  // --- layer 1: aggregate 9-dim input first (A x) @ W0 ---
  k_prep_x<<<nbN, 256, 0, stream>>>(x, dinv, u, N);
  k_spmm9<<<nbN, 256, 0, stream>>>(u, offs, cnt, rows, dinv, ax, N);
  k_gemm_in<<<sb, 256, 0, stream>>>(ax, W0, b0, Abuf, stats, N);
  // --- layer 2 ---
  k_fold<<<1, 128, 0, stream>>>(stats, g1, be1, W1, Wf, tw, invN);
  k_gemm128<<<gb, 256, 0, stream>>>(Abuf, Wf, dinv, Lb, N);
  k_spmm<0><<<sb, 256, 0, stream>>>(Lb, offs, cnt, rows, dinv, q, tw, b1,
                                    Abuf, stats + 256, nullptr, nullptr, nullptr, N);
  // --- layer 3 ---
  k_fold<<<1, 128, 0, stream>>>(stats + 256, g2, be2, W2, Wf, tw, invN);
  k_gemm128<<<gb, 256, 0, stream>>>(Abuf, Wf, dinv, Lb, N);
  k_spmm<0><<<sb, 256, 0, stream>>>(Lb, offs, cnt, rows, dinv, q, tw, b2,
                                    Abuf, stats + 512, nullptr, nullptr, nullptr, N);
  // --- layer 4 (+ fused pool @ Wout) ---
  k_fold<<<1, 128, 0, stream>>>(stats + 512, g3, be3, W3, Wf, tw, invN);
  k_gemm128<<<gb, 256, 0, stream>>>(Abuf, Wf, dinv, Lb, N);
  k_spmm<1><<<sb, 256, 0, stream>>>(Lb, offs, cnt, rows, dinv, q, tw, b3,
                                    Abuf, nullptr, Wout, batch, pacc, N);
  k_out<<<(G + 255) / 256, 256, 0, stream>>>(pacc, cntG, bout, out, G);
}

// Round 4
// 1145.536 us; speedup vs baseline: 1.2525x; 1.1510x over previous
//
#include <hip/hip_runtime.h>

// GCN forward: 4x [GEMM -> symmetric-normalized aggregation -> lrelu -> BN(folded)]
// then mean-pool per graph @ Wout.
//
// Key structure:
//  - CSR built per launch (counting sort): scatter->gather, no big float atomics.
//  - Layer 1 commuted: A(x@W0) = (Ax)@W0 -> gather 48B rows instead of 512B.
//  - dinv folded: linS = (h@W)*dinv[row]; agg[v] = dinv[v]*(linS[v] + sum_in linS[row]).
//  - BN folded into next GEMM: Wf = s[:,None]*W, plus row-constant term t@W entering
//    aggregation as q[v]*(t@W), q[v] = dinv[v]*(dinv[v]+sum_in dinv[row]).
//  - L (gathered buffer) bf16; Abuf (activations) bf16; 128x128 layer GEMMs run on
//    bf16 MFMA (16x16x32), weights pre-swizzled into B-fragment order by k_fold.
//    fp32 GEMM was ~140us (LDS-bound vector ALU); MFMA target ~10-15us.
//  - SpMM left identical to R3 (~210us wall under investigation separately).
//  - Final layer fuses pool: per-node dot(a4,Wout) -> atomicAdd per-graph.

#define LRELU(z) ((z) > 0.f ? (z) : 0.01f * (z))
#define ADD4(d, s) \
  { d.x += s.x; d.y += s.y; d.z += s.z; d.w += s.w; }

typedef __attribute__((ext_vector_type(8))) short short8;
typedef __attribute__((ext_vector_type(4))) float float4v;

__device__ inline unsigned bf16_rn(float a) {
  unsigned u = __float_as_uint(a);
  return (u + 0x7FFFu + ((u >> 16) & 1u)) >> 16;
}

__device__ inline unsigned pack_bf16x2(float a, float b) {
  return bf16_rn(a) | (bf16_rn(b) << 16);
}

// unpack uint2 (4 bf16) -> float4
__device__ inline float4 unpack_bf16x4(uint2 u) {
  float4 r;
  r.x = __uint_as_float(u.x << 16);
  r.y = __uint_as_float(u.x & 0xffff0000u);
  r.z = __uint_as_float(u.y << 16);
  r.w = __uint_as_float(u.y & 0xffff0000u);
  return r;
}

__global__ __launch_bounds__(256) void k_count(const int* __restrict__ ei,
                                               int* __restrict__ cnt, int E) {
  int i = blockIdx.x * 256 + threadIdx.x;
  if (i < E) atomicAdd(&cnt[ei[E + i]], 1);
}

__global__ __launch_bounds__(256) void k_dinv(const int* __restrict__ cnt,
                                              float* __restrict__ dinv, int N) {
  int i = blockIdx.x * 256 + threadIdx.x;
  if (i < N) dinv[i] = rsqrtf((float)(cnt[i] + 1));
}

__global__ __launch_bounds__(256) void k_sd(const int* __restrict__ ei,
                                            const float* __restrict__ dinv,
                                            float* __restrict__ sd, int E) {
  int i = blockIdx.x * 256 + threadIdx.x;
  if (i < E) atomicAdd(&sd[ei[E + i]], dinv[ei[i]]);
}

__global__ __launch_bounds__(256) void k_q(const float* __restrict__ dinv,
                                           const float* __restrict__ sd,
                                           float* __restrict__ q, int N) {
  int i = blockIdx.x * 256 + threadIdx.x;
  if (i < N) q[i] = dinv[i] * (dinv[i] + sd[i]);
}

__global__ __launch_bounds__(256) void k_scan1(const int* __restrict__ cnt,
                                               int* __restrict__ incl,
                                               int* __restrict__ bsums, int N) {
  __shared__ int s[256];
  int tid = threadIdx.x;
  int idx = blockIdx.x * 256 + tid;
  int v = (idx < N) ? cnt[idx] : 0;
  s[tid] = v;
  __syncthreads();
  for (int off = 1; off < 256; off <<= 1) {
    int t = (tid >= off) ? s[tid - off] : 0;
    __syncthreads();
    s[tid] += t;
    __syncthreads();
  }
  if (idx < N) incl[idx] = s[tid];
  if (tid == 255) bsums[blockIdx.x] = s[255];
}

// nb must be <= 512 (N <= 131072 here: nb = 391)
__global__ __launch_bounds__(512) void k_scan2(const int* __restrict__ bsums,
                                               int* __restrict__ bpref, int nb) {
  __shared__ int s[512];
  int tid = threadIdx.x;
  int v = (tid < nb) ? bsums[tid] : 0;
  s[tid] = v;
  __syncthreads();
  for (int off = 1; off < 512; off <<= 1) {
    int t = (tid >= off) ? s[tid - off] : 0;
    __syncthreads();
    s[tid] += t;
    __syncthreads();
  }
  bpref[tid] = s[tid] - v;  // exclusive prefix of block sums
}

__global__ __launch_bounds__(256) void k_scan3(const int* __restrict__ incl,
                                               const int* __restrict__ cnt,
                                               const int* __restrict__ bpref,
                                               int* __restrict__ offs, int N) {
  int idx = blockIdx.x * 256 + threadIdx.x;
  if (idx < N) offs[idx] = incl[idx] - cnt[idx] + bpref[blockIdx.x];
}

__global__ __launch_bounds__(256) void k_csr(const int* __restrict__ ei,
                                             const int* __restrict__ offs,
                                             int* __restrict__ cursor,
                                             int* __restrict__ rows, int E) {
  int i = blockIdx.x * 256 + threadIdx.x;
  if (i < E) {
    int c = ei[E + i];
    int p = offs[c] + atomicAdd(&cursor[c], 1);
    rows[p] = ei[i];
  }
}

__global__ __launch_bounds__(256) void k_cntg(const int* __restrict__ batch,
                                              float* __restrict__ cntG, int N) {
  int i = blockIdx.x * 256 + threadIdx.x;
  if (i < N) atomicAdd(&cntG[batch[i]], 1.0f);
}

// u[v][0:9] = x[v][0:9] * dinv[v], padded to 12 floats
__global__ __launch_bounds__(256) void k_prep_x(const float* __restrict__ x,
                                                const float* __restrict__ dinv,
                                                float* __restrict__ u, int N) {
  int i = blockIdx.x * 256 + threadIdx.x;
  if (i >= N) return;
  float dv = dinv[i];
  const float* xr = x + (size_t)i * 9;
  float4 v0, v1, v2;
  v0.x = xr[0] * dv; v0.y = xr[1] * dv; v0.z = xr[2] * dv; v0.w = xr[3] * dv;
  v1.x = xr[4] * dv; v1.y = xr[5] * dv; v1.z = xr[6] * dv; v1.w = xr[7] * dv;
  v2 = make_float4(xr[8] * dv, 0.f, 0.f, 0.f);
  float4* u4 = (float4*)u;
  u4[(size_t)i * 3 + 0] = v0;
  u4[(size_t)i * 3 + 1] = v1;
  u4[(size_t)i * 3 + 2] = v2;
}

// ax[v] = dinv[v]*(u[v] + sum_in u[row]) over 12-float (padded 9) rows
__global__ __launch_bounds__(256) void k_spmm9(
    const float* __restrict__ u, const int* __restrict__ offs,
    const int* __restrict__ cnt, const int* __restrict__ rows,
    const float* __restrict__ dinv, float* __restrict__ ax, int N) {
  int i = blockIdx.x * 256 + threadIdx.x;
  if (i >= N) return;
  const float4* __restrict__ u4 = (const float4*)u;
  const int st = offs[i];
  const int dg = cnt[i];
  float4 a0 = u4[(size_t)i * 3 + 0];
  float4 a1 = u4[(size_t)i * 3 + 1];
  float4 a2 = u4[(size_t)i * 3 + 2];
  float4 c0 = make_float4(0, 0, 0, 0), c1 = c0, c2 = c0;
  int e = 0, r0 = 0, r1 = 0;
  if (dg >= 2) { r0 = rows[st]; r1 = rows[st + 1]; }
  for (; e + 4 <= dg; e += 2) {
    float4 x0 = u4[(size_t)r0 * 3 + 0];
    float4 x1 = u4[(size_t)r0 * 3 + 1];
    float4 x2 = u4[(size_t)r0 * 3 + 2];
    float4 y0 = u4[(size_t)r1 * 3 + 0];
    float4 y1 = u4[(size_t)r1 * 3 + 1];
    float4 y2 = u4[(size_t)r1 * 3 + 2];
    r0 = rows[st + e + 2];
    r1 = rows[st + e + 3];
    ADD4(a0, x0); ADD4(a1, x1); ADD4(a2, x2);
    ADD4(c0, y0); ADD4(c1, y1); ADD4(c2, y2);
  }
  if (e + 2 <= dg) {
    float4 x0 = u4[(size_t)r0 * 3 + 0];
    float4 x1 = u4[(size_t)r0 * 3 + 1];
    float4 x2 = u4[(size_t)r0 * 3 + 2];
    float4 y0 = u4[(size_t)r1 * 3 + 0];
    float4 y1 = u4[(size_t)r1 * 3 + 1];
    float4 y2 = u4[(size_t)r1 * 3 + 2];
    ADD4(a0, x0); ADD4(a1, x1); ADD4(a2, x2);
    ADD4(c0, y0); ADD4(c1, y1); ADD4(c2, y2);
    e += 2;
  }
  for (; e < dg; e++) {
    int r = rows[st + e];
    float4 x0 = u4[(size_t)r * 3 + 0];
    float4 x1 = u4[(size_t)r * 3 + 1];
    float4 x2 = u4[(size_t)r * 3 + 2];
    ADD4(a0, x0); ADD4(a1, x1); ADD4(a2, x2);
  }
  ADD4(a0, c0); ADD4(a1, c1); ADD4(a2, c2);
  float dv = dinv[i];
  a0.x *= dv; a0.y *= dv; a0.z *= dv; a0.w *= dv;
  a1.x *= dv; a1.y *= dv; a1.z *= dv; a1.w *= dv;
  a2.x *= dv;
  a2.y = 0.f; a2.z = 0.f; a2.w = 0.f;
  float4* ax4 = (float4*)ax;
  ax4[(size_t)i * 3 + 0] = a0;
  ax4[(size_t)i * 3 + 1] = a1;
  ax4[(size_t)i * 3 + 2] = a2;
}

// h1 = lrelu(ax[v][0:9] @ W0 + b0); writes Abuf (bf16); accumulates fp32 BN stats.
__global__ __launch_bounds__(256) void k_gemm_in(
    const float* __restrict__ ax, const float* __restrict__ W0,
    const float* __restrict__ b0, unsigned short* __restrict__ Abuf,
    float* __restrict__ stats, int N) {
  __shared__ float Wl[9 * 128];
  __shared__ float rs[128], rq[128];
  const int t = threadIdx.x;
  for (int i = t; i < 9 * 128; i += 256) Wl[i] = W0[i];
  if (t < 128) { rs[t] = 0.f; rq[t] = 0.f; }
  __syncthreads();
  const int col = t & 127;
  const int rsub = t >> 7;
  const int base = blockIdx.x * 16;
  const float bc = b0[col];
  float ls = 0.f, lq = 0.f;
  for (int it = 0; it < 8; it++) {
    int row = base + it * 2 + rsub;
    if (row < N) {
      const float* ar = ax + (size_t)row * 12;
      float acc = bc;
#pragma unroll
      for (int k = 0; k < 9; k++) acc += ar[k] * Wl[k * 128 + col];
      float a = LRELU(acc);
      Abuf[(size_t)row * 128 + col] = (unsigned short)bf16_rn(a);
      ls += a;
      lq += a * a;
    }
  }
  atomicAdd(&rs[col], ls);
  atomicAdd(&rq[col], lq);
  __syncthreads();
  if (t < 128) {
    atomicAdd(&stats[t], rs[t]);
    atomicAdd(&stats[128 + t], rq[t]);
  }
}

// bf16 MFMA GEMM: L[v][:] = bf16((A[v][:] @ Wf) * dinv[v]).
// Block: 64 rows, 4 waves x (16 rows x 128 cols). Wb is pre-swizzled into
// B-fragment order (16x16x32: B[k=quad*8+j][n=lane&15]).
__global__ __launch_bounds__(256) void k_gemm_mfma(
    const unsigned short* __restrict__ Ab, const uint4* __restrict__ Wb,
    const float* __restrict__ dinv, unsigned short* __restrict__ Lb, int N) {
  __shared__ uint4 Bl[2048];               // 32 KB: all B fragments
  __shared__ unsigned short Dl[4 * 2048];  // 16 KB: per-wave D staging
  __shared__ float dvs[64];
  const int t = threadIdx.x;
  const int row0 = blockIdx.x * 64;
#pragma unroll
  for (int i = 0; i < 8; i++) Bl[t + i * 256] = Wb[t + i * 256];
  if (t < 64) {
    int r = row0 + t;
    dvs[t] = (r < N) ? dinv[r] : 0.f;
  }
  __syncthreads();
  const int w = t >> 6;
  const int lane = t & 63;
  const int m = lane & 15;
  const int quad = lane >> 4;
  const int rowA = min(row0 + w * 16 + m, N - 1);
  const uint4* Arow = (const uint4*)(Ab + (size_t)rowA * 128);
  uint4 a[4];
#pragma unroll
  for (int kt = 0; kt < 4; kt++) a[kt] = Arow[kt * 4 + quad];
  float4v acc[8];
#pragma unroll
  for (int nt = 0; nt < 8; nt++) acc[nt] = (float4v)0.0f;
#pragma unroll
  for (int nt = 0; nt < 8; nt++) {
#pragma unroll
    for (int kt = 0; kt < 4; kt++) {
      uint4 b = Bl[((kt * 8 + nt) * 4 + quad) * 16 + m];
      acc[nt] = __builtin_amdgcn_mfma_f32_16x16x32_bf16(
          *(short8*)&a[kt], *(short8*)&b, acc[nt], 0, 0, 0);
    }
  }
  // epilogue: scale by dinv, pack bf16 into LDS, then coalesced 16B stores.
  unsigned short* Dw = Dl + w * 2048;
#pragma unroll
  for (int r = 0; r < 4; r++) {
    float dv = dvs[w * 16 + quad * 4 + r];
#pragma unroll
    for (int nt = 0; nt < 8; nt++) {
      Dw[(quad * 4 + r) * 128 + nt * 16 + m] =
          (unsigned short)bf16_rn(acc[nt][r] * dv);
    }
  }
  __syncthreads();
  const uint4* Dw4 = (const uint4*)Dw;
#pragma unroll
  for (int p = 0; p < 4; p++) {
    int row = row0 + w * 16 + p * 4 + (lane >> 4);
    if (row < N) {
      ((uint4*)(Lb + (size_t)row * 128))[lane & 15] = Dw4[p * 64 + lane];
    }
  }
}

// SpMM over 128-dim bf16 rows (256B). 256 threads = 8 groups x 32 lanes; group owns
// a node, lane q32 owns bf16x4 chunk q32 of the row. fp32 accumulate, index prefetch.
// MODE 0: a = lrelu(dinv*(self+gather) + q*tw + b); write Aout (bf16); BN stats.
// MODE 1: same a, then dot(a, Wout) group-reduced, atomicAdd per-graph pool.
template <int MODE>
__global__ __launch_bounds__(256) void k_spmm(
    const unsigned* __restrict__ Lb, const int* __restrict__ offs,
    const int* __restrict__ cnt, const int* __restrict__ rows,
    const float* __restrict__ dinv, const float* __restrict__ qv,
    const float* __restrict__ tw, const float* __restrict__ bias,
    unsigned short* __restrict__ Aout, float* __restrict__ stats,
    const float* __restrict__ wout, const int* __restrict__ batch,
    float* __restrict__ pacc, int N) {
  const int t = threadIdx.x;
  const int g = t >> 5;
  const int q32 = t & 31;
  const uint2* __restrict__ L2p = (const uint2*)Lb;
  const float4 t4 = ((const float4*)tw)[q32];
  const float4 b4 = ((const float4*)bias)[q32];
  float4 wo4 = make_float4(0, 0, 0, 0);
  if (MODE == 1) wo4 = ((const float4*)wout)[q32];
  __shared__ float rs[128], rq[128];
  float4 ls = make_float4(0, 0, 0, 0), lq = make_float4(0, 0, 0, 0);
  if (MODE == 0) {
    if (t < 128) { rs[t] = 0.f; rq[t] = 0.f; }
    __syncthreads();
  }
  const int vbase = blockIdx.x * 16 + g * 2;
  for (int n = 0; n < 2; n++) {
    const int v = vbase + n;
    if (v >= N) break;
    const int st = offs[v];
    const int dg = cnt[v];
    float4 s0 = unpack_bf16x4(L2p[(size_t)v * 32 + q32]);
    float4 s1 = make_float4(0, 0, 0, 0), s2 = s1, s3 = s1;
    int e = 0, r0 = 0, r1 = 0, r2 = 0, r3 = 0;
    if (dg >= 4) {
      r0 = rows[st]; r1 = rows[st + 1]; r2 = rows[st + 2]; r3 = rows[st + 3];
    }
    for (; e + 8 <= dg; e += 4) {
      uint2 u0 = L2p[(size_t)r0 * 32 + q32];
      uint2 u1 = L2p[(size_t)r1 * 32 + q32];
      uint2 u2 = L2p[(size_t)r2 * 32 + q32];
      uint2 u3 = L2p[(size_t)r3 * 32 + q32];
      r0 = rows[st + e + 4]; r1 = rows[st + e + 5];
      r2 = rows[st + e + 6]; r3 = rows[st + e + 7];
      float4 g0 = unpack_bf16x4(u0);
      float4 g1 = unpack_bf16x4(u1);
      float4 g2 = unpack_bf16x4(u2);
      float4 g3 = unpack_bf16x4(u3);
      ADD4(s0, g0); ADD4(s1, g1); ADD4(s2, g2); ADD4(s3, g3);
    }
    if (e + 4 <= dg) {
      float4 g0 = unpack_bf16x4(L2p[(size_t)r0 * 32 + q32]);
      float4 g1 = unpack_bf16x4(L2p[(size_t)r1 * 32 + q32]);
      float4 g2 = unpack_bf16x4(L2p[(size_t)r2 * 32 + q32]);
      float4 g3 = unpack_bf16x4(L2p[(size_t)r3 * 32 + q32]);
      ADD4(s0, g0); ADD4(s1, g1); ADD4(s2, g2); ADD4(s3, g3);
      e += 4;
    }
    for (; e < dg; e++) {
      int r = rows[st + e];
      float4 g0 = unpack_bf16x4(L2p[(size_t)r * 32 + q32]);
      ADD4(s0, g0);
    }
    float4 acc;
    acc.x = (s0.x + s1.x) + (s2.x + s3.x);
    acc.y = (s0.y + s1.y) + (s2.y + s3.y);
    acc.z = (s0.z + s1.z) + (s2.z + s3.z);
    acc.w = (s0.w + s1.w) + (s2.w + s3.w);
    const float dv = dinv[v];
    const float qf = qv[v];
    float4 a;
    a.x = LRELU(dv * acc.x + qf * t4.x + b4.x);
    a.y = LRELU(dv * acc.y + qf * t4.y + b4.y);
    a.z = LRELU(dv * acc.z + qf * t4.z + b4.z);
    a.w = LRELU(dv * acc.w + qf * t4.w + b4.w);
    if (MODE == 0) {
      uint2 p;
      p.x = pack_bf16x2(a.x, a.y);
      p.y = pack_bf16x2(a.z, a.w);
      ((uint2*)Aout)[(size_t)v * 32 + q32] = p;
      ls.x += a.x; ls.y += a.y; ls.z += a.z; ls.w += a.w;
      lq.x += a.x * a.x; lq.y += a.y * a.y;
      lq.z += a.z * a.z; lq.w += a.w * a.w;
    } else {
      float s = a.x * wo4.x + a.y * wo4.y + a.z * wo4.z + a.w * wo4.w;
      s += __shfl_down(s, 16, 32);
      s += __shfl_down(s, 8, 32);
      s += __shfl_down(s, 4, 32);
      s += __shfl_down(s, 2, 32);
      s += __shfl_down(s, 1, 32);
      if (q32 == 0) atomicAdd(&pacc[batch[v]], s);
    }
  }
  if (MODE == 0) {
    const int f0 = q32 * 4;
    atomicAdd(&rs[f0 + 0], ls.x); atomicAdd(&rs[f0 + 1], ls.y);
    atomicAdd(&rs[f0 + 2], ls.z); atomicAdd(&rs[f0 + 3], ls.w);
    atomicAdd(&rq[f0 + 0], lq.x); atomicAdd(&rq[f0 + 1], lq.y);
    atomicAdd(&rq[f0 + 2], lq.z); atomicAdd(&rq[f0 + 3], lq.w);
    __syncthreads();
    if (t < 128) {
      atomicAdd(&stats[t], rs[t]);
      atomicAdd(&stats[128 + t], rq[t]);
    }
  }
}

// Fold BN affine into next layer's weights; emit bf16 Wb in MFMA B-fragment
// order: elem index ((((kt*8+nt)*4+quad)*16+n)*8+jj), k=kt*32+quad*8+jj, col=nt*16+n.
__global__ __launch_bounds__(128) void k_fold(const float* __restrict__ stats,
                                              const float* __restrict__ g,
                                              const float* __restrict__ be,
                                              const float* __restrict__ W,
                                              unsigned short* __restrict__ Wb,
                                              float* __restrict__ tw, float invN) {
  __shared__ float ss[128], tt[128];
  const int j = threadIdx.x;
  float m = stats[j] * invN;
  float var = stats[128 + j] * invN - m * m;
  float sj = g[j] * rsqrtf(var + 1e-5f);
  ss[j] = sj;
  tt[j] = be[j] - m * sj;
  __syncthreads();
  const int nt = j >> 4;
  const int n = j & 15;
  float acc = 0.f;
  for (int i = 0; i < 128; i++) {
    float w = W[i * 128 + j];
    acc += tt[i] * w;
    int kt = i >> 5, quad = (i >> 3) & 3, jj = i & 7;
    Wb[((((kt * 8 + nt) * 4 + quad) * 16 + n) << 3) + jj] =
        (unsigned short)bf16_rn(ss[i] * w);
  }
  tw[j] = acc;
}

__global__ __launch_bounds__(256) void k_out(const float* __restrict__ pacc,
                                             const float* __restrict__ cntG,
                                             const float* __restrict__ bout,
                                             float* __restrict__ out, int G) {
  int i = blockIdx.x * 256 + threadIdx.x;
  if (i < G) out[i] = pacc[i] / fmaxf(cntG[i], 1.0f) + bout[0];
}

extern "C" void kernel_launch(void* const* d_in, const int* in_sizes, int n_in,
                              void* d_out, int out_size, void* d_ws, size_t ws_size,
                              hipStream_t stream) {
  const float* x    = (const float*)d_in[0];
  const int*   ei   = (const int*)d_in[1];
  const int*   batch= (const int*)d_in[2];
  const float* W0   = (const float*)d_in[3];
  const float* b0   = (const float*)d_in[4];
  const float* W1   = (const float*)d_in[5];
  const float* b1   = (const float*)d_in[6];
  const float* W2   = (const float*)d_in[7];
  const float* b2   = (const float*)d_in[8];
  const float* W3   = (const float*)d_in[9];
  const float* b3   = (const float*)d_in[10];
  const float* g1   = (const float*)d_in[11];
  const float* be1  = (const float*)d_in[12];
  const float* g2   = (const float*)d_in[13];
  const float* be2  = (const float*)d_in[14];
  const float* g3   = (const float*)d_in[15];
  const float* be3  = (const float*)d_in[16];
  const float* Wout = (const float*)d_in[17];
  const float* bout = (const float*)d_in[18];
  float* out = (float*)d_out;

  const int N = in_sizes[0] / 9;
  const int E = in_sizes[1] / 2;
  const int G = out_size;

  char* w = (char*)d_ws;
  auto alloc = [&](size_t bytes) -> void* {
    void* p = (void*)w;
    w += (bytes + 255) & ~(size_t)255;
    return p;
  };
  int*   cnt    = (int*)alloc((size_t)N * 4);
  int*   cursor = (int*)alloc((size_t)N * 4);
  int*   offs   = (int*)alloc((size_t)N * 4);
  int*   incl   = (int*)alloc((size_t)N * 4);
  int*   bsums  = (int*)alloc(512 * 4);
  int*   bpref  = (int*)alloc(512 * 4);
  float* dinv   = (float*)alloc((size_t)N * 4);
  float* sd     = (float*)alloc((size_t)N * 4);
  float* q      = (float*)alloc((size_t)N * 4);
  int*   rows   = (int*)alloc((size_t)E * 4);
  float* cntG   = (float*)alloc((size_t)G * 4);
  float* pacc   = (float*)alloc((size_t)G * 4);
  float* stats  = (float*)alloc(3 * 256 * 4);
  unsigned short* Wb = (unsigned short*)alloc(128 * 128 * 2);  // bf16 B-frag layout
  float* tw     = (float*)alloc(128 * 4);
  float* u      = (float*)alloc((size_t)N * 12 * 4);
  float* ax     = (float*)alloc((size_t)N * 12 * 4);
  unsigned* Lb  = (unsigned*)alloc((size_t)N * 128 * 2);       // bf16 rows, 256B each
  unsigned short* Abuf = (unsigned short*)alloc((size_t)N * 128 * 2);  // bf16 acts

  hipMemsetAsync(cnt,    0, (size_t)N * 4, stream);
  hipMemsetAsync(cursor, 0, (size_t)N * 4, stream);
  hipMemsetAsync(sd,     0, (size_t)N * 4, stream);
  hipMemsetAsync(cntG,   0, (size_t)G * 4, stream);
  hipMemsetAsync(pacc,   0, (size_t)G * 4, stream);
  hipMemsetAsync(stats,  0, 3 * 256 * 4, stream);

  const int eb  = (E + 255) / 256;
  const int nbN = (N + 255) / 256;  // also the scan block count (must be <= 512)
  const int sb  = (N + 15) / 16;    // spmm / gemm_in blocks
  const int mb  = (N + 63) / 64;    // mfma gemm blocks
  const float invN = 1.0f / (float)N;

  // --- graph preprocessing ---
  k_count<<<eb, 256, 0, stream>>>(ei, cnt, E);
  k_dinv<<<nbN, 256, 0, stream>>>(cnt, dinv, N);
  k_sd<<<eb, 256, 0, stream>>>(ei, dinv, sd, E);
  k_q<<<nbN, 256, 0, stream>>>(dinv, sd, q, N);
  k_scan1<<<nbN, 256, 0, stream>>>(cnt, incl, bsums, N);
  k_scan2<<<1, 512, 0, stream>>>(bsums, bpref, nbN);
  k_scan3<<<nbN, 256, 0, stream>>>(incl, cnt, bpref, offs, N);
  k_csr<<<eb, 256, 0, stream>>>(ei, offs, cursor, rows, E);
  k_cntg<<<nbN, 256, 0, stream>>>(batch, cntG, N);

  // --- layer 1: aggregate 9-dim input first (A x) @ W0 ---
  k_prep_x<<<nbN, 256, 0, stream>>>(x, dinv, u, N);
  k_spmm9<<<nbN, 256, 0, stream>>>(u, offs, cnt, rows, dinv, ax, N);
  k_gemm_in<<<sb, 256, 0, stream>>>(ax, W0, b0, Abuf, stats, N);
  // --- layer 2 ---
  k_fold<<<1, 128, 0, stream>>>(stats, g1, be1, W1, Wb, tw, invN);
  k_gemm_mfma<<<mb, 256, 0, stream>>>(Abuf, (const uint4*)Wb, dinv, (unsigned short*)Lb, N);
  k_spmm<0><<<sb, 256, 0, stream>>>(Lb, offs, cnt, rows, dinv, q, tw, b1,
                                    Abuf, stats + 256, nullptr, nullptr, nullptr, N);
  // --- layer 3 ---
  k_fold<<<1, 128, 0, stream>>>(stats + 256, g2, be2, W2, Wb, tw, invN);
  k_gemm_mfma<<<mb, 256, 0, stream>>>(Abuf, (const uint4*)Wb, dinv, (unsigned short*)Lb, N);
  k_spmm<0><<<sb, 256, 0, stream>>>(Lb, offs, cnt, rows, dinv, q, tw, b2,
                                    Abuf, stats + 512, nullptr, nullptr, nullptr, N);
  // --- layer 4 (+ fused pool @ Wout) ---
  k_fold<<<1, 128, 0, stream>>>(stats + 512, g3, be3, W3, Wb, tw, invN);
  k_gemm_mfma<<<mb, 256, 0, stream>>>(Abuf, (const uint4*)Wb, dinv, (unsigned short*)Lb, N);
  k_spmm<1><<<sb, 256, 0, stream>>>(Lb, offs, cnt, rows, dinv, q, tw, b3,
                                    nullptr, nullptr, Wout, batch, pacc, N);
  k_out<<<(G + 255) / 256, 256, 0, stream>>>(pacc, cntG, bout, out, G);
}

// Round 5
// 1045.346 us; speedup vs baseline: 1.3726x; 1.0958x over previous
//
#include <hip/hip_runtime.h>

// GCN forward: 4x [GEMM -> symmetric-normalized aggregation -> lrelu -> BN(folded)]
// then mean-pool per graph @ Wout.
//
// Key structure:
//  - CSR built per launch (counting sort); sd accumulation fused into CSR pass.
//  - Layer 1 commuted: A(x@W0) = (Ax)@W0 -> gather 48B rows instead of 512B.
//  - dinv folded into GEMM epilogue + gather epilogue; BN folded into next GEMM
//    (Wf = s*W bf16 B-frag layout; row-constant t@W enters as q[v]*tw).
//  - Gathers: per-node indices loaded 32-wide in ONE coalesced load, shfl-broadcast,
//    then all gathers issued dependency-free (R4 evidence: 4-deep index-prefetch
//    pipeline = one round trip per 4 edges was the latency bottleneck theory).
//  - L bf16 (256B rows), Abuf bf16; 128x128 GEMMs on bf16 MFMA 16x16x32.
//  - Final layer fuses pool: per-node dot(a,Wout) -> atomicAdd per-graph.

#define LRELU(z) ((z) > 0.f ? (z) : 0.01f * (z))
#define ADD4(d, s) \
  { d.x += s.x; d.y += s.y; d.z += s.z; d.w += s.w; }

typedef __attribute__((ext_vector_type(8))) short short8;
typedef __attribute__((ext_vector_type(4))) float float4v;

__device__ inline unsigned bf16_rn(float a) {
  unsigned u = __float_as_uint(a);
  return (u + 0x7FFFu + ((u >> 16) & 1u)) >> 16;
}

__device__ inline unsigned pack_bf16x2(float a, float b) {
  return bf16_rn(a) | (bf16_rn(b) << 16);
}

__device__ inline float4 unpack_bf16x4(uint2 u) {
  float4 r;
  r.x = __uint_as_float(u.x << 16);
  r.y = __uint_as_float(u.x & 0xffff0000u);
  r.z = __uint_as_float(u.y << 16);
  r.w = __uint_as_float(u.y & 0xffff0000u);
  return r;
}

__global__ __launch_bounds__(256) void k_count(const int* __restrict__ ei,
                                               int* __restrict__ cnt, int E) {
  int i = blockIdx.x * 256 + threadIdx.x;
  if (i < E) atomicAdd(&cnt[ei[E + i]], 1);
}

__global__ __launch_bounds__(256) void k_dinv(const int* __restrict__ cnt,
                                              float* __restrict__ dinv, int N) {
  int i = blockIdx.x * 256 + threadIdx.x;
  if (i < N) dinv[i] = rsqrtf((float)(cnt[i] + 1));
}

__global__ __launch_bounds__(256) void k_q(const float* __restrict__ dinv,
                                           const float* __restrict__ sd,
                                           float* __restrict__ q, int N) {
  int i = blockIdx.x * 256 + threadIdx.x;
  if (i < N) q[i] = dinv[i] * (dinv[i] + sd[i]);
}

__global__ __launch_bounds__(256) void k_scan1(const int* __restrict__ cnt,
                                               int* __restrict__ incl,
                                               int* __restrict__ bsums, int N) {
  __shared__ int s[256];
  int tid = threadIdx.x;
  int idx = blockIdx.x * 256 + tid;
  int v = (idx < N) ? cnt[idx] : 0;
  s[tid] = v;
  __syncthreads();
  for (int off = 1; off < 256; off <<= 1) {
    int t = (tid >= off) ? s[tid - off] : 0;
    __syncthreads();
    s[tid] += t;
    __syncthreads();
  }
  if (idx < N) incl[idx] = s[tid];
  if (tid == 255) bsums[blockIdx.x] = s[255];
}

// nb must be <= 512 (N <= 131072 here: nb = 391)
__global__ __launch_bounds__(512) void k_scan2(const int* __restrict__ bsums,
                                               int* __restrict__ bpref, int nb) {
  __shared__ int s[512];
  int tid = threadIdx.x;
  int v = (tid < nb) ? bsums[tid] : 0;
  s[tid] = v;
  __syncthreads();
  for (int off = 1; off < 512; off <<= 1) {
    int t = (tid >= off) ? s[tid - off] : 0;
    __syncthreads();
    s[tid] += t;
    __syncthreads();
  }
  bpref[tid] = s[tid] - v;  // exclusive prefix of block sums
}

__global__ __launch_bounds__(256) void k_scan3(const int* __restrict__ incl,
                                               const int* __restrict__ cnt,
                                               const int* __restrict__ bpref,
                                               int* __restrict__ offs, int N) {
  int idx = blockIdx.x * 256 + threadIdx.x;
  if (idx < N) offs[idx] = incl[idx] - cnt[idx] + bpref[blockIdx.x];
}

// CSR build + sd accumulation fused (saves one full E pass).
__global__ __launch_bounds__(256) void k_csr_sd(const int* __restrict__ ei,
                                                const int* __restrict__ offs,
                                                int* __restrict__ cursor,
                                                const float* __restrict__ dinv,
                                                int* __restrict__ rows,
                                                float* __restrict__ sd, int E) {
  int i = blockIdx.x * 256 + threadIdx.x;
  if (i < E) {
    int s = ei[i];
    int c = ei[E + i];
    int p = offs[c] + atomicAdd(&cursor[c], 1);
    rows[p] = s;
    atomicAdd(&sd[c], dinv[s]);
  }
}

__global__ __launch_bounds__(256) void k_cntg(const int* __restrict__ batch,
                                              float* __restrict__ cntG, int N) {
  int i = blockIdx.x * 256 + threadIdx.x;
  if (i < N) atomicAdd(&cntG[batch[i]], 1.0f);
}

// u[v][0:9] = x[v][0:9] * dinv[v], padded to 12 floats (padding zeroed)
__global__ __launch_bounds__(256) void k_prep_x(const float* __restrict__ x,
                                                const float* __restrict__ dinv,
                                                float* __restrict__ u, int N) {
  int i = blockIdx.x * 256 + threadIdx.x;
  if (i >= N) return;
  float dv = dinv[i];
  const float* xr = x + (size_t)i * 9;
  float4 v0, v1, v2;
  v0.x = xr[0] * dv; v0.y = xr[1] * dv; v0.z = xr[2] * dv; v0.w = xr[3] * dv;
  v1.x = xr[4] * dv; v1.y = xr[5] * dv; v1.z = xr[6] * dv; v1.w = xr[7] * dv;
  v2 = make_float4(xr[8] * dv, 0.f, 0.f, 0.f);
  float4* u4 = (float4*)u;
  u4[(size_t)i * 3 + 0] = v0;
  u4[(size_t)i * 3 + 1] = v1;
  u4[(size_t)i * 3 + 2] = v2;
}

// ax[v] = dinv[v]*(u[v] + sum_in u[row]) over 12-float (padded 9) rows.
// 16-lane group per node: one coalesced 16-wide index load per batch,
// shfl-broadcast, then dependency-free scalar gathers (lane f = feature f).
__global__ __launch_bounds__(256) void k_spmm9(
    const float* __restrict__ u, const int* __restrict__ offs,
    const int* __restrict__ cnt, const int* __restrict__ rows,
    const float* __restrict__ dinv, float* __restrict__ ax, int N) {
  const int t = threadIdx.x;
  const int g = t >> 4;
  const int f = t & 15;
  const int v = blockIdx.x * 16 + g;
  if (v >= N) return;
  const int st = offs[v];
  const int dg = cnt[v];
  const bool act = (f < 12);
  float a0 = act ? u[(size_t)v * 12 + f] : 0.f;
  float a1 = 0.f, a2 = 0.f, a3 = 0.f;
  for (int b = 0; b < dg; b += 16) {
    int rem = dg - b;
    int idx = 0;
    if (f < rem) idx = rows[st + b + f];
    int mm = rem < 16 ? rem : 16;
    int e = 0;
    for (; e + 8 <= mm; e += 8) {
      int r0 = __shfl(idx, e + 0, 16), r1 = __shfl(idx, e + 1, 16);
      int r2 = __shfl(idx, e + 2, 16), r3 = __shfl(idx, e + 3, 16);
      int r4 = __shfl(idx, e + 4, 16), r5 = __shfl(idx, e + 5, 16);
      int r6 = __shfl(idx, e + 6, 16), r7 = __shfl(idx, e + 7, 16);
      float x0 = 0, x1 = 0, x2 = 0, x3 = 0, x4 = 0, x5 = 0, x6 = 0, x7 = 0;
      if (act) {
        x0 = u[(size_t)r0 * 12 + f]; x1 = u[(size_t)r1 * 12 + f];
        x2 = u[(size_t)r2 * 12 + f]; x3 = u[(size_t)r3 * 12 + f];
        x4 = u[(size_t)r4 * 12 + f]; x5 = u[(size_t)r5 * 12 + f];
        x6 = u[(size_t)r6 * 12 + f]; x7 = u[(size_t)r7 * 12 + f];
      }
      a0 += x0; a1 += x1; a2 += x2; a3 += x3;
      a0 += x4; a1 += x5; a2 += x6; a3 += x7;
    }
    for (; e + 4 <= mm; e += 4) {
      int r0 = __shfl(idx, e + 0, 16), r1 = __shfl(idx, e + 1, 16);
      int r2 = __shfl(idx, e + 2, 16), r3 = __shfl(idx, e + 3, 16);
      float x0 = 0, x1 = 0, x2 = 0, x3 = 0;
      if (act) {
        x0 = u[(size_t)r0 * 12 + f]; x1 = u[(size_t)r1 * 12 + f];
        x2 = u[(size_t)r2 * 12 + f]; x3 = u[(size_t)r3 * 12 + f];
      }
      a0 += x0; a1 += x1; a2 += x2; a3 += x3;
    }
    for (; e < mm; e++) {
      int r = __shfl(idx, e, 16);
      if (act) a0 += u[(size_t)r * 12 + f];
    }
  }
  if (f < 9) ax[(size_t)v * 12 + f] = ((a0 + a1) + (a2 + a3)) * dinv[v];
}

// h1 = lrelu(ax[v][0:9] @ W0 + b0); writes Abuf (bf16); accumulates fp32 BN stats.
__global__ __launch_bounds__(256) void k_gemm_in(
    const float* __restrict__ ax, const float* __restrict__ W0,
    const float* __restrict__ b0, unsigned short* __restrict__ Abuf,
    float* __restrict__ stats, int N) {
  __shared__ float Wl[9 * 128];
  __shared__ float rs[128], rq[128];
  const int t = threadIdx.x;
  for (int i = t; i < 9 * 128; i += 256) Wl[i] = W0[i];
  if (t < 128) { rs[t] = 0.f; rq[t] = 0.f; }
  __syncthreads();
  const int col = t & 127;
  const int rsub = t >> 7;
  const int base = blockIdx.x * 16;
  const float bc = b0[col];
  float ls = 0.f, lq = 0.f;
  for (int it = 0; it < 8; it++) {
    int row = base + it * 2 + rsub;
    if (row < N) {
      const float* ar = ax + (size_t)row * 12;
      float acc = bc;
#pragma unroll
      for (int k = 0; k < 9; k++) acc += ar[k] * Wl[k * 128 + col];
      float a = LRELU(acc);
      Abuf[(size_t)row * 128 + col] = (unsigned short)bf16_rn(a);
      ls += a;
      lq += a * a;
    }
  }
  atomicAdd(&rs[col], ls);
  atomicAdd(&rq[col], lq);
  __syncthreads();
  if (t < 128) {
    atomicAdd(&stats[t], rs[t]);
    atomicAdd(&stats[128 + t], rq[t]);
  }
}

// bf16 MFMA GEMM: L[v][:] = bf16((A[v][:] @ Wf) * dinv[v]).
// Block: 64 rows, 4 waves x (16 rows x 128 cols). Wb pre-swizzled B-frag order.
__global__ __launch_bounds__(256) void k_gemm_mfma(
    const unsigned short* __restrict__ Ab, const uint4* __restrict__ Wb,
    const float* __restrict__ dinv, unsigned short* __restrict__ Lb, int N) {
  __shared__ uint4 Bl[2048];               // 32 KB: all B fragments
  __shared__ unsigned short Dl[4 * 2048];  // 16 KB: per-wave D staging
  __shared__ float dvs[64];
  const int t = threadIdx.x;
  const int row0 = blockIdx.x * 64;
#pragma unroll
  for (int i = 0; i < 8; i++) Bl[t + i * 256] = Wb[t + i * 256];
  if (t < 64) {
    int r = row0 + t;
    dvs[t] = (r < N) ? dinv[r] : 0.f;
  }
  __syncthreads();
  const int w = t >> 6;
  const int lane = t & 63;
  const int m = lane & 15;
  const int quad = lane >> 4;
  const int rowA = min(row0 + w * 16 + m, N - 1);
  const uint4* Arow = (const uint4*)(Ab + (size_t)rowA * 128);
  uint4 a[4];
#pragma unroll
  for (int kt = 0; kt < 4; kt++) a[kt] = Arow[kt * 4 + quad];
  float4v acc[8];
#pragma unroll
  for (int nt = 0; nt < 8; nt++) acc[nt] = (float4v)0.0f;
#pragma unroll
  for (int nt = 0; nt < 8; nt++) {
#pragma unroll
    for (int kt = 0; kt < 4; kt++) {
      uint4 b = Bl[((kt * 8 + nt) * 4 + quad) * 16 + m];
      acc[nt] = __builtin_amdgcn_mfma_f32_16x16x32_bf16(
          *(short8*)&a[kt], *(short8*)&b, acc[nt], 0, 0, 0);
    }
  }
  unsigned short* Dw = Dl + w * 2048;
#pragma unroll
  for (int r = 0; r < 4; r++) {
    float dv = dvs[w * 16 + quad * 4 + r];
#pragma unroll
    for (int nt = 0; nt < 8; nt++) {
      Dw[(quad * 4 + r) * 128 + nt * 16 + m] =
          (unsigned short)bf16_rn(acc[nt][r] * dv);
    }
  }
  __syncthreads();
  const uint4* Dw4 = (const uint4*)Dw;
#pragma unroll
  for (int p = 0; p < 4; p++) {
    int row = row0 + w * 16 + p * 4 + (lane >> 4);
    if (row < N) {
      ((uint4*)(Lb + (size_t)row * 128))[lane & 15] = Dw4[p * 64 + lane];
    }
  }
}

// SpMM over 128-dim bf16 rows (256B). 8 groups x 32 lanes; group owns a node,
// lane q32 owns bf16x4 chunk q32. Indices loaded 32-wide per node and
// shfl-broadcast -> all gathers dependency-free. fp32 accumulate.
// MODE 0: a = lrelu(dinv*(self+gather) + q*tw + b); write Aout (bf16); BN stats.
// MODE 1: same a, then dot(a, Wout) group-reduced, atomicAdd per-graph pool.
template <int MODE>
__global__ __launch_bounds__(256) void k_spmm(
    const unsigned* __restrict__ Lb, const int* __restrict__ offs,
    const int* __restrict__ cnt, const int* __restrict__ rows,
    const float* __restrict__ dinv, const float* __restrict__ qv,
    const float* __restrict__ tw, const float* __restrict__ bias,
    unsigned short* __restrict__ Aout, float* __restrict__ stats,
    const float* __restrict__ wout, const int* __restrict__ batch,
    float* __restrict__ pacc, int N) {
  const int t = threadIdx.x;
  const int g = t >> 5;
  const int q32 = t & 31;
  const uint2* __restrict__ L2p = (const uint2*)Lb;
  const float4 t4 = ((const float4*)tw)[q32];
  const float4 b4 = ((const float4*)bias)[q32];
  float4 wo4 = make_float4(0, 0, 0, 0);
  if (MODE == 1) wo4 = ((const float4*)wout)[q32];
  __shared__ float rs[128], rq[128];
  float4 ls = make_float4(0, 0, 0, 0), lq = make_float4(0, 0, 0, 0);
  if (MODE == 0) {
    if (t < 128) { rs[t] = 0.f; rq[t] = 0.f; }
    __syncthreads();
  }
  const int vbase = blockIdx.x * 16 + g * 2;
  for (int n = 0; n < 2; n++) {
    const int v = vbase + n;
    if (v >= N) break;
    const int st = offs[v];
    const int dg = cnt[v];
    float4 s0 = unpack_bf16x4(L2p[(size_t)v * 32 + q32]);
    float4 s1 = make_float4(0, 0, 0, 0), s2 = s1, s3 = s1;
    for (int b = 0; b < dg; b += 32) {
      int rem = dg - b;
      int idx = 0;
      if (q32 < rem) idx = rows[st + b + q32];
      int mm = rem < 32 ? rem : 32;
      int e = 0;
      for (; e + 8 <= mm; e += 8) {
        int r0 = __shfl(idx, e + 0, 32), r1 = __shfl(idx, e + 1, 32);
        int r2 = __shfl(idx, e + 2, 32), r3 = __shfl(idx, e + 3, 32);
        int r4 = __shfl(idx, e + 4, 32), r5 = __shfl(idx, e + 5, 32);
        int r6 = __shfl(idx, e + 6, 32), r7 = __shfl(idx, e + 7, 32);
        uint2 u0 = L2p[(size_t)r0 * 32 + q32];
        uint2 u1 = L2p[(size_t)r1 * 32 + q32];
        uint2 u2 = L2p[(size_t)r2 * 32 + q32];
        uint2 u3 = L2p[(size_t)r3 * 32 + q32];
        uint2 u4 = L2p[(size_t)r4 * 32 + q32];
        uint2 u5 = L2p[(size_t)r5 * 32 + q32];
        uint2 u6 = L2p[(size_t)r6 * 32 + q32];
        uint2 u7 = L2p[(size_t)r7 * 32 + q32];
        float4 g0 = unpack_bf16x4(u0); ADD4(s0, g0);
        float4 g1 = unpack_bf16x4(u1); ADD4(s1, g1);
        float4 g2 = unpack_bf16x4(u2); ADD4(s2, g2);
        float4 g3 = unpack_bf16x4(u3); ADD4(s3, g3);
        float4 g4 = unpack_bf16x4(u4); ADD4(s0, g4);
        float4 g5 = unpack_bf16x4(u5); ADD4(s1, g5);
        float4 g6 = unpack_bf16x4(u6); ADD4(s2, g6);
        float4 g7 = unpack_bf16x4(u7); ADD4(s3, g7);
      }
      for (; e + 4 <= mm; e += 4) {
        int r0 = __shfl(idx, e + 0, 32), r1 = __shfl(idx, e + 1, 32);
        int r2 = __shfl(idx, e + 2, 32), r3 = __shfl(idx, e + 3, 32);
        uint2 u0 = L2p[(size_t)r0 * 32 + q32];
        uint2 u1 = L2p[(size_t)r1 * 32 + q32];
        uint2 u2 = L2p[(size_t)r2 * 32 + q32];
        uint2 u3 = L2p[(size_t)r3 * 32 + q32];
        float4 g0 = unpack_bf16x4(u0); ADD4(s0, g0);
        float4 g1 = unpack_bf16x4(u1); ADD4(s1, g1);
        float4 g2 = unpack_bf16x4(u2); ADD4(s2, g2);
        float4 g3 = unpack_bf16x4(u3); ADD4(s3, g3);
      }
      for (; e < mm; e++) {
        int r = __shfl(idx, e, 32);
        float4 g0 = unpack_bf16x4(L2p[(size_t)r * 32 + q32]);
        ADD4(s0, g0);
      }
    }
    float4 acc;
    acc.x = (s0.x + s1.x) + (s2.x + s3.x);
    acc.y = (s0.y + s1.y) + (s2.y + s3.y);
    acc.z = (s0.z + s1.z) + (s2.z + s3.z);
    acc.w = (s0.w + s1.w) + (s2.w + s3.w);
    const float dv = dinv[v];
    const float qf = qv[v];
    float4 a;
    a.x = LRELU(dv * acc.x + qf * t4.x + b4.x);
    a.y = LRELU(dv * acc.y + qf * t4.y + b4.y);
    a.z = LRELU(dv * acc.z + qf * t4.z + b4.z);
    a.w = LRELU(dv * acc.w + qf * t4.w + b4.w);
    if (MODE == 0) {
      uint2 p;
      p.x = pack_bf16x2(a.x, a.y);
      p.y = pack_bf16x2(a.z, a.w);
      ((uint2*)Aout)[(size_t)v * 32 + q32] = p;
      ls.x += a.x; ls.y += a.y; ls.z += a.z; ls.w += a.w;
      lq.x += a.x * a.x; lq.y += a.y * a.y;
      lq.z += a.z * a.z; lq.w += a.w * a.w;
    } else {
      float s = a.x * wo4.x + a.y * wo4.y + a.z * wo4.z + a.w * wo4.w;
      s += __shfl_down(s, 16, 32);
      s += __shfl_down(s, 8, 32);
      s += __shfl_down(s, 4, 32);
      s += __shfl_down(s, 2, 32);
      s += __shfl_down(s, 1, 32);
      if (q32 == 0) atomicAdd(&pacc[batch[v]], s);
    }
  }
  if (MODE == 0) {
    const int f0 = q32 * 4;
    atomicAdd(&rs[f0 + 0], ls.x); atomicAdd(&rs[f0 + 1], ls.y);
    atomicAdd(&rs[f0 + 2], ls.z); atomicAdd(&rs[f0 + 3], ls.w);
    atomicAdd(&rq[f0 + 0], lq.x); atomicAdd(&rq[f0 + 1], lq.y);
    atomicAdd(&rq[f0 + 2], lq.z); atomicAdd(&rq[f0 + 3], lq.w);
    __syncthreads();
    if (t < 128) {
      atomicAdd(&stats[t], rs[t]);
      atomicAdd(&stats[128 + t], rq[t]);
    }
  }
}

// Fold BN affine into next layer's weights (parallel: 8 blocks x 16 W-rows).
// Emits bf16 Wb in MFMA B-frag order; tw accumulated atomically (pre-zeroed).
__global__ __launch_bounds__(128) void k_fold(const float* __restrict__ stats,
                                              const float* __restrict__ g,
                                              const float* __restrict__ be,
                                              const float* __restrict__ W,
                                              unsigned short* __restrict__ Wb,
                                              float* __restrict__ tw, float invN) {
  const int j = threadIdx.x;
  const int i0 = blockIdx.x * 16;
  const int nt = j >> 4;
  const int n = j & 15;
  float acc = 0.f;
#pragma unroll
  for (int ii = 0; ii < 16; ii++) {
    int i = i0 + ii;
    float m = stats[i] * invN;
    float var = stats[128 + i] * invN - m * m;
    float si = g[i] * rsqrtf(var + 1e-5f);
    float ti = be[i] - m * si;
    float w = W[i * 128 + j];
    acc += ti * w;
    int kt = i >> 5, quad = (i >> 3) & 3, jj = i & 7;
    Wb[((((kt * 8 + nt) * 4 + quad) * 16 + n) << 3) + jj] =
        (unsigned short)bf16_rn(si * w);
  }
  atomicAdd(&tw[j], acc);
}

__global__ __launch_bounds__(256) void k_out(const float* __restrict__ pacc,
                                             const float* __restrict__ cntG,
                                             const float* __restrict__ bout,
                                             float* __restrict__ out, int G) {
  int i = blockIdx.x * 256 + threadIdx.x;
  if (i < G) out[i] = pacc[i] / fmaxf(cntG[i], 1.0f) + bout[0];
}

extern "C" void kernel_launch(void* const* d_in, const int* in_sizes, int n_in,
                              void* d_out, int out_size, void* d_ws, size_t ws_size,
                              hipStream_t stream) {
  const float* x    = (const float*)d_in[0];
  const int*   ei   = (const int*)d_in[1];
  const int*   batch= (const int*)d_in[2];
  const float* W0   = (const float*)d_in[3];
  const float* b0   = (const float*)d_in[4];
  const float* W1   = (const float*)d_in[5];
  const float* b1   = (const float*)d_in[6];
  const float* W2   = (const float*)d_in[7];
  const float* b2   = (const float*)d_in[8];
  const float* W3   = (const float*)d_in[9];
  const float* b3   = (const float*)d_in[10];
  const float* g1   = (const float*)d_in[11];
  const float* be1  = (const float*)d_in[12];
  const float* g2   = (const float*)d_in[13];
  const float* be2  = (const float*)d_in[14];
  const float* g3   = (const float*)d_in[15];
  const float* be3  = (const float*)d_in[16];
  const float* Wout = (const float*)d_in[17];
  const float* bout = (const float*)d_in[18];
  float* out = (float*)d_out;

  const int N = in_sizes[0] / 9;
  const int E = in_sizes[1] / 2;
  const int G = out_size;

  char* w = (char*)d_ws;
  auto alloc = [&](size_t bytes) -> void* {
    void* p = (void*)w;
    w += (bytes + 255) & ~(size_t)255;
    return p;
  };
  int*   cnt    = (int*)alloc((size_t)N * 4);
  int*   cursor = (int*)alloc((size_t)N * 4);
  int*   offs   = (int*)alloc((size_t)N * 4);
  int*   incl   = (int*)alloc((size_t)N * 4);
  int*   bsums  = (int*)alloc(512 * 4);
  int*   bpref  = (int*)alloc(512 * 4);
  float* dinv   = (float*)alloc((size_t)N * 4);
  float* sd     = (float*)alloc((size_t)N * 4);
  float* q      = (float*)alloc((size_t)N * 4);
  int*   rows   = (int*)alloc((size_t)E * 4);
  float* cntG   = (float*)alloc((size_t)G * 4);
  float* pacc   = (float*)alloc((size_t)G * 4);
  float* stats  = (float*)alloc(3 * 256 * 4);
  float* tw3    = (float*)alloc(3 * 128 * 4);
  unsigned short* Wb = (unsigned short*)alloc(128 * 128 * 2);  // bf16 B-frag layout
  float* u      = (float*)alloc((size_t)N * 12 * 4);
  float* ax     = (float*)alloc((size_t)N * 12 * 4);
  unsigned* Lb  = (unsigned*)alloc((size_t)N * 128 * 2);       // bf16 rows, 256B each
  unsigned short* Abuf = (unsigned short*)alloc((size_t)N * 128 * 2);  // bf16 acts

  hipMemsetAsync(cnt,    0, (size_t)N * 4, stream);
  hipMemsetAsync(cursor, 0, (size_t)N * 4, stream);
  hipMemsetAsync(sd,     0, (size_t)N * 4, stream);
  hipMemsetAsync(cntG,   0, (size_t)G * 4, stream);
  hipMemsetAsync(pacc,   0, (size_t)G * 4, stream);
  hipMemsetAsync(stats,  0, 3 * 256 * 4, stream);
  hipMemsetAsync(tw3,    0, 3 * 128 * 4, stream);

  const int eb  = (E + 255) / 256;
  const int nbN = (N + 255) / 256;  // also the scan block count (must be <= 512)
  const int sb  = (N + 15) / 16;    // spmm / spmm9 / gemm_in blocks
  const int mb  = (N + 63) / 64;    // mfma gemm blocks
  const float invN = 1.0f / (float)N;
  float* twA = tw3;
  float* twB = tw3 + 128;
  float* twC = tw3 + 256;

  // --- graph preprocessing ---
  k_count<<<eb, 256, 0, stream>>>(ei, cnt, E);
  k_dinv<<<nbN, 256, 0, stream>>>(cnt, dinv, N);
  k_scan1<<<nbN, 256, 0, stream>>>(cnt, incl, bsums, N);
  k_scan2<<<1, 512, 0, stream>>>(bsums, bpref, nbN);
  k_scan3<<<nbN, 256, 0, stream>>>(incl, cnt, bpref, offs, N);
  k_csr_sd<<<eb, 256, 0, stream>>>(ei, offs, cursor, dinv, rows, sd, E);
  k_q<<<nbN, 256, 0, stream>>>(dinv, sd, q, N);
  k_cntg<<<nbN, 256, 0, stream>>>(batch, cntG, N);

  // --- layer 1: aggregate 9-dim input first (A x) @ W0 ---
  k_prep_x<<<nbN, 256, 0, stream>>>(x, dinv, u, N);
  k_spmm9<<<sb, 256, 0, stream>>>(u, offs, cnt, rows, dinv, ax, N);
  k_gemm_in<<<sb, 256, 0, stream>>>(ax, W0, b0, Abuf, stats, N);
  // --- layer 2 ---
  k_fold<<<8, 128, 0, stream>>>(stats, g1, be1, W1, Wb, twA, invN);
  k_gemm_mfma<<<mb, 256, 0, stream>>>(Abuf, (const uint4*)Wb, dinv, (unsigned short*)Lb, N);
  k_spmm<0><<<sb, 256, 0, stream>>>(Lb, offs, cnt, rows, dinv, q, twA, b1,
                                    Abuf, stats + 256, nullptr, nullptr, nullptr, N);
  // --- layer 3 ---
  k_fold<<<8, 128, 0, stream>>>(stats + 256, g2, be2, W2, Wb, twB, invN);
  k_gemm_mfma<<<mb, 256, 0, stream>>>(Abuf, (const uint4*)Wb, dinv, (unsigned short*)Lb, N);
  k_spmm<0><<<sb, 256, 0, stream>>>(Lb, offs, cnt, rows, dinv, q, twB, b2,
                                    Abuf, stats + 512, nullptr, nullptr, nullptr, N);
  // --- layer 4 (+ fused pool @ Wout) ---
  k_fold<<<8, 128, 0, stream>>>(stats + 512, g3, be3, W3, Wb, twC, invN);
  k_gemm_mfma<<<mb, 256, 0, stream>>>(Abuf, (const uint4*)Wb, dinv, (unsigned short*)Lb, N);
  k_spmm<1><<<sb, 256, 0, stream>>>(Lb, offs, cnt, rows, dinv, q, twC, b3,
                                    nullptr, nullptr, Wout, batch, pacc, N);
  k_out<<<(G + 255) / 256, 256, 0, stream>>>(pacc, cntG, bout, out, G);
}

// Round 6
// 1034.961 us; speedup vs baseline: 1.3863x; 1.0100x over previous
//
#include <hip/hip_runtime.h>

// GCN forward: 4x [GEMM -> symmetric-normalized aggregation -> lrelu -> BN(folded)]
// then mean-pool per graph @ Wout.
//
// Key structure:
//  - CSR built per launch (counting sort); sd fused into CSR pass.
//  - Layer 1 commuted: A(x@W0) = (Ax)@W0; u stored bf16 (24B rows, 2.4MB ->
//    fully L2-resident per XCD -> spmm9 gathers hit L2).
//  - dinv folded into GEMM/gather epilogues; BN folded into next GEMM.
//  - k_spmm (256B bf16 row gathers) measured at ~2.2 TB/s random-gather wall
//    (R1-R5: 235->185us across 5 structures); left unchanged this round.
//  - Dispatch compaction: dinv in scan1, prep_x in scan3, cntg in q; 1 memset.
//  - Final layer fuses pool: per-node dot(a,Wout) -> atomicAdd per-graph.

#define LRELU(z) ((z) > 0.f ? (z) : 0.01f * (z))
#define ADD4(d, s) \
  { d.x += s.x; d.y += s.y; d.z += s.z; d.w += s.w; }

typedef __attribute__((ext_vector_type(8))) short short8;
typedef __attribute__((ext_vector_type(4))) float float4v;

__device__ inline unsigned bf16_rn(float a) {
  unsigned u = __float_as_uint(a);
  return (u + 0x7FFFu + ((u >> 16) & 1u)) >> 16;
}

__device__ inline unsigned pack_bf16x2(float a, float b) {
  return bf16_rn(a) | (bf16_rn(b) << 16);
}

__device__ inline float bf16f(unsigned short s) {
  return __uint_as_float(((unsigned)s) << 16);
}

__device__ inline float4 unpack_bf16x4(uint2 u) {
  float4 r;
  r.x = __uint_as_float(u.x << 16);
  r.y = __uint_as_float(u.x & 0xffff0000u);
  r.z = __uint_as_float(u.y << 16);
  r.w = __uint_as_float(u.y & 0xffff0000u);
  return r;
}

__global__ __launch_bounds__(256) void k_count(const int* __restrict__ ei,
                                               int* __restrict__ cnt, int E) {
  int i = blockIdx.x * 256 + threadIdx.x;
  if (i < E) atomicAdd(&cnt[ei[E + i]], 1);
}

// block-scan of cnt + dinv computation fused
__global__ __launch_bounds__(256) void k_scan1(const int* __restrict__ cnt,
                                               int* __restrict__ incl,
                                               int* __restrict__ bsums,
                                               float* __restrict__ dinv, int N) {
  __shared__ int s[256];
  int tid = threadIdx.x;
  int idx = blockIdx.x * 256 + tid;
  int v = (idx < N) ? cnt[idx] : 0;
  if (idx < N) dinv[idx] = rsqrtf((float)(v + 1));
  s[tid] = v;
  __syncthreads();
  for (int off = 1; off < 256; off <<= 1) {
    int t = (tid >= off) ? s[tid - off] : 0;
    __syncthreads();
    s[tid] += t;
    __syncthreads();
  }
  if (idx < N) incl[idx] = s[tid];
  if (tid == 255) bsums[blockIdx.x] = s[255];
}

// nb must be <= 512 (N <= 131072 here: nb = 391)
__global__ __launch_bounds__(512) void k_scan2(const int* __restrict__ bsums,
                                               int* __restrict__ bpref, int nb) {
  __shared__ int s[512];
  int tid = threadIdx.x;
  int v = (tid < nb) ? bsums[tid] : 0;
  s[tid] = v;
  __syncthreads();
  for (int off = 1; off < 512; off <<= 1) {
    int t = (tid >= off) ? s[tid - off] : 0;
    __syncthreads();
    s[tid] += t;
    __syncthreads();
  }
  bpref[tid] = s[tid] - v;  // exclusive prefix of block sums
}

// offs computation + u preparation fused: u[v][0:9] = bf16(x[v][0:9]*dinv[v]),
// 12 bf16 slots (24B rows; 2.4MB total -> L2-resident per XCD).
__global__ __launch_bounds__(256) void k_scan3_prep(
    const int* __restrict__ incl, const int* __restrict__ cnt,
    const int* __restrict__ bpref, int* __restrict__ offs,
    const float* __restrict__ x, const float* __restrict__ dinv,
    unsigned* __restrict__ u, int N) {
  int idx = blockIdx.x * 256 + threadIdx.x;
  if (idx >= N) return;
  offs[idx] = incl[idx] - cnt[idx] + bpref[blockIdx.x];
  float dv = dinv[idx];
  const float* xr = x + (size_t)idx * 9;
  unsigned p0 = pack_bf16x2(xr[0] * dv, xr[1] * dv);
  unsigned p1 = pack_bf16x2(xr[2] * dv, xr[3] * dv);
  unsigned p2 = pack_bf16x2(xr[4] * dv, xr[5] * dv);
  unsigned p3 = pack_bf16x2(xr[6] * dv, xr[7] * dv);
  unsigned p4 = pack_bf16x2(xr[8] * dv, 0.f);
  uint2* u2 = (uint2*)u;
  u2[(size_t)idx * 3 + 0] = make_uint2(p0, p1);
  u2[(size_t)idx * 3 + 1] = make_uint2(p2, p3);
  u2[(size_t)idx * 3 + 2] = make_uint2(p4, 0u);
}

// CSR build + sd accumulation fused.
__global__ __launch_bounds__(256) void k_csr_sd(const int* __restrict__ ei,
                                                const int* __restrict__ offs,
                                                int* __restrict__ cursor,
                                                const float* __restrict__ dinv,
                                                int* __restrict__ rows,
                                                float* __restrict__ sd, int E) {
  int i = blockIdx.x * 256 + threadIdx.x;
  if (i < E) {
    int s = ei[i];
    int c = ei[E + i];
    int p = offs[c] + atomicAdd(&cursor[c], 1);
    rows[p] = s;
    atomicAdd(&sd[c], dinv[s]);
  }
}

// q computation + per-graph node count fused.
__global__ __launch_bounds__(256) void k_q_cntg(const float* __restrict__ dinv,
                                                const float* __restrict__ sd,
                                                float* __restrict__ q,
                                                const int* __restrict__ batch,
                                                float* __restrict__ cntG, int N) {
  int i = blockIdx.x * 256 + threadIdx.x;
  if (i < N) {
    q[i] = dinv[i] * (dinv[i] + sd[i]);
    atomicAdd(&cntG[batch[i]], 1.0f);
  }
}

// ax[v] = dinv[v]*(u[v] + sum_in u[row]) over bf16 12-slot (9 used) rows.
// 16-lane group per node: coalesced 16-wide index load, shfl-broadcast,
// dependency-free 2B gathers (lane f<9 = feature f), L2-resident source.
__global__ __launch_bounds__(256) void k_spmm9(
    const unsigned short* __restrict__ u, const int* __restrict__ offs,
    const int* __restrict__ cnt, const int* __restrict__ rows,
    const float* __restrict__ dinv, float* __restrict__ ax, int N) {
  const int t = threadIdx.x;
  const int g = t >> 4;
  const int f = t & 15;
  const int v = blockIdx.x * 16 + g;
  if (v >= N) return;
  const int st = offs[v];
  const int dg = cnt[v];
  const bool act = (f < 9);
  float a0 = act ? bf16f(u[(size_t)v * 12 + f]) : 0.f;
  float a1 = 0.f, a2 = 0.f, a3 = 0.f;
  for (int b = 0; b < dg; b += 16) {
    int rem = dg - b;
    int idx = 0;
    if (f < rem) idx = rows[st + b + f];
    int mm = rem < 16 ? rem : 16;
    int e = 0;
    for (; e + 8 <= mm; e += 8) {
      int r0 = __shfl(idx, e + 0, 16), r1 = __shfl(idx, e + 1, 16);
      int r2 = __shfl(idx, e + 2, 16), r3 = __shfl(idx, e + 3, 16);
      int r4 = __shfl(idx, e + 4, 16), r5 = __shfl(idx, e + 5, 16);
      int r6 = __shfl(idx, e + 6, 16), r7 = __shfl(idx, e + 7, 16);
      float x0 = 0, x1 = 0, x2 = 0, x3 = 0, x4 = 0, x5 = 0, x6 = 0, x7 = 0;
      if (act) {
        x0 = bf16f(u[(size_t)r0 * 12 + f]); x1 = bf16f(u[(size_t)r1 * 12 + f]);
        x2 = bf16f(u[(size_t)r2 * 12 + f]); x3 = bf16f(u[(size_t)r3 * 12 + f]);
        x4 = bf16f(u[(size_t)r4 * 12 + f]); x5 = bf16f(u[(size_t)r5 * 12 + f]);
        x6 = bf16f(u[(size_t)r6 * 12 + f]); x7 = bf16f(u[(size_t)r7 * 12 + f]);
      }
      a0 += x0; a1 += x1; a2 += x2; a3 += x3;
      a0 += x4; a1 += x5; a2 += x6; a3 += x7;
    }
    for (; e + 4 <= mm; e += 4) {
      int r0 = __shfl(idx, e + 0, 16), r1 = __shfl(idx, e + 1, 16);
      int r2 = __shfl(idx, e + 2, 16), r3 = __shfl(idx, e + 3, 16);
      float x0 = 0, x1 = 0, x2 = 0, x3 = 0;
      if (act) {
        x0 = bf16f(u[(size_t)r0 * 12 + f]); x1 = bf16f(u[(size_t)r1 * 12 + f]);
        x2 = bf16f(u[(size_t)r2 * 12 + f]); x3 = bf16f(u[(size_t)r3 * 12 + f]);
      }
      a0 += x0; a1 += x1; a2 += x2; a3 += x3;
    }
    for (; e < mm; e++) {
      int r = __shfl(idx, e, 16);
      if (act) a0 += bf16f(u[(size_t)r * 12 + f]);
    }
  }
  if (f < 9) ax[(size_t)v * 12 + f] = ((a0 + a1) + (a2 + a3)) * dinv[v];
}

// h1 = lrelu(ax[v][0:9] @ W0 + b0); writes Abuf (bf16); accumulates fp32 BN stats.
__global__ __launch_bounds__(256) void k_gemm_in(
    const float* __restrict__ ax, const float* __restrict__ W0,
    const float* __restrict__ b0, unsigned short* __restrict__ Abuf,
    float* __restrict__ stats, int N) {
  __shared__ float Wl[9 * 128];
  __shared__ float rs[128], rq[128];
  const int t = threadIdx.x;
  for (int i = t; i < 9 * 128; i += 256) Wl[i] = W0[i];
  if (t < 128) { rs[t] = 0.f; rq[t] = 0.f; }
  __syncthreads();
  const int col = t & 127;
  const int rsub = t >> 7;
  const int base = blockIdx.x * 16;
  const float bc = b0[col];
  float ls = 0.f, lq = 0.f;
  for (int it = 0; it < 8; it++) {
    int row = base + it * 2 + rsub;
    if (row < N) {
      const float* ar = ax + (size_t)row * 12;
      float acc = bc;
#pragma unroll
      for (int k = 0; k < 9; k++) acc += ar[k] * Wl[k * 128 + col];
      float a = LRELU(acc);
      Abuf[(size_t)row * 128 + col] = (unsigned short)bf16_rn(a);
      ls += a;
      lq += a * a;
    }
  }
  atomicAdd(&rs[col], ls);
  atomicAdd(&rq[col], lq);
  __syncthreads();
  if (t < 128) {
    atomicAdd(&stats[t], rs[t]);
    atomicAdd(&stats[128 + t], rq[t]);
  }
}

// bf16 MFMA GEMM: L[v][:] = bf16((A[v][:] @ Wf) * dinv[v]).
// Block: 64 rows, 4 waves x (16 rows x 128 cols). Wb pre-swizzled B-frag order.
__global__ __launch_bounds__(256) void k_gemm_mfma(
    const unsigned short* __restrict__ Ab, const uint4* __restrict__ Wb,
    const float* __restrict__ dinv, unsigned short* __restrict__ Lb, int N) {
  __shared__ uint4 Bl[2048];               // 32 KB: all B fragments
  __shared__ unsigned short Dl[4 * 2048];  // 16 KB: per-wave D staging
  __shared__ float dvs[64];
  const int t = threadIdx.x;
  const int row0 = blockIdx.x * 64;
#pragma unroll
  for (int i = 0; i < 8; i++) Bl[t + i * 256] = Wb[t + i * 256];
  if (t < 64) {
    int r = row0 + t;
    dvs[t] = (r < N) ? dinv[r] : 0.f;
  }
  __syncthreads();
  const int w = t >> 6;
  const int lane = t & 63;
  const int m = lane & 15;
  const int quad = lane >> 4;
  const int rowA = min(row0 + w * 16 + m, N - 1);
  const uint4* Arow = (const uint4*)(Ab + (size_t)rowA * 128);
  uint4 a[4];
#pragma unroll
  for (int kt = 0; kt < 4; kt++) a[kt] = Arow[kt * 4 + quad];
  float4v acc[8];
#pragma unroll
  for (int nt = 0; nt < 8; nt++) acc[nt] = (float4v)0.0f;
#pragma unroll
  for (int nt = 0; nt < 8; nt++) {
#pragma unroll
    for (int kt = 0; kt < 4; kt++) {
      uint4 b = Bl[((kt * 8 + nt) * 4 + quad) * 16 + m];
      acc[nt] = __builtin_amdgcn_mfma_f32_16x16x32_bf16(
          *(short8*)&a[kt], *(short8*)&b, acc[nt], 0, 0, 0);
    }
  }
  unsigned short* Dw = Dl + w * 2048;
#pragma unroll
  for (int r = 0; r < 4; r++) {
    float dv = dvs[w * 16 + quad * 4 + r];
#pragma unroll
    for (int nt = 0; nt < 8; nt++) {
      Dw[(quad * 4 + r) * 128 + nt * 16 + m] =
          (unsigned short)bf16_rn(acc[nt][r] * dv);
    }
  }
  __syncthreads();
  const uint4* Dw4 = (const uint4*)Dw;
#pragma unroll
  for (int p = 0; p < 4; p++) {
    int row = row0 + w * 16 + p * 4 + (lane >> 4);
    if (row < N) {
      ((uint4*)(Lb + (size_t)row * 128))[lane & 15] = Dw4[p * 64 + lane];
    }
  }
}

// SpMM over 128-dim bf16 rows (256B). 8 groups x 32 lanes; group owns a node,
// lane q32 owns bf16x4 chunk q32. Indices loaded 32-wide, shfl-broadcast,
// gathers dependency-free. fp32 accumulate. (Unchanged from R5 — at the
// ~2.2 TB/s random-gather wall.)
template <int MODE>
__global__ __launch_bounds__(256) void k_spmm(
    const unsigned* __restrict__ Lb, const int* __restrict__ offs,
    const int* __restrict__ cnt, const int* __restrict__ rows,
    const float* __restrict__ dinv, const float* __restrict__ qv,
    const float* __restrict__ tw, const float* __restrict__ bias,
    unsigned short* __restrict__ Aout, float* __restrict__ stats,
    const float* __restrict__ wout, const int* __restrict__ batch,
    float* __restrict__ pacc, int N) {
  const int t = threadIdx.x;
  const int g = t >> 5;
  const int q32 = t & 31;
  const uint2* __restrict__ L2p = (const uint2*)Lb;
  const float4 t4 = ((const float4*)tw)[q32];
  const float4 b4 = ((const float4*)bias)[q32];
  float4 wo4 = make_float4(0, 0, 0, 0);
  if (MODE == 1) wo4 = ((const float4*)wout)[q32];
  __shared__ float rs[128], rq[128];
  float4 ls = make_float4(0, 0, 0, 0), lq = make_float4(0, 0, 0, 0);
  if (MODE == 0) {
    if (t < 128) { rs[t] = 0.f; rq[t] = 0.f; }
    __syncthreads();
  }
  const int vbase = blockIdx.x * 16 + g * 2;
  for (int n = 0; n < 2; n++) {
    const int v = vbase + n;
    if (v >= N) break;
    const int st = offs[v];
    const int dg = cnt[v];
    float4 s0 = unpack_bf16x4(L2p[(size_t)v * 32 + q32]);
    float4 s1 = make_float4(0, 0, 0, 0), s2 = s1, s3 = s1;
    for (int b = 0; b < dg; b += 32) {
      int rem = dg - b;
      int idx = 0;
      if (q32 < rem) idx = rows[st + b + q32];
      int mm = rem < 32 ? rem : 32;
      int e = 0;
      for (; e + 8 <= mm; e += 8) {
        int r0 = __shfl(idx, e + 0, 32), r1 = __shfl(idx, e + 1, 32);
        int r2 = __shfl(idx, e + 2, 32), r3 = __shfl(idx, e + 3, 32);
        int r4 = __shfl(idx, e + 4, 32), r5 = __shfl(idx, e + 5, 32);
        int r6 = __shfl(idx, e + 6, 32), r7 = __shfl(idx, e + 7, 32);
        uint2 u0 = L2p[(size_t)r0 * 32 + q32];
        uint2 u1 = L2p[(size_t)r1 * 32 + q32];
        uint2 u2 = L2p[(size_t)r2 * 32 + q32];
        uint2 u3 = L2p[(size_t)r3 * 32 + q32];
        uint2 u4 = L2p[(size_t)r4 * 32 + q32];
        uint2 u5 = L2p[(size_t)r5 * 32 + q32];
        uint2 u6 = L2p[(size_t)r6 * 32 + q32];
        uint2 u7 = L2p[(size_t)r7 * 32 + q32];
        float4 g0 = unpack_bf16x4(u0); ADD4(s0, g0);
        float4 g1 = unpack_bf16x4(u1); ADD4(s1, g1);
        float4 g2 = unpack_bf16x4(u2); ADD4(s2, g2);
        float4 g3 = unpack_bf16x4(u3); ADD4(s3, g3);
        float4 g4 = unpack_bf16x4(u4); ADD4(s0, g4);
        float4 g5 = unpack_bf16x4(u5); ADD4(s1, g5);
        float4 g6 = unpack_bf16x4(u6); ADD4(s2, g6);
        float4 g7 = unpack_bf16x4(u7); ADD4(s3, g7);
      }
      for (; e + 4 <= mm; e += 4) {
        int r0 = __shfl(idx, e + 0, 32), r1 = __shfl(idx, e + 1, 32);
        int r2 = __shfl(idx, e + 2, 32), r3 = __shfl(idx, e + 3, 32);
        uint2 u0 = L2p[(size_t)r0 * 32 + q32];
        uint2 u1 = L2p[(size_t)r1 * 32 + q32];
        uint2 u2 = L2p[(size_t)r2 * 32 + q32];
        uint2 u3 = L2p[(size_t)r3 * 32 + q32];
        float4 g0 = unpack_bf16x4(u0); ADD4(s0, g0);
        float4 g1 = unpack_bf16x4(u1); ADD4(s1, g1);
        float4 g2 = unpack_bf16x4(u2); ADD4(s2, g2);
        float4 g3 = unpack_bf16x4(u3); ADD4(s3, g3);
      }
      for (; e < mm; e++) {
        int r = __shfl(idx, e, 32);
        float4 g0 = unpack_bf16x4(L2p[(size_t)r * 32 + q32]);
        ADD4(s0, g0);
      }
    }
    float4 acc;
    acc.x = (s0.x + s1.x) + (s2.x + s3.x);
    acc.y = (s0.y + s1.y) + (s2.y + s3.y);
    acc.z = (s0.z + s1.z) + (s2.z + s3.z);
    acc.w = (s0.w + s1.w) + (s2.w + s3.w);
    const float dv = dinv[v];
    const float qf = qv[v];
    float4 a;
    a.x = LRELU(dv * acc.x + qf * t4.x + b4.x);
    a.y = LRELU(dv * acc.y + qf * t4.y + b4.y);
    a.z = LRELU(dv * acc.z + qf * t4.z + b4.z);
    a.w = LRELU(dv * acc.w + qf * t4.w + b4.w);
    if (MODE == 0) {
      uint2 p;
      p.x = pack_bf16x2(a.x, a.y);
      p.y = pack_bf16x2(a.z, a.w);
      ((uint2*)Aout)[(size_t)v * 32 + q32] = p;
      ls.x += a.x; ls.y += a.y; ls.z += a.z; ls.w += a.w;
      lq.x += a.x * a.x; lq.y += a.y * a.y;
      lq.z += a.z * a.z; lq.w += a.w * a.w;
    } else {
      float s = a.x * wo4.x + a.y * wo4.y + a.z * wo4.z + a.w * wo4.w;
      s += __shfl_down(s, 16, 32);
      s += __shfl_down(s, 8, 32);
      s += __shfl_down(s, 4, 32);
      s += __shfl_down(s, 2, 32);
      s += __shfl_down(s, 1, 32);
      if (q32 == 0) atomicAdd(&pacc[batch[v]], s);
    }
  }
  if (MODE == 0) {
    const int f0 = q32 * 4;
    atomicAdd(&rs[f0 + 0], ls.x); atomicAdd(&rs[f0 + 1], ls.y);
    atomicAdd(&rs[f0 + 2], ls.z); atomicAdd(&rs[f0 + 3], ls.w);
    atomicAdd(&rq[f0 + 0], lq.x); atomicAdd(&rq[f0 + 1], lq.y);
    atomicAdd(&rq[f0 + 2], lq.z); atomicAdd(&rq[f0 + 3], lq.w);
    __syncthreads();
    if (t < 128) {
      atomicAdd(&stats[t], rs[t]);
      atomicAdd(&stats[128 + t], rq[t]);
    }
  }
}

// Fold BN affine into next layer's weights (parallel: 8 blocks x 16 W-rows).
// Emits bf16 Wb in MFMA B-frag order; tw accumulated atomically (pre-zeroed).
__global__ __launch_bounds__(128) void k_fold(const float* __restrict__ stats,
                                              const float* __restrict__ g,
                                              const float* __restrict__ be,
                                              const float* __restrict__ W,
                                              unsigned short* __restrict__ Wb,
                                              float* __restrict__ tw, float invN) {
  const int j = threadIdx.x;
  const int i0 = blockIdx.x * 16;
  const int nt = j >> 4;
  const int n = j & 15;
  float acc = 0.f;
#pragma unroll
  for (int ii = 0; ii < 16; ii++) {
    int i = i0 + ii;
    float m = stats[i] * invN;
    float var = stats[128 + i] * invN - m * m;
    float si = g[i] * rsqrtf(var + 1e-5f);
    float ti = be[i] - m * si;
    float w = W[i * 128 + j];
    acc += ti * w;
    int kt = i >> 5, quad = (i >> 3) & 3, jj = i & 7;
    Wb[((((kt * 8 + nt) * 4 + quad) * 16 + n) << 3) + jj] =
        (unsigned short)bf16_rn(si * w);
  }
  atomicAdd(&tw[j], acc);
}

__global__ __launch_bounds__(256) void k_out(const float* __restrict__ pacc,
                                             const float* __restrict__ cntG,
                                             const float* __restrict__ bout,
                                             float* __restrict__ out, int G) {
  int i = blockIdx.x * 256 + threadIdx.x;
  if (i < G) out[i] = pacc[i] / fmaxf(cntG[i], 1.0f) + bout[0];
}

extern "C" void kernel_launch(void* const* d_in, const int* in_sizes, int n_in,
                              void* d_out, int out_size, void* d_ws, size_t ws_size,
                              hipStream_t stream) {
  const float* x    = (const float*)d_in[0];
  const int*   ei   = (const int*)d_in[1];
  const int*   batch= (const int*)d_in[2];
  const float* W0   = (const float*)d_in[3];
  const float* b0   = (const float*)d_in[4];
  const float* W1   = (const float*)d_in[5];
  const float* b1   = (const float*)d_in[6];
  const float* W2   = (const float*)d_in[7];
  const float* b2   = (const float*)d_in[8];
  const float* W3   = (const float*)d_in[9];
  const float* b3   = (const float*)d_in[10];
  const float* g1   = (const float*)d_in[11];
  const float* be1  = (const float*)d_in[12];
  const float* g2   = (const float*)d_in[13];
  const float* be2  = (const float*)d_in[14];
  const float* g3   = (const float*)d_in[15];
  const float* be3  = (const float*)d_in[16];
  const float* Wout = (const float*)d_in[17];
  const float* bout = (const float*)d_in[18];
  float* out = (float*)d_out;

  const int N = in_sizes[0] / 9;
  const int E = in_sizes[1] / 2;
  const int G = out_size;

  char* w = (char*)d_ws;
  auto alloc = [&](size_t bytes) -> void* {
    void* p = (void*)w;
    w += (bytes + 255) & ~(size_t)255;
    return p;
  };
  // ---- zeroed region (ONE memset) ----
  char* zbase = w;
  int*   cnt    = (int*)alloc((size_t)N * 4);
  int*   cursor = (int*)alloc((size_t)N * 4);
  float* sd     = (float*)alloc((size_t)N * 4);
  float* cntG   = (float*)alloc((size_t)G * 4);
  float* pacc   = (float*)alloc((size_t)G * 4);
  float* stats  = (float*)alloc(3 * 256 * 4);
  float* tw3    = (float*)alloc(3 * 128 * 4);
  size_t zsize = (size_t)(w - zbase);
  // ---- non-zeroed ----
  int*   offs   = (int*)alloc((size_t)N * 4);
  int*   incl   = (int*)alloc((size_t)N * 4);
  int*   bsums  = (int*)alloc(512 * 4);
  int*   bpref  = (int*)alloc(512 * 4);
  float* dinv   = (float*)alloc((size_t)N * 4);
  float* q      = (float*)alloc((size_t)N * 4);
  int*   rows   = (int*)alloc((size_t)E * 4);
  unsigned short* Wb = (unsigned short*)alloc(128 * 128 * 2);  // bf16 B-frag layout
  unsigned* u   = (unsigned*)alloc((size_t)N * 12 * 2);        // bf16, 24B rows
  float* ax     = (float*)alloc((size_t)N * 12 * 4);
  unsigned* Lb  = (unsigned*)alloc((size_t)N * 128 * 2);       // bf16 rows, 256B
  unsigned short* Abuf = (unsigned short*)alloc((size_t)N * 128 * 2);  // bf16 acts

  hipMemsetAsync(zbase, 0, zsize, stream);

  const int eb  = (E + 255) / 256;
  const int nbN = (N + 255) / 256;  // also the scan block count (must be <= 512)
  const int sb  = (N + 15) / 16;    // spmm / spmm9 / gemm_in blocks
  const int mb  = (N + 63) / 64;    // mfma gemm blocks
  const float invN = 1.0f / (float)N;
  float* twA = tw3;
  float* twB = tw3 + 128;
  float* twC = tw3 + 256;

  // --- graph preprocessing ---
  k_count<<<eb, 256, 0, stream>>>(ei, cnt, E);
  k_scan1<<<nbN, 256, 0, stream>>>(cnt, incl, bsums, dinv, N);
  k_scan2<<<1, 512, 0, stream>>>(bsums, bpref, nbN);
  k_scan3_prep<<<nbN, 256, 0, stream>>>(incl, cnt, bpref, offs, x, dinv, u, N);
  k_csr_sd<<<eb, 256, 0, stream>>>(ei, offs, cursor, dinv, rows, sd, E);
  k_q_cntg<<<nbN, 256, 0, stream>>>(dinv, sd, q, batch, cntG, N);

  // --- layer 1: aggregate 9-dim input first (A x) @ W0 ---
  k_spmm9<<<sb, 256, 0, stream>>>((const unsigned short*)u, offs, cnt, rows,
                                  dinv, ax, N);
  k_gemm_in<<<sb, 256, 0, stream>>>(ax, W0, b0, Abuf, stats, N);
  // --- layer 2 ---
  k_fold<<<8, 128, 0, stream>>>(stats, g1, be1, W1, Wb, twA, invN);
  k_gemm_mfma<<<mb, 256, 0, stream>>>(Abuf, (const uint4*)Wb, dinv, (unsigned short*)Lb, N);
  k_spmm<0><<<sb, 256, 0, stream>>>(Lb, offs, cnt, rows, dinv, q, twA, b1,
                                    Abuf, stats + 256, nullptr, nullptr, nullptr, N);
  // --- layer 3 ---
  k_fold<<<8, 128, 0, stream>>>(stats + 256, g2, be2, W2, Wb, twB, invN);
  k_gemm_mfma<<<mb, 256, 0, stream>>>(Abuf, (const uint4*)Wb, dinv, (unsigned short*)Lb, N);
  k_spmm<0><<<sb, 256, 0, stream>>>(Lb, offs, cnt, rows, dinv, q, twB, b2,
                                    Abuf, stats + 512, nullptr, nullptr, nullptr, N);
  // --- layer 4 (+ fused pool @ Wout) ---
  k_fold<<<8, 128, 0, stream>>>(stats + 512, g3, be3, W3, Wb, twC, invN);
  k_gemm_mfma<<<mb, 256, 0, stream>>>(Abuf, (const uint4*)Wb, dinv, (unsigned short*)Lb, N);
  k_spmm<1><<<sb, 256, 0, stream>>>(Lb, offs, cnt, rows, dinv, q, twC, b3,
                                    nullptr, nullptr, Wout, batch, pacc, N);
  k_out<<<(G + 255) / 256, 256, 0, stream>>>(pacc, cntG, bout, out, G);
}

// Round 7
// 996.575 us; speedup vs baseline: 1.4397x; 1.0385x over previous
//
#include <hip/hip_runtime.h>

// GCN forward: 4x [GEMM -> symmetric-normalized aggregation -> lrelu -> BN(folded)]
// then mean-pool per graph @ Wout.
//
// Key structure:
//  - CSR built per launch (counting sort).
//  - Layer 1 commuted: A(x@W0) = (Ax)@W0; u bf16 24B rows (slot 9 = bf16(dinv) so
//    spmm9's idle lane 9 computes sd -> q for free; no sd atomics, no q kernel).
//  - dinv folded into GEMM/gather epilogues; BN folded into next GEMM.
//  - Gathers use NON-TEMPORAL loads: R2-R6 established per-L2-line cost 25-39 cy
//    invariant to bytes/ILP -> L1 MSHR-limit theory; nt bypasses L1 allocation.
//  - L bf16 (256B rows), Abuf bf16; 128x128 GEMMs on bf16 MFMA 16x16x32.
//  - Final layer fuses pool: per-node dot(a,Wout) -> atomicAdd per-graph.

#define LRELU(z) ((z) > 0.f ? (z) : 0.01f * (z))
#define ADD4(d, s) \
  { d.x += s.x; d.y += s.y; d.z += s.z; d.w += s.w; }

typedef __attribute__((ext_vector_type(8))) short short8;
typedef __attribute__((ext_vector_type(4))) float float4v;

__device__ inline unsigned bf16_rn(float a) {
  unsigned u = __float_as_uint(a);
  return (u + 0x7FFFu + ((u >> 16) & 1u)) >> 16;
}

__device__ inline unsigned pack_bf16x2(float a, float b) {
  return bf16_rn(a) | (bf16_rn(b) << 16);
}

__device__ inline float bf16f(unsigned short s) {
  return __uint_as_float(((unsigned)s) << 16);
}

__device__ inline float4 unpack_bf16x4(uint2 u) {
  float4 r;
  r.x = __uint_as_float(u.x << 16);
  r.y = __uint_as_float(u.x & 0xffff0000u);
  r.z = __uint_as_float(u.y << 16);
  r.w = __uint_as_float(u.y & 0xffff0000u);
  return r;
}

// non-temporal 8B gather (bypasses L1 allocation)
__device__ inline uint2 ntload_u2(const uint2* p) {
  unsigned long long v =
      __builtin_nontemporal_load((const unsigned long long*)p);
  uint2 r;
  r.x = (unsigned)v;
  r.y = (unsigned)(v >> 32);
  return r;
}

__device__ inline unsigned short ntload_us(const unsigned short* p) {
  return __builtin_nontemporal_load(p);
}

__global__ __launch_bounds__(256) void k_count(const int* __restrict__ ei,
                                               int* __restrict__ cnt, int E) {
  int i = blockIdx.x * 256 + threadIdx.x;
  if (i < E) atomicAdd(&cnt[ei[E + i]], 1);
}

// block-scan of cnt + dinv + per-graph node count fused
__global__ __launch_bounds__(256) void k_scan1(const int* __restrict__ cnt,
                                               int* __restrict__ incl,
                                               int* __restrict__ bsums,
                                               float* __restrict__ dinv,
                                               const int* __restrict__ batch,
                                               float* __restrict__ cntG, int N) {
  __shared__ int s[256];
  int tid = threadIdx.x;
  int idx = blockIdx.x * 256 + tid;
  int v = (idx < N) ? cnt[idx] : 0;
  if (idx < N) {
    dinv[idx] = rsqrtf((float)(v + 1));
    atomicAdd(&cntG[batch[idx]], 1.0f);
  }
  s[tid] = v;
  __syncthreads();
  for (int off = 1; off < 256; off <<= 1) {
    int t = (tid >= off) ? s[tid - off] : 0;
    __syncthreads();
    s[tid] += t;
    __syncthreads();
  }
  if (idx < N) incl[idx] = s[tid];
  if (tid == 255) bsums[blockIdx.x] = s[255];
}

// nb must be <= 512 (N <= 131072 here: nb = 391)
__global__ __launch_bounds__(512) void k_scan2(const int* __restrict__ bsums,
                                               int* __restrict__ bpref, int nb) {
  __shared__ int s[512];
  int tid = threadIdx.x;
  int v = (tid < nb) ? bsums[tid] : 0;
  s[tid] = v;
  __syncthreads();
  for (int off = 1; off < 512; off <<= 1) {
    int t = (tid >= off) ? s[tid - off] : 0;
    __syncthreads();
    s[tid] += t;
    __syncthreads();
  }
  bpref[tid] = s[tid] - v;  // exclusive prefix of block sums
}

// offs computation + u preparation fused: u[v][0:9] = bf16(x[v][0:9]*dinv[v]),
// slot 9 = bf16(dinv[v]) (for spmm9's lane-9 sd gather), slots 10,11 = 0.
// 24B rows; 2.4MB total.
__global__ __launch_bounds__(256) void k_scan3_prep(
    const int* __restrict__ incl, const int* __restrict__ cnt,
    const int* __restrict__ bpref, int* __restrict__ offs,
    const float* __restrict__ x, const float* __restrict__ dinv,
    unsigned* __restrict__ u, int N) {
  int idx = blockIdx.x * 256 + threadIdx.x;
  if (idx >= N) return;
  offs[idx] = incl[idx] - cnt[idx] + bpref[blockIdx.x];
  float dv = dinv[idx];
  const float* xr = x + (size_t)idx * 9;
  unsigned p0 = pack_bf16x2(xr[0] * dv, xr[1] * dv);
  unsigned p1 = pack_bf16x2(xr[2] * dv, xr[3] * dv);
  unsigned p2 = pack_bf16x2(xr[4] * dv, xr[5] * dv);
  unsigned p3 = pack_bf16x2(xr[6] * dv, xr[7] * dv);
  unsigned p4 = pack_bf16x2(xr[8] * dv, dv);
  uint2* u2 = (uint2*)u;
  u2[(size_t)idx * 3 + 0] = make_uint2(p0, p1);
  u2[(size_t)idx * 3 + 1] = make_uint2(p2, p3);
  u2[(size_t)idx * 3 + 2] = make_uint2(p4, 0u);
}

// CSR build (counting sort placement).
__global__ __launch_bounds__(256) void k_csr(const int* __restrict__ ei,
                                             const int* __restrict__ offs,
                                             int* __restrict__ cursor,
                                             int* __restrict__ rows, int E) {
  int i = blockIdx.x * 256 + threadIdx.x;
  if (i < E) {
    int c = ei[E + i];
    int p = offs[c] + atomicAdd(&cursor[c], 1);
    rows[p] = ei[i];
  }
}

// ax[v] = dinv[v]*(u[v] + sum_in u[row]) over bf16 rows; lane 9 accumulates
// sum_in dinv[row] (u slot 9) and emits q[v] = dinv*(dinv+sd).
// 16-lane group per node: coalesced 16-wide index load, shfl-broadcast,
// dependency-free nt 2B gathers.
__global__ __launch_bounds__(256) void k_spmm9(
    const unsigned short* __restrict__ u, const int* __restrict__ offs,
    const int* __restrict__ cnt, const int* __restrict__ rows,
    const float* __restrict__ dinv, float* __restrict__ ax,
    float* __restrict__ q, int N) {
  const int t = threadIdx.x;
  const int g = t >> 4;
  const int f = t & 15;
  const int v = blockIdx.x * 16 + g;
  if (v >= N) return;
  const int st = offs[v];
  const int dg = cnt[v];
  const bool act = (f < 10);
  float a0 = (f < 9) ? bf16f(u[(size_t)v * 12 + f]) : 0.f;
  float a1 = 0.f, a2 = 0.f, a3 = 0.f;
  for (int b = 0; b < dg; b += 16) {
    int rem = dg - b;
    int idx = 0;
    if (f < rem) idx = rows[st + b + f];
    int mm = rem < 16 ? rem : 16;
    int e = 0;
    for (; e + 8 <= mm; e += 8) {
      int r0 = __shfl(idx, e + 0, 16), r1 = __shfl(idx, e + 1, 16);
      int r2 = __shfl(idx, e + 2, 16), r3 = __shfl(idx, e + 3, 16);
      int r4 = __shfl(idx, e + 4, 16), r5 = __shfl(idx, e + 5, 16);
      int r6 = __shfl(idx, e + 6, 16), r7 = __shfl(idx, e + 7, 16);
      float x0 = 0, x1 = 0, x2 = 0, x3 = 0, x4 = 0, x5 = 0, x6 = 0, x7 = 0;
      if (act) {
        x0 = bf16f(ntload_us(u + (size_t)r0 * 12 + f));
        x1 = bf16f(ntload_us(u + (size_t)r1 * 12 + f));
        x2 = bf16f(ntload_us(u + (size_t)r2 * 12 + f));
        x3 = bf16f(ntload_us(u + (size_t)r3 * 12 + f));
        x4 = bf16f(ntload_us(u + (size_t)r4 * 12 + f));
        x5 = bf16f(ntload_us(u + (size_t)r5 * 12 + f));
        x6 = bf16f(ntload_us(u + (size_t)r6 * 12 + f));
        x7 = bf16f(ntload_us(u + (size_t)r7 * 12 + f));
      }
      a0 += x0; a1 += x1; a2 += x2; a3 += x3;
      a0 += x4; a1 += x5; a2 += x6; a3 += x7;
    }
    for (; e + 4 <= mm; e += 4) {
      int r0 = __shfl(idx, e + 0, 16), r1 = __shfl(idx, e + 1, 16);
      int r2 = __shfl(idx, e + 2, 16), r3 = __shfl(idx, e + 3, 16);
      float x0 = 0, x1 = 0, x2 = 0, x3 = 0;
      if (act) {
        x0 = bf16f(ntload_us(u + (size_t)r0 * 12 + f));
        x1 = bf16f(ntload_us(u + (size_t)r1 * 12 + f));
        x2 = bf16f(ntload_us(u + (size_t)r2 * 12 + f));
        x3 = bf16f(ntload_us(u + (size_t)r3 * 12 + f));
      }
      a0 += x0; a1 += x1; a2 += x2; a3 += x3;
    }
    for (; e < mm; e++) {
      int r = __shfl(idx, e, 16);
      if (act) a0 += bf16f(ntload_us(u + (size_t)r * 12 + f));
    }
  }
  float sum = (a0 + a1) + (a2 + a3);
  if (f < 9) {
    ax[(size_t)v * 12 + f] = sum * dinv[v];
  } else if (f == 9) {
    float dv = dinv[v];
    q[v] = dv * (dv + sum);
  }
}

// h1 = lrelu(ax[v][0:9] @ W0 + b0); writes Abuf (bf16); accumulates fp32 BN stats.
__global__ __launch_bounds__(256) void k_gemm_in(
    const float* __restrict__ ax, const float* __restrict__ W0,
    const float* __restrict__ b0, unsigned short* __restrict__ Abuf,
    float* __restrict__ stats, int N) {
  __shared__ float Wl[9 * 128];
  __shared__ float rs[128], rq[128];
  const int t = threadIdx.x;
  for (int i = t; i < 9 * 128; i += 256) Wl[i] = W0[i];
  if (t < 128) { rs[t] = 0.f; rq[t] = 0.f; }
  __syncthreads();
  const int col = t & 127;
  const int rsub = t >> 7;
  const int base = blockIdx.x * 16;
  const float bc = b0[col];
  float ls = 0.f, lq = 0.f;
  for (int it = 0; it < 8; it++) {
    int row = base + it * 2 + rsub;
    if (row < N) {
      const float* ar = ax + (size_t)row * 12;
      float acc = bc;
#pragma unroll
      for (int k = 0; k < 9; k++) acc += ar[k] * Wl[k * 128 + col];
      float a = LRELU(acc);
      Abuf[(size_t)row * 128 + col] = (unsigned short)bf16_rn(a);
      ls += a;
      lq += a * a;
    }
  }
  atomicAdd(&rs[col], ls);
  atomicAdd(&rq[col], lq);
  __syncthreads();
  if (t < 128) {
    atomicAdd(&stats[t], rs[t]);
    atomicAdd(&stats[128 + t], rq[t]);
  }
}

// bf16 MFMA GEMM: L[v][:] = bf16((A[v][:] @ Wf) * dinv[v]).
// Block: 64 rows, 4 waves x (16 rows x 128 cols). Wb pre-swizzled B-frag order.
__global__ __launch_bounds__(256) void k_gemm_mfma(
    const unsigned short* __restrict__ Ab, const uint4* __restrict__ Wb,
    const float* __restrict__ dinv, unsigned short* __restrict__ Lb, int N) {
  __shared__ uint4 Bl[2048];               // 32 KB: all B fragments
  __shared__ unsigned short Dl[4 * 2048];  // 16 KB: per-wave D staging
  __shared__ float dvs[64];
  const int t = threadIdx.x;
  const int row0 = blockIdx.x * 64;
#pragma unroll
  for (int i = 0; i < 8; i++) Bl[t + i * 256] = Wb[t + i * 256];
  if (t < 64) {
    int r = row0 + t;
    dvs[t] = (r < N) ? dinv[r] : 0.f;
  }
  __syncthreads();
  const int w = t >> 6;
  const int lane = t & 63;
  const int m = lane & 15;
  const int quad = lane >> 4;
  const int rowA = min(row0 + w * 16 + m, N - 1);
  const uint4* Arow = (const uint4*)(Ab + (size_t)rowA * 128);
  uint4 a[4];
#pragma unroll
  for (int kt = 0; kt < 4; kt++) a[kt] = Arow[kt * 4 + quad];
  float4v acc[8];
#pragma unroll
  for (int nt = 0; nt < 8; nt++) acc[nt] = (float4v)0.0f;
#pragma unroll
  for (int nt = 0; nt < 8; nt++) {
#pragma unroll
    for (int kt = 0; kt < 4; kt++) {
      uint4 b = Bl[((kt * 8 + nt) * 4 + quad) * 16 + m];
      acc[nt] = __builtin_amdgcn_mfma_f32_16x16x32_bf16(
          *(short8*)&a[kt], *(short8*)&b, acc[nt], 0, 0, 0);
    }
  }
  unsigned short* Dw = Dl + w * 2048;
#pragma unroll
  for (int r = 0; r < 4; r++) {
    float dv = dvs[w * 16 + quad * 4 + r];
#pragma unroll
    for (int nt = 0; nt < 8; nt++) {
      Dw[(quad * 4 + r) * 128 + nt * 16 + m] =
          (unsigned short)bf16_rn(acc[nt][r] * dv);
    }
  }
  __syncthreads();
  const uint4* Dw4 = (const uint4*)Dw;
#pragma unroll
  for (int p = 0; p < 4; p++) {
    int row = row0 + w * 16 + p * 4 + (lane >> 4);
    if (row < N) {
      ((uint4*)(Lb + (size_t)row * 128))[lane & 15] = Dw4[p * 64 + lane];
    }
  }
}

// SpMM over 128-dim bf16 rows (256B). 8 groups x 32 lanes; group owns a node,
// lane q32 owns bf16x4 chunk q32. Indices loaded 32-wide, shfl-broadcast,
// gathers dependency-free + NON-TEMPORAL (L1 bypass). fp32 accumulate.
// MODE 0: a = lrelu(dinv*(self+gather) + q*tw + b); write Aout (bf16); BN stats.
// MODE 1: same a, then dot(a, Wout) group-reduced, atomicAdd per-graph pool.
template <int MODE>
__global__ __launch_bounds__(256) void k_spmm(
    const unsigned* __restrict__ Lb, const int* __restrict__ offs,
    const int* __restrict__ cnt, const int* __restrict__ rows,
    const float* __restrict__ dinv, const float* __restrict__ qv,
    const float* __restrict__ tw, const float* __restrict__ bias,
    unsigned short* __restrict__ Aout, float* __restrict__ stats,
    const float* __restrict__ wout, const int* __restrict__ batch,
    float* __restrict__ pacc, int N) {
  const int t = threadIdx.x;
  const int g = t >> 5;
  const int q32 = t & 31;
  const uint2* __restrict__ L2p = (const uint2*)Lb;
  const float4 t4 = ((const float4*)tw)[q32];
  const float4 b4 = ((const float4*)bias)[q32];
  float4 wo4 = make_float4(0, 0, 0, 0);
  if (MODE == 1) wo4 = ((const float4*)wout)[q32];
  __shared__ float rs[128], rq[128];
  float4 ls = make_float4(0, 0, 0, 0), lq = make_float4(0, 0, 0, 0);
  if (MODE == 0) {
    if (t < 128) { rs[t] = 0.f; rq[t] = 0.f; }
    __syncthreads();
  }
  const int vbase = blockIdx.x * 16 + g * 2;
  for (int n = 0; n < 2; n++) {
    const int v = vbase + n;
    if (v >= N) break;
    const int st = offs[v];
    const int dg = cnt[v];
    float4 s0 = unpack_bf16x4(L2p[(size_t)v * 32 + q32]);
    float4 s1 = make_float4(0, 0, 0, 0), s2 = s1, s3 = s1;
    for (int b = 0; b < dg; b += 32) {
      int rem = dg - b;
      int idx = 0;
      if (q32 < rem) idx = rows[st + b + q32];
      int mm = rem < 32 ? rem : 32;
      int e = 0;
      for (; e + 8 <= mm; e += 8) {
        int r0 = __shfl(idx, e + 0, 32), r1 = __shfl(idx, e + 1, 32);
        int r2 = __shfl(idx, e + 2, 32), r3 = __shfl(idx, e + 3, 32);
        int r4 = __shfl(idx, e + 4, 32), r5 = __shfl(idx, e + 5, 32);
        int r6 = __shfl(idx, e + 6, 32), r7 = __shfl(idx, e + 7, 32);
        uint2 u0 = ntload_u2(L2p + (size_t)r0 * 32 + q32);
        uint2 u1 = ntload_u2(L2p + (size_t)r1 * 32 + q32);
        uint2 u2 = ntload_u2(L2p + (size_t)r2 * 32 + q32);
        uint2 u3 = ntload_u2(L2p + (size_t)r3 * 32 + q32);
        uint2 u4 = ntload_u2(L2p + (size_t)r4 * 32 + q32);
        uint2 u5 = ntload_u2(L2p + (size_t)r5 * 32 + q32);
        uint2 u6 = ntload_u2(L2p + (size_t)r6 * 32 + q32);
        uint2 u7 = ntload_u2(L2p + (size_t)r7 * 32 + q32);
        float4 g0 = unpack_bf16x4(u0); ADD4(s0, g0);
        float4 g1 = unpack_bf16x4(u1); ADD4(s1, g1);
        float4 g2 = unpack_bf16x4(u2); ADD4(s2, g2);
        float4 g3 = unpack_bf16x4(u3); ADD4(s3, g3);
        float4 g4 = unpack_bf16x4(u4); ADD4(s0, g4);
        float4 g5 = unpack_bf16x4(u5); ADD4(s1, g5);
        float4 g6 = unpack_bf16x4(u6); ADD4(s2, g6);
        float4 g7 = unpack_bf16x4(u7); ADD4(s3, g7);
      }
      for (; e + 4 <= mm; e += 4) {
        int r0 = __shfl(idx, e + 0, 32), r1 = __shfl(idx, e + 1, 32);
        int r2 = __shfl(idx, e + 2, 32), r3 = __shfl(idx, e + 3, 32);
        uint2 u0 = ntload_u2(L2p + (size_t)r0 * 32 + q32);
        uint2 u1 = ntload_u2(L2p + (size_t)r1 * 32 + q32);
        uint2 u2 = ntload_u2(L2p + (size_t)r2 * 32 + q32);
        uint2 u3 = ntload_u2(L2p + (size_t)r3 * 32 + q32);
        float4 g0 = unpack_bf16x4(u0); ADD4(s0, g0);
        float4 g1 = unpack_bf16x4(u1); ADD4(s1, g1);
        float4 g2 = unpack_bf16x4(u2); ADD4(s2, g2);
        float4 g3 = unpack_bf16x4(u3); ADD4(s3, g3);
      }
      for (; e < mm; e++) {
        int r = __shfl(idx, e, 32);
        float4 g0 = unpack_bf16x4(ntload_u2(L2p + (size_t)r * 32 + q32));
        ADD4(s0, g0);
      }
    }
    float4 acc;
    acc.x = (s0.x + s1.x) + (s2.x + s3.x);
    acc.y = (s0.y + s1.y) + (s2.y + s3.y);
    acc.z = (s0.z + s1.z) + (s2.z + s3.z);
    acc.w = (s0.w + s1.w) + (s2.w + s3.w);
    const float dv = dinv[v];
    const float qf = qv[v];
    float4 a;
    a.x = LRELU(dv * acc.x + qf * t4.x + b4.x);
    a.y = LRELU(dv * acc.y + qf * t4.y + b4.y);
    a.z = LRELU(dv * acc.z + qf * t4.z + b4.z);
    a.w = LRELU(dv * acc.w + qf * t4.w + b4.w);
    if (MODE == 0) {
      uint2 p;
      p.x = pack_bf16x2(a.x, a.y);
      p.y = pack_bf16x2(a.z, a.w);
      ((uint2*)Aout)[(size_t)v * 32 + q32] = p;
      ls.x += a.x; ls.y += a.y; ls.z += a.z; ls.w += a.w;
      lq.x += a.x * a.x; lq.y += a.y * a.y;
      lq.z += a.z * a.z; lq.w += a.w * a.w;
    } else {
      float s = a.x * wo4.x + a.y * wo4.y + a.z * wo4.z + a.w * wo4.w;
      s += __shfl_down(s, 16, 32);
      s += __shfl_down(s, 8, 32);
      s += __shfl_down(s, 4, 32);
      s += __shfl_down(s, 2, 32);
      s += __shfl_down(s, 1, 32);
      if (q32 == 0) atomicAdd(&pacc[batch[v]], s);
    }
  }
  if (MODE == 0) {
    const int f0 = q32 * 4;
    atomicAdd(&rs[f0 + 0], ls.x); atomicAdd(&rs[f0 + 1], ls.y);
    atomicAdd(&rs[f0 + 2], ls.z); atomicAdd(&rs[f0 + 3], ls.w);
    atomicAdd(&rq[f0 + 0], lq.x); atomicAdd(&rq[f0 + 1], lq.y);
    atomicAdd(&rq[f0 + 2], lq.z); atomicAdd(&rq[f0 + 3], lq.w);
    __syncthreads();
    if (t < 128) {
      atomicAdd(&stats[t], rs[t]);
      atomicAdd(&stats[128 + t], rq[t]);
    }
  }
}

// Fold BN affine into next layer's weights (parallel: 8 blocks x 16 W-rows).
// Emits bf16 Wb in MFMA B-frag order; tw accumulated atomically (pre-zeroed).
__global__ __launch_bounds__(128) void k_fold(const float* __restrict__ stats,
                                              const float* __restrict__ g,
                                              const float* __restrict__ be,
                                              const float* __restrict__ W,
                                              unsigned short* __restrict__ Wb,
                                              float* __restrict__ tw, float invN) {
  const int j = threadIdx.x;
  const int i0 = blockIdx.x * 16;
  const int nt = j >> 4;
  const int n = j & 15;
  float acc = 0.f;
#pragma unroll
  for (int ii = 0; ii < 16; ii++) {
    int i = i0 + ii;
    float m = stats[i] * invN;
    float var = stats[128 + i] * invN - m * m;
    float si = g[i] * rsqrtf(var + 1e-5f);
    float ti = be[i] - m * si;
    float w = W[i * 128 + j];
    acc += ti * w;
    int kt = i >> 5, quad = (i >> 3) & 3, jj = i & 7;
    Wb[((((kt * 8 + nt) * 4 + quad) * 16 + n) << 3) + jj] =
        (unsigned short)bf16_rn(si * w);
  }
  atomicAdd(&tw[j], acc);
}

__global__ __launch_bounds__(256) void k_out(const float* __restrict__ pacc,
                                             const float* __restrict__ cntG,
                                             const float* __restrict__ bout,
                                             float* __restrict__ out, int G) {
  int i = blockIdx.x * 256 + threadIdx.x;
  if (i < G) out[i] = pacc[i] / fmaxf(cntG[i], 1.0f) + bout[0];
}

extern "C" void kernel_launch(void* const* d_in, const int* in_sizes, int n_in,
                              void* d_out, int out_size, void* d_ws, size_t ws_size,
                              hipStream_t stream) {
  const float* x    = (const float*)d_in[0];
  const int*   ei   = (const int*)d_in[1];
  const int*   batch= (const int*)d_in[2];
  const float* W0   = (const float*)d_in[3];
  const float* b0   = (const float*)d_in[4];
  const float* W1   = (const float*)d_in[5];
  const float* b1   = (const float*)d_in[6];
  const float* W2   = (const float*)d_in[7];
  const float* b2   = (const float*)d_in[8];
  const float* W3   = (const float*)d_in[9];
  const float* b3   = (const float*)d_in[10];
  const float* g1   = (const float*)d_in[11];
  const float* be1  = (const float*)d_in[12];
  const float* g2   = (const float*)d_in[13];
  const float* be2  = (const float*)d_in[14];
  const float* g3   = (const float*)d_in[15];
  const float* be3  = (const float*)d_in[16];
  const float* Wout = (const float*)d_in[17];
  const float* bout = (const float*)d_in[18];
  float* out = (float*)d_out;

  const int N = in_sizes[0] / 9;
  const int E = in_sizes[1] / 2;
  const int G = out_size;

  char* w = (char*)d_ws;
  auto alloc = [&](size_t bytes) -> void* {
    void* p = (void*)w;
    w += (bytes + 255) & ~(size_t)255;
    return p;
  };
  // ---- zeroed region (ONE memset) ----
  char* zbase = w;
  int*   cnt    = (int*)alloc((size_t)N * 4);
  int*   cursor = (int*)alloc((size_t)N * 4);
  float* cntG   = (float*)alloc((size_t)G * 4);
  float* pacc   = (float*)alloc((size_t)G * 4);
  float* stats  = (float*)alloc(3 * 256 * 4);
  float* tw3    = (float*)alloc(3 * 128 * 4);
  size_t zsize = (size_t)(w - zbase);
  // ---- non-zeroed ----
  int*   offs   = (int*)alloc((size_t)N * 4);
  int*   incl   = (int*)alloc((size_t)N * 4);
  int*   bsums  = (int*)alloc(512 * 4);
  int*   bpref  = (int*)alloc(512 * 4);
  float* dinv   = (float*)alloc((size_t)N * 4);
  float* q      = (float*)alloc((size_t)N * 4);
  int*   rows   = (int*)alloc((size_t)E * 4);
  unsigned short* Wb = (unsigned short*)alloc(128 * 128 * 2);  // bf16 B-frag layout
  unsigned* u   = (unsigned*)alloc((size_t)N * 12 * 2);        // bf16, 24B rows
  float* ax     = (float*)alloc((size_t)N * 12 * 4);
  unsigned* Lb  = (unsigned*)alloc((size_t)N * 128 * 2);       // bf16 rows, 256B
  unsigned short* Abuf = (unsigned short*)alloc((size_t)N * 128 * 2);  // bf16 acts

  hipMemsetAsync(zbase, 0, zsize, stream);

  const int eb  = (E + 255) / 256;
  const int nbN = (N + 255) / 256;  // also the scan block count (must be <= 512)
  const int sb  = (N + 15) / 16;    // spmm / spmm9 / gemm_in blocks
  const int mb  = (N + 63) / 64;    // mfma gemm blocks
  const float invN = 1.0f / (float)N;
  float* twA = tw3;
  float* twB = tw3 + 128;
  float* twC = tw3 + 256;

  // --- graph preprocessing ---
  k_count<<<eb, 256, 0, stream>>>(ei, cnt, E);
  k_scan1<<<nbN, 256, 0, stream>>>(cnt, incl, bsums, dinv, batch, cntG, N);
  k_scan2<<<1, 512, 0, stream>>>(bsums, bpref, nbN);
  k_scan3_prep<<<nbN, 256, 0, stream>>>(incl, cnt, bpref, offs, x, dinv, u, N);
  k_csr<<<eb, 256, 0, stream>>>(ei, offs, cursor, rows, E);

  // --- layer 1: aggregate 9-dim input first (A x) @ W0; also emits q ---
  k_spmm9<<<sb, 256, 0, stream>>>((const unsigned short*)u, offs, cnt, rows,
                                  dinv, ax, q, N);
  k_gemm_in<<<sb, 256, 0, stream>>>(ax, W0, b0, Abuf, stats, N);
  // --- layer 2 ---
  k_fold<<<8, 128, 0, stream>>>(stats, g1, be1, W1, Wb, twA, invN);
  k_gemm_mfma<<<mb, 256, 0, stream>>>(Abuf, (const uint4*)Wb, dinv, (unsigned short*)Lb, N);
  k_spmm<0><<<sb, 256, 0, stream>>>(Lb, offs, cnt, rows, dinv, q, twA, b1,
                                    Abuf, stats + 256, nullptr, nullptr, nullptr, N);
  // --- layer 3 ---
  k_fold<<<8, 128, 0, stream>>>(stats + 256, g2, be2, W2, Wb, twB, invN);
  k_gemm_mfma<<<mb, 256, 0, stream>>>(Abuf, (const uint4*)Wb, dinv, (unsigned short*)Lb, N);
  k_spmm<0><<<sb, 256, 0, stream>>>(Lb, offs, cnt, rows, dinv, q, twB, b2,
                                    Abuf, stats + 512, nullptr, nullptr, nullptr, N);
  // --- layer 4 (+ fused pool @ Wout) ---
  k_fold<<<8, 128, 0, stream>>>(stats + 512, g3, be3, W3, Wb, twC, invN);
  k_gemm_mfma<<<mb, 256, 0, stream>>>(Abuf, (const uint4*)Wb, dinv, (unsigned short*)Lb, N);
  k_spmm<1><<<sb, 256, 0, stream>>>(Lb, offs, cnt, rows, dinv, q, twC, b3,
                                    nullptr, nullptr, Wout, batch, pacc, N);
  k_out<<<(G + 255) / 256, 256, 0, stream>>>(pacc, cntG, bout, out, G);
}

// Round 8
// 864.862 us; speedup vs baseline: 1.6590x; 1.1523x over previous
//
#include <hip/hip_runtime.h>

// GCN forward: 4x [GEMM -> symmetric-normalized aggregation -> lrelu -> BN(folded)]
// then mean-pool per graph @ Wout.
//
// Key structure:
//  - CSR via counting sort, rank captured in count pass (atomicAdd return) ->
//    placement pass has NO atomics (plain random read offs + random write).
//  - Layer 1 commuted: A(x@W0) = (Ax)@W0; u bf16 24B rows (slot 9 = bf16(dinv) so
//    spmm9's idle lane 9 computes sd -> q for free).
//  - dinv folded into GEMM/gather epilogues; BN folded into next GEMM.
//  - k_spmm gather wall (R2-R7): ~45 cy/edge fixed + ~14 cy/line, concurrency
//    capped ~20 line-misses/CU; nt-loads falsified (R7) -> plain loads.
//  - cntG via binary search on sorted batch (no contended atomics).
//  - L bf16 (256B rows), Abuf bf16; 128x128 GEMMs on bf16 MFMA 16x16x32.
//  - Final layer fuses pool; per-block run-aggregated pacc atomics.

#define LRELU(z) ((z) > 0.f ? (z) : 0.01f * (z))
#define ADD4(d, s) \
  { d.x += s.x; d.y += s.y; d.z += s.z; d.w += s.w; }

typedef __attribute__((ext_vector_type(8))) short short8;
typedef __attribute__((ext_vector_type(4))) float float4v;

__device__ inline unsigned bf16_rn(float a) {
  unsigned u = __float_as_uint(a);
  return (u + 0x7FFFu + ((u >> 16) & 1u)) >> 16;
}

__device__ inline unsigned pack_bf16x2(float a, float b) {
  return bf16_rn(a) | (bf16_rn(b) << 16);
}

__device__ inline float bf16f(unsigned short s) {
  return __uint_as_float(((unsigned)s) << 16);
}

__device__ inline float4 unpack_bf16x4(uint2 u) {
  float4 r;
  r.x = __uint_as_float(u.x << 16);
  r.y = __uint_as_float(u.x & 0xffff0000u);
  r.z = __uint_as_float(u.y << 16);
  r.w = __uint_as_float(u.y & 0xffff0000u);
  return r;
}

// count pass: cnt[col]++ and record each edge's rank within its column.
__global__ __launch_bounds__(256) void k_count(const int* __restrict__ ei,
                                               int* __restrict__ cnt,
                                               int* __restrict__ rank, int E) {
  int i = blockIdx.x * 256 + threadIdx.x;
  if (i < E) rank[i] = atomicAdd(&cnt[ei[E + i]], 1);
}

// block-scan of cnt + dinv fused
__global__ __launch_bounds__(256) void k_scan1(const int* __restrict__ cnt,
                                               int* __restrict__ incl,
                                               int* __restrict__ bsums,
                                               float* __restrict__ dinv, int N) {
  __shared__ int s[256];
  int tid = threadIdx.x;
  int idx = blockIdx.x * 256 + tid;
  int v = (idx < N) ? cnt[idx] : 0;
  if (idx < N) dinv[idx] = rsqrtf((float)(v + 1));
  s[tid] = v;
  __syncthreads();
  for (int off = 1; off < 256; off <<= 1) {
    int t = (tid >= off) ? s[tid - off] : 0;
    __syncthreads();
    s[tid] += t;
    __syncthreads();
  }
  if (idx < N) incl[idx] = s[tid];
  if (tid == 255) bsums[blockIdx.x] = s[255];
}

// nb must be <= 512 (N <= 131072 here: nb = 391)
__global__ __launch_bounds__(512) void k_scan2(const int* __restrict__ bsums,
                                               int* __restrict__ bpref, int nb) {
  __shared__ int s[512];
  int tid = threadIdx.x;
  int v = (tid < nb) ? bsums[tid] : 0;
  s[tid] = v;
  __syncthreads();
  for (int off = 1; off < 512; off <<= 1) {
    int t = (tid >= off) ? s[tid - off] : 0;
    __syncthreads();
    s[tid] += t;
    __syncthreads();
  }
  bpref[tid] = s[tid] - v;  // exclusive prefix of block sums
}

// cntG[g] = #nodes with batch==g, via binary search on the SORTED batch array.
__global__ __launch_bounds__(256) void k_cntg(const int* __restrict__ batch,
                                              float* __restrict__ cntG,
                                              int N, int G) {
  int g = blockIdx.x * 256 + threadIdx.x;
  if (g >= G) return;
  int lo = 0, hi = N;
  while (lo < hi) { int mid = (lo + hi) >> 1; if (batch[mid] < g) lo = mid + 1; else hi = mid; }
  int a = lo;
  hi = N;
  while (lo < hi) { int mid = (lo + hi) >> 1; if (batch[mid] < g + 1) lo = mid + 1; else hi = mid; }
  cntG[g] = (float)(lo - a);
}

// offs computation + u preparation fused: u[v][0:9] = bf16(x[v][0:9]*dinv[v]),
// slot 9 = bf16(dinv[v]), slots 10,11 = 0. 24B rows.
__global__ __launch_bounds__(256) void k_scan3_prep(
    const int* __restrict__ incl, const int* __restrict__ cnt,
    const int* __restrict__ bpref, int* __restrict__ offs,
    const float* __restrict__ x, const float* __restrict__ dinv,
    unsigned* __restrict__ u, int N) {
  int idx = blockIdx.x * 256 + threadIdx.x;
  if (idx >= N) return;
  offs[idx] = incl[idx] - cnt[idx] + bpref[blockIdx.x];
  float dv = dinv[idx];
  const float* xr = x + (size_t)idx * 9;
  unsigned p0 = pack_bf16x2(xr[0] * dv, xr[1] * dv);
  unsigned p1 = pack_bf16x2(xr[2] * dv, xr[3] * dv);
  unsigned p2 = pack_bf16x2(xr[4] * dv, xr[5] * dv);
  unsigned p3 = pack_bf16x2(xr[6] * dv, xr[7] * dv);
  unsigned p4 = pack_bf16x2(xr[8] * dv, dv);
  uint2* u2 = (uint2*)u;
  u2[(size_t)idx * 3 + 0] = make_uint2(p0, p1);
  u2[(size_t)idx * 3 + 1] = make_uint2(p2, p3);
  u2[(size_t)idx * 3 + 2] = make_uint2(p4, 0u);
}

// CSR placement: NO atomics (offs random read + rank from count pass).
__global__ __launch_bounds__(256) void k_csr(const int* __restrict__ ei,
                                             const int* __restrict__ offs,
                                             const int* __restrict__ rank,
                                             int* __restrict__ rows, int E) {
  int i = blockIdx.x * 256 + threadIdx.x;
  if (i < E) {
    int c = ei[E + i];
    rows[offs[c] + rank[i]] = ei[i];
  }
}

// ax[v] = dinv[v]*(u[v] + sum_in u[row]); lane 9 accumulates sum_in dinv[row]
// and emits q[v] = dinv*(dinv+sd). 16-lane group per node; coalesced 16-wide
// index load, shfl-broadcast, dependency-free 2B gathers.
__global__ __launch_bounds__(256) void k_spmm9(
    const unsigned short* __restrict__ u, const int* __restrict__ offs,
    const int* __restrict__ cnt, const int* __restrict__ rows,
    const float* __restrict__ dinv, float* __restrict__ ax,
    float* __restrict__ q, int N) {
  const int t = threadIdx.x;
  const int g = t >> 4;
  const int f = t & 15;
  const int v = blockIdx.x * 16 + g;
  if (v >= N) return;
  const int st = offs[v];
  const int dg = cnt[v];
  const bool act = (f < 10);
  float a0 = (f < 9) ? bf16f(u[(size_t)v * 12 + f]) : 0.f;
  float a1 = 0.f, a2 = 0.f, a3 = 0.f;
  for (int b = 0; b < dg; b += 16) {
    int rem = dg - b;
    int idx = 0;
    if (f < rem) idx = rows[st + b + f];
    int mm = rem < 16 ? rem : 16;
    int e = 0;
    for (; e + 8 <= mm; e += 8) {
      int r0 = __shfl(idx, e + 0, 16), r1 = __shfl(idx, e + 1, 16);
      int r2 = __shfl(idx, e + 2, 16), r3 = __shfl(idx, e + 3, 16);
      int r4 = __shfl(idx, e + 4, 16), r5 = __shfl(idx, e + 5, 16);
      int r6 = __shfl(idx, e + 6, 16), r7 = __shfl(idx, e + 7, 16);
      float x0 = 0, x1 = 0, x2 = 0, x3 = 0, x4 = 0, x5 = 0, x6 = 0, x7 = 0;
      if (act) {
        x0 = bf16f(u[(size_t)r0 * 12 + f]); x1 = bf16f(u[(size_t)r1 * 12 + f]);
        x2 = bf16f(u[(size_t)r2 * 12 + f]); x3 = bf16f(u[(size_t)r3 * 12 + f]);
        x4 = bf16f(u[(size_t)r4 * 12 + f]); x5 = bf16f(u[(size_t)r5 * 12 + f]);
        x6 = bf16f(u[(size_t)r6 * 12 + f]); x7 = bf16f(u[(size_t)r7 * 12 + f]);
      }
      a0 += x0; a1 += x1; a2 += x2; a3 += x3;
      a0 += x4; a1 += x5; a2 += x6; a3 += x7;
    }
    for (; e + 4 <= mm; e += 4) {
      int r0 = __shfl(idx, e + 0, 16), r1 = __shfl(idx, e + 1, 16);
      int r2 = __shfl(idx, e + 2, 16), r3 = __shfl(idx, e + 3, 16);
      float x0 = 0, x1 = 0, x2 = 0, x3 = 0;
      if (act) {
        x0 = bf16f(u[(size_t)r0 * 12 + f]); x1 = bf16f(u[(size_t)r1 * 12 + f]);
        x2 = bf16f(u[(size_t)r2 * 12 + f]); x3 = bf16f(u[(size_t)r3 * 12 + f]);
      }
      a0 += x0; a1 += x1; a2 += x2; a3 += x3;
    }
    for (; e < mm; e++) {
      int r = __shfl(idx, e, 16);
      if (act) a0 += bf16f(u[(size_t)r * 12 + f]);
    }
  }
  float sum = (a0 + a1) + (a2 + a3);
  if (f < 9) {
    ax[(size_t)v * 12 + f] = sum * dinv[v];
  } else if (f == 9) {
    float dv = dinv[v];
    q[v] = dv * (dv + sum);
  }
}

// h1 = lrelu(ax[v][0:9] @ W0 + b0); writes Abuf (bf16); accumulates fp32 BN stats.
__global__ __launch_bounds__(256) void k_gemm_in(
    const float* __restrict__ ax, const float* __restrict__ W0,
    const float* __restrict__ b0, unsigned short* __restrict__ Abuf,
    float* __restrict__ stats, int N) {
  __shared__ float Wl[9 * 128];
  __shared__ float rs[128], rq[128];
  const int t = threadIdx.x;
  for (int i = t; i < 9 * 128; i += 256) Wl[i] = W0[i];
  if (t < 128) { rs[t] = 0.f; rq[t] = 0.f; }
  __syncthreads();
  const int col = t & 127;
  const int rsub = t >> 7;
  const int base = blockIdx.x * 16;
  const float bc = b0[col];
  float ls = 0.f, lq = 0.f;
  for (int it = 0; it < 8; it++) {
    int row = base + it * 2 + rsub;
    if (row < N) {
      const float* ar = ax + (size_t)row * 12;
      float acc = bc;
#pragma unroll
      for (int k = 0; k < 9; k++) acc += ar[k] * Wl[k * 128 + col];
      float a = LRELU(acc);
      Abuf[(size_t)row * 128 + col] = (unsigned short)bf16_rn(a);
      ls += a;
      lq += a * a;
    }
  }
  atomicAdd(&rs[col], ls);
  atomicAdd(&rq[col], lq);
  __syncthreads();
  if (t < 128) {
    atomicAdd(&stats[t], rs[t]);
    atomicAdd(&stats[128 + t], rq[t]);
  }
}

// bf16 MFMA GEMM: L[v][:] = bf16((A[v][:] @ Wf) * dinv[v]).
// Block: 64 rows, 4 waves x (16 rows x 128 cols). Wb pre-swizzled B-frag order.
__global__ __launch_bounds__(256) void k_gemm_mfma(
    const unsigned short* __restrict__ Ab, const uint4* __restrict__ Wb,
    const float* __restrict__ dinv, unsigned short* __restrict__ Lb, int N) {
  __shared__ uint4 Bl[2048];               // 32 KB: all B fragments
  __shared__ unsigned short Dl[4 * 2048];  // 16 KB: per-wave D staging
  __shared__ float dvs[64];
  const int t = threadIdx.x;
  const int row0 = blockIdx.x * 64;
#pragma unroll
  for (int i = 0; i < 8; i++) Bl[t + i * 256] = Wb[t + i * 256];
  if (t < 64) {
    int r = row0 + t;
    dvs[t] = (r < N) ? dinv[r] : 0.f;
  }
  __syncthreads();
  const int w = t >> 6;
  const int lane = t & 63;
  const int m = lane & 15;
  const int quad = lane >> 4;
  const int rowA = min(row0 + w * 16 + m, N - 1);
  const uint4* Arow = (const uint4*)(Ab + (size_t)rowA * 128);
  uint4 a[4];
#pragma unroll
  for (int kt = 0; kt < 4; kt++) a[kt] = Arow[kt * 4 + quad];
  float4v acc[8];
#pragma unroll
  for (int nt = 0; nt < 8; nt++) acc[nt] = (float4v)0.0f;
#pragma unroll
  for (int nt = 0; nt < 8; nt++) {
#pragma unroll
    for (int kt = 0; kt < 4; kt++) {
      uint4 b = Bl[((kt * 8 + nt) * 4 + quad) * 16 + m];
      acc[nt] = __builtin_amdgcn_mfma_f32_16x16x32_bf16(
          *(short8*)&a[kt], *(short8*)&b, acc[nt], 0, 0, 0);
    }
  }
  unsigned short* Dw = Dl + w * 2048;
#pragma unroll
  for (int r = 0; r < 4; r++) {
    float dv = dvs[w * 16 + quad * 4 + r];
#pragma unroll
    for (int nt = 0; nt < 8; nt++) {
      Dw[(quad * 4 + r) * 128 + nt * 16 + m] =
          (unsigned short)bf16_rn(acc[nt][r] * dv);
    }
  }
  __syncthreads();
  const uint4* Dw4 = (const uint4*)Dw;
#pragma unroll
  for (int p = 0; p < 4; p++) {
    int row = row0 + w * 16 + p * 4 + (lane >> 4);
    if (row < N) {
      ((uint4*)(Lb + (size_t)row * 128))[lane & 15] = Dw4[p * 64 + lane];
    }
  }
}

// SpMM over 128-dim bf16 rows (256B). 8 groups x 32 lanes; group owns a node,
// lane q32 owns bf16x4 chunk q32. Indices loaded 32-wide, shfl-broadcast,
// gathers dependency-free. fp32 accumulate.
// MODE 0: a = lrelu(dinv*(self+gather) + q*tw + b); write Aout (bf16); BN stats.
// MODE 1: same a, dot(a,Wout) group-reduced; pacc atomics run-aggregated per block.
template <int MODE>
__global__ __launch_bounds__(256) void k_spmm(
    const unsigned* __restrict__ Lb, const int* __restrict__ offs,
    const int* __restrict__ cnt, const int* __restrict__ rows,
    const float* __restrict__ dinv, const float* __restrict__ qv,
    const float* __restrict__ tw, const float* __restrict__ bias,
    unsigned short* __restrict__ Aout, float* __restrict__ stats,
    const float* __restrict__ wout, const int* __restrict__ batch,
    float* __restrict__ pacc, int N) {
  const int t = threadIdx.x;
  const int g = t >> 5;
  const int q32 = t & 31;
  const uint2* __restrict__ L2p = (const uint2*)Lb;
  const float4 t4 = ((const float4*)tw)[q32];
  const float4 b4 = ((const float4*)bias)[q32];
  float4 wo4 = make_float4(0, 0, 0, 0);
  if (MODE == 1) wo4 = ((const float4*)wout)[q32];
  __shared__ float rs[128], rq[128];
  __shared__ float psum[16];
  __shared__ int pb[16];
  float4 ls = make_float4(0, 0, 0, 0), lq = make_float4(0, 0, 0, 0);
  if (MODE == 0) {
    if (t < 128) { rs[t] = 0.f; rq[t] = 0.f; }
    __syncthreads();
  } else {
    if (t < 16) pb[t] = -1;
    __syncthreads();
  }
  const int vbase = blockIdx.x * 16 + g * 2;
  for (int n = 0; n < 2; n++) {
    const int v = vbase + n;
    if (v >= N) break;
    const int st = offs[v];
    const int dg = cnt[v];
    float4 s0 = unpack_bf16x4(L2p[(size_t)v * 32 + q32]);
    float4 s1 = make_float4(0, 0, 0, 0), s2 = s1, s3 = s1;
    for (int b = 0; b < dg; b += 32) {
      int rem = dg - b;
      int idx = 0;
      if (q32 < rem) idx = rows[st + b + q32];
      int mm = rem < 32 ? rem : 32;
      int e = 0;
      for (; e + 8 <= mm; e += 8) {
        int r0 = __shfl(idx, e + 0, 32), r1 = __shfl(idx, e + 1, 32);
        int r2 = __shfl(idx, e + 2, 32), r3 = __shfl(idx, e + 3, 32);
        int r4 = __shfl(idx, e + 4, 32), r5 = __shfl(idx, e + 5, 32);
        int r6 = __shfl(idx, e + 6, 32), r7 = __shfl(idx, e + 7, 32);
        uint2 u0 = L2p[(size_t)r0 * 32 + q32];
        uint2 u1 = L2p[(size_t)r1 * 32 + q32];
        uint2 u2 = L2p[(size_t)r2 * 32 + q32];
        uint2 u3 = L2p[(size_t)r3 * 32 + q32];
        uint2 u4 = L2p[(size_t)r4 * 32 + q32];
        uint2 u5 = L2p[(size_t)r5 * 32 + q32];
        uint2 u6 = L2p[(size_t)r6 * 32 + q32];
        uint2 u7 = L2p[(size_t)r7 * 32 + q32];
        float4 g0 = unpack_bf16x4(u0); ADD4(s0, g0);
        float4 g1 = unpack_bf16x4(u1); ADD4(s1, g1);
        float4 g2 = unpack_bf16x4(u2); ADD4(s2, g2);
        float4 g3 = unpack_bf16x4(u3); ADD4(s3, g3);
        float4 g4 = unpack_bf16x4(u4); ADD4(s0, g4);
        float4 g5 = unpack_bf16x4(u5); ADD4(s1, g5);
        float4 g6 = unpack_bf16x4(u6); ADD4(s2, g6);
        float4 g7 = unpack_bf16x4(u7); ADD4(s3, g7);
      }
      for (; e + 4 <= mm; e += 4) {
        int r0 = __shfl(idx, e + 0, 32), r1 = __shfl(idx, e + 1, 32);
        int r2 = __shfl(idx, e + 2, 32), r3 = __shfl(idx, e + 3, 32);
        uint2 u0 = L2p[(size_t)r0 * 32 + q32];
        uint2 u1 = L2p[(size_t)r1 * 32 + q32];
        uint2 u2 = L2p[(size_t)r2 * 32 + q32];
        uint2 u3 = L2p[(size_t)r3 * 32 + q32];
        float4 g0 = unpack_bf16x4(u0); ADD4(s0, g0);
        float4 g1 = unpack_bf16x4(u1); ADD4(s1, g1);
        float4 g2 = unpack_bf16x4(u2); ADD4(s2, g2);
        float4 g3 = unpack_bf16x4(u3); ADD4(s3, g3);
      }
      for (; e < mm; e++) {
        int r = __shfl(idx, e, 32);
        float4 g0 = unpack_bf16x4(L2p[(size_t)r * 32 + q32]);
        ADD4(s0, g0);
      }
    }
    float4 acc;
    acc.x = (s0.x + s1.x) + (s2.x + s3.x);
    acc.y = (s0.y + s1.y) + (s2.y + s3.y);
    acc.z = (s0.z + s1.z) + (s2.z + s3.z);
    acc.w = (s0.w + s1.w) + (s2.w + s3.w);
    const float dv = dinv[v];
    const float qf = qv[v];
    float4 a;
    a.x = LRELU(dv * acc.x + qf * t4.x + b4.x);
    a.y = LRELU(dv * acc.y + qf * t4.y + b4.y);
    a.z = LRELU(dv * acc.z + qf * t4.z + b4.z);
    a.w = LRELU(dv * acc.w + qf * t4.w + b4.w);
    if (MODE == 0) {
      uint2 p;
      p.x = pack_bf16x2(a.x, a.y);
      p.y = pack_bf16x2(a.z, a.w);
      ((uint2*)Aout)[(size_t)v * 32 + q32] = p;
      ls.x += a.x; ls.y += a.y; ls.z += a.z; ls.w += a.w;
      lq.x += a.x * a.x; lq.y += a.y * a.y;
      lq.z += a.z * a.z; lq.w += a.w * a.w;
    } else {
      float s = a.x * wo4.x + a.y * wo4.y + a.z * wo4.z + a.w * wo4.w;
      s += __shfl_down(s, 16, 32);
      s += __shfl_down(s, 8, 32);
      s += __shfl_down(s, 4, 32);
      s += __shfl_down(s, 2, 32);
      s += __shfl_down(s, 1, 32);
      if (q32 == 0) {
        psum[g * 2 + n] = s;
        pb[g * 2 + n] = batch[v];
      }
    }
  }
  if (MODE == 0) {
    const int f0 = q32 * 4;
    atomicAdd(&rs[f0 + 0], ls.x); atomicAdd(&rs[f0 + 1], ls.y);
    atomicAdd(&rs[f0 + 2], ls.z); atomicAdd(&rs[f0 + 3], ls.w);
    atomicAdd(&rq[f0 + 0], lq.x); atomicAdd(&rq[f0 + 1], lq.y);
    atomicAdd(&rq[f0 + 2], lq.z); atomicAdd(&rq[f0 + 3], lq.w);
    __syncthreads();
    if (t < 128) {
      atomicAdd(&stats[t], rs[t]);
      atomicAdd(&stats[128 + t], rq[t]);
    }
  } else {
    __syncthreads();
    if (t < 16) {
      int b = pb[t];
      if (b >= 0 && (t == 0 || pb[t - 1] != b)) {
        float s = psum[t];
        for (int j = t + 1; j < 16 && pb[j] == b; j++) s += psum[j];
        atomicAdd(&pacc[b], s);
      }
    }
  }
}

// Fold BN affine into next layer's weights (parallel: 8 blocks x 16 W-rows).
// Emits bf16 Wb in MFMA B-frag order; tw accumulated atomically (pre-zeroed).
__global__ __launch_bounds__(128) void k_fold(const float* __restrict__ stats,
                                              const float* __restrict__ g,
                                              const float* __restrict__ be,
                                              const float* __restrict__ W,
                                              unsigned short* __restrict__ Wb,
                                              float* __restrict__ tw, float invN) {
  const int j = threadIdx.x;
  const int i0 = blockIdx.x * 16;
  const int nt = j >> 4;
  const int n = j & 15;
  float acc = 0.f;
#pragma unroll
  for (int ii = 0; ii < 16; ii++) {
    int i = i0 + ii;
    float m = stats[i] * invN;
    float var = stats[128 + i] * invN - m * m;
    float si = g[i] * rsqrtf(var + 1e-5f);
    float ti = be[i] - m * si;
    float w = W[i * 128 + j];
    acc += ti * w;
    int kt = i >> 5, quad = (i >> 3) & 3, jj = i & 7;
    Wb[((((kt * 8 + nt) * 4 + quad) * 16 + n) << 3) + jj] =
        (unsigned short)bf16_rn(si * w);
  }
  atomicAdd(&tw[j], acc);
}

__global__ __launch_bounds__(256) void k_out(const float* __restrict__ pacc,
                                             const float* __restrict__ cntG,
                                             const float* __restrict__ bout,
                                             float* __restrict__ out, int G) {
  int i = blockIdx.x * 256 + threadIdx.x;
  if (i < G) out[i] = pacc[i] / fmaxf(cntG[i], 1.0f) + bout[0];
}

extern "C" void kernel_launch(void* const* d_in, const int* in_sizes, int n_in,
                              void* d_out, int out_size, void* d_ws, size_t ws_size,
                              hipStream_t stream) {
  const float* x    = (const float*)d_in[0];
  const int*   ei   = (const int*)d_in[1];
  const int*   batch= (const int*)d_in[2];
  const float* W0   = (const float*)d_in[3];
  const float* b0   = (const float*)d_in[4];
  const float* W1   = (const float*)d_in[5];
  const float* b1   = (const float*)d_in[6];
  const float* W2   = (const float*)d_in[7];
  const float* b2   = (const float*)d_in[8];
  const float* W3   = (const float*)d_in[9];
  const float* b3   = (const float*)d_in[10];
  const float* g1   = (const float*)d_in[11];
  const float* be1  = (const float*)d_in[12];
  const float* g2   = (const float*)d_in[13];
  const float* be2  = (const float*)d_in[14];
  const float* g3   = (const float*)d_in[15];
  const float* be3  = (const float*)d_in[16];
  const float* Wout = (const float*)d_in[17];
  const float* bout = (const float*)d_in[18];
  float* out = (float*)d_out;

  const int N = in_sizes[0] / 9;
  const int E = in_sizes[1] / 2;
  const int G = out_size;

  char* w = (char*)d_ws;
  auto alloc = [&](size_t bytes) -> void* {
    void* p = (void*)w;
    w += (bytes + 255) & ~(size_t)255;
    return p;
  };
  // ---- zeroed region (ONE memset) ----
  char* zbase = w;
  int*   cnt    = (int*)alloc((size_t)N * 4);
  float* pacc   = (float*)alloc((size_t)G * 4);
  float* stats  = (float*)alloc(3 * 256 * 4);
  float* tw3    = (float*)alloc(3 * 128 * 4);
  size_t zsize = (size_t)(w - zbase);
  // ---- non-zeroed ----
  int*   offs   = (int*)alloc((size_t)N * 4);
  int*   incl   = (int*)alloc((size_t)N * 4);
  int*   bsums  = (int*)alloc(512 * 4);
  int*   bpref  = (int*)alloc(512 * 4);
  float* dinv   = (float*)alloc((size_t)N * 4);
  float* q      = (float*)alloc((size_t)N * 4);
  float* cntG   = (float*)alloc((size_t)G * 4);
  int*   rank   = (int*)alloc((size_t)E * 4);
  int*   rows   = (int*)alloc((size_t)E * 4);
  unsigned short* Wb = (unsigned short*)alloc(128 * 128 * 2);  // bf16 B-frag layout
  unsigned* u   = (unsigned*)alloc((size_t)N * 12 * 2);        // bf16, 24B rows
  float* ax     = (float*)alloc((size_t)N * 12 * 4);
  unsigned* Lb  = (unsigned*)alloc((size_t)N * 128 * 2);       // bf16 rows, 256B
  unsigned short* Abuf = (unsigned short*)alloc((size_t)N * 128 * 2);  // bf16 acts

  hipMemsetAsync(zbase, 0, zsize, stream);

  const int eb  = (E + 255) / 256;
  const int nbN = (N + 255) / 256;  // also the scan block count (must be <= 512)
  const int sb  = (N + 15) / 16;    // spmm / spmm9 / gemm_in blocks
  const int mb  = (N + 63) / 64;    // mfma gemm blocks
  const float invN = 1.0f / (float)N;
  float* twA = tw3;
  float* twB = tw3 + 128;
  float* twC = tw3 + 256;

  // --- graph preprocessing ---
  k_count<<<eb, 256, 0, stream>>>(ei, cnt, rank, E);
  k_scan1<<<nbN, 256, 0, stream>>>(cnt, incl, bsums, dinv, N);
  k_scan2<<<1, 512, 0, stream>>>(bsums, bpref, nbN);
  k_scan3_prep<<<nbN, 256, 0, stream>>>(incl, cnt, bpref, offs, x, dinv, u, N);
  k_csr<<<eb, 256, 0, stream>>>(ei, offs, rank, rows, E);
  k_cntg<<<(G + 255) / 256, 256, 0, stream>>>(batch, cntG, N, G);

  // --- layer 1: aggregate 9-dim input first (A x) @ W0; also emits q ---
  k_spmm9<<<sb, 256, 0, stream>>>((const unsigned short*)u, offs, cnt, rows,
                                  dinv, ax, q, N);
  k_gemm_in<<<sb, 256, 0, stream>>>(ax, W0, b0, Abuf, stats, N);
  // --- layer 2 ---
  k_fold<<<8, 128, 0, stream>>>(stats, g1, be1, W1, Wb, twA, invN);
  k_gemm_mfma<<<mb, 256, 0, stream>>>(Abuf, (const uint4*)Wb, dinv, (unsigned short*)Lb, N);
  k_spmm<0><<<sb, 256, 0, stream>>>(Lb, offs, cnt, rows, dinv, q, twA, b1,
                                    Abuf, stats + 256, nullptr, nullptr, nullptr, N);
  // --- layer 3 ---
  k_fold<<<8, 128, 0, stream>>>(stats + 256, g2, be2, W2, Wb, twB, invN);
  k_gemm_mfma<<<mb, 256, 0, stream>>>(Abuf, (const uint4*)Wb, dinv, (unsigned short*)Lb, N);
  k_spmm<0><<<sb, 256, 0, stream>>>(Lb, offs, cnt, rows, dinv, q, twB, b2,
                                    Abuf, stats + 512, nullptr, nullptr, nullptr, N);
  // --- layer 4 (+ fused pool @ Wout) ---
  k_fold<<<8, 128, 0, stream>>>(stats + 512, g3, be3, W3, Wb, twC, invN);
  k_gemm_mfma<<<mb, 256, 0, stream>>>(Abuf, (const uint4*)Wb, dinv, (unsigned short*)Lb, N);
  k_spmm<1><<<sb, 256, 0, stream>>>(Lb, offs, cnt, rows, dinv, q, twC, b3,
                                    nullptr, nullptr, Wout, batch, pacc, N);
  k_out<<<(G + 255) / 256, 256, 0, stream>>>(pacc, cntG, bout, out, G);
}